// Round 1
// 20883.893 us; speedup vs baseline: 1.1500x; 1.1500x over previous
//
#include <hip/hip_runtime.h>
#include <cstddef>
#include <cstdint>
#include <math.h>

// ============================ constants ============================
static constexpr int NN   = 1024;   // lr_dim
static constexpr int HRD  = 2048;   // hr_dim
static constexpr int DIMF = 320;
static constexpr int TB   = 85;     // sytrd LDS tail block (85x87 fp64 = 59 KB LDS)
static constexpr int CB2  = 256;    // persistent sytrd blocks (<= CU count -> co-resident)
static constexpr int BT2  = 1024;   // threads per sytrd block (16 waves)
static constexpr int NGRP = 8;      // barrier tree groups
static constexpr int BPG  = 32;     // blocks per group (CB2 = NGRP*BPG)
static constexpr int NWY  = 16;     // WY reflector groups (64 each)

#define EPI_NONE      0
#define EPI_BIAS      1
#define EPI_BIAS_ADD  2
#define EPI_ABS_DIAG1 3
#define EPI_RELU      4

// agent-scope coherent access helpers (sc1): bypass stale per-XCD L2 without fences.
// [R6 measured: RELAXED agent loads observe remote atomicAdds -> coherent read path works]
// NOTE: these now carry ONLY the small cross-block traffic (Rstage pivot row, P, pvA).
// Bulk trailing-matrix traffic is owner-private and uses plain cached loads/stores.
__device__ __forceinline__ double gload(const double* p){
    return __hip_atomic_load(p, __ATOMIC_RELAXED, __HIP_MEMORY_SCOPE_AGENT);
}
__device__ __forceinline__ void gstore(double* p, double v){
    __hip_atomic_store(p, v, __ATOMIC_RELAXED, __HIP_MEMORY_SCOPE_AGENT);
}

// ============================ fp32 GEMM 64-tile (fallback, odd K) ============================
template<int EPI>
__global__ __launch_bounds__(256) void gemm32(
    const float* __restrict__ A, const float* __restrict__ B, float* __restrict__ C,
    int M, int N, int K, const float* __restrict__ bias, const float* __restrict__ D)
{
    __shared__ float As[16][65];
    __shared__ float Bs[16][65];
    const int bm = blockIdx.y << 6, bn = blockIdx.x << 6;
    const int tid = threadIdx.x;
    const int tm = (tid >> 4) << 2, tn = (tid & 15) << 2;
    float acc[4][4] = {};
    const int kt = (K + 15) >> 4;
    for (int k0 = 0; k0 < kt; ++k0){
        const int kb = k0 << 4;
        for (int t = tid; t < 1024; t += 256){
            int m = t >> 4, k = t & 15;
            int gm = bm + m, gk = kb + k;
            As[k][m] = (gm < M && gk < K) ? A[(size_t)gm*K + gk] : 0.f;
        }
        for (int t = tid; t < 1024; t += 256){
            int k = t >> 6, nn2 = t & 63;
            int gk = kb + k, gn = bn + nn2;
            Bs[k][nn2] = (gk < K && gn < N) ? B[(size_t)gk*N + gn] : 0.f;
        }
        __syncthreads();
        #pragma unroll
        for (int k = 0; k < 16; ++k){
            float a0 = As[k][tm], a1 = As[k][tm+1], a2 = As[k][tm+2], a3 = As[k][tm+3];
            float b0 = Bs[k][tn], b1 = Bs[k][tn+1], b2 = Bs[k][tn+2], b3 = Bs[k][tn+3];
            acc[0][0] += a0*b0; acc[0][1] += a0*b1; acc[0][2] += a0*b2; acc[0][3] += a0*b3;
            acc[1][0] += a1*b0; acc[1][1] += a1*b1; acc[1][2] += a1*b2; acc[1][3] += a1*b3;
            acc[2][0] += a2*b0; acc[2][1] += a2*b1; acc[2][2] += a2*b2; acc[2][3] += a2*b3;
            acc[3][0] += a3*b0; acc[3][1] += a3*b1; acc[3][2] += a3*b2; acc[3][3] += a3*b3;
        }
        __syncthreads();
    }
    #pragma unroll
    for (int r = 0; r < 4; ++r){
        int gm = bm + tm + r; if (gm >= M) continue;
        #pragma unroll
        for (int c = 0; c < 4; ++c){
            int gn = bn + tn + c; if (gn >= N) continue;
            float v = acc[r][c];
            if (EPI == EPI_BIAS)            v += bias[gn];
            else if (EPI == EPI_BIAS_ADD)   v += bias[gn] + D[(size_t)gm*N + gn];
            else if (EPI == EPI_ABS_DIAG1)  v = (gm == gn) ? 1.0f : fabsf(v);
            else if (EPI == EPI_RELU)       v = fmaxf(v, 0.0f);
            C[(size_t)gm*N + gn] = v;
        }
    }
}

// ============================ fp32 GEMM 128-tile (K%16==0, N%8==0) ============================
template<int EPI>
__global__ __launch_bounds__(256) void gemm128(
    const float* __restrict__ A, const float* __restrict__ B, float* __restrict__ C,
    int M, int N, int K, const float* __restrict__ bias, const float* __restrict__ D)
{
    __shared__ float As[16][132];
    __shared__ float Bs[16][132];
    const int bm = blockIdx.y << 7, bn = blockIdx.x << 7;
    const int tid = threadIdx.x;
    const int tm = (tid >> 4) << 3;
    const int tn = (tid & 15) << 3;
    const int ar = tid >> 1;
    const int ak = (tid & 1) << 3;
    const int br = tid >> 4;
    const int bc = (tid & 15) << 3;
    float acc[8][8] = {};
    for (int kb = 0; kb < K; kb += 16){
        {
            int gm = bm + ar, gk = kb + ak;
            float4 a0, a1;
            if (gm < M){
                const float* p = A + (size_t)gm*K + gk;
                a0 = *(const float4*)p; a1 = *(const float4*)(p + 4);
            } else { a0 = make_float4(0.f,0.f,0.f,0.f); a1 = a0; }
            As[ak+0][ar]=a0.x; As[ak+1][ar]=a0.y; As[ak+2][ar]=a0.z; As[ak+3][ar]=a0.w;
            As[ak+4][ar]=a1.x; As[ak+5][ar]=a1.y; As[ak+6][ar]=a1.z; As[ak+7][ar]=a1.w;
        }
        {
            int gk = kb + br, gn = bn + bc;
            float4 b0, b1;
            if (gn + 7 < N){
                const float* p = B + (size_t)gk*N + gn;
                b0 = *(const float4*)p; b1 = *(const float4*)(p + 4);
            } else {
                float t0[8];
                #pragma unroll
                for (int i = 0; i < 8; ++i){ int g = gn + i; t0[i] = (g < N) ? B[(size_t)gk*N + g] : 0.f; }
                b0 = make_float4(t0[0],t0[1],t0[2],t0[3]); b1 = make_float4(t0[4],t0[5],t0[6],t0[7]);
            }
            *(float4*)&Bs[br][bc] = b0; *(float4*)&Bs[br][bc+4] = b1;
        }
        __syncthreads();
        #pragma unroll
        for (int k = 0; k < 16; ++k){
            float4 a0 = *(const float4*)&As[k][tm];
            float4 a1 = *(const float4*)&As[k][tm+4];
            float4 b0 = *(const float4*)&Bs[k][tn];
            float4 b1 = *(const float4*)&Bs[k][tn+4];
            float av[8] = {a0.x,a0.y,a0.z,a0.w,a1.x,a1.y,a1.z,a1.w};
            float bv[8] = {b0.x,b0.y,b0.z,b0.w,b1.x,b1.y,b1.z,b1.w};
            #pragma unroll
            for (int i = 0; i < 8; ++i)
                #pragma unroll
                for (int jj = 0; jj < 8; ++jj) acc[i][jj] += av[i]*bv[jj];
        }
        __syncthreads();
    }
    #pragma unroll
    for (int i = 0; i < 8; ++i){
        int gm = bm + tm + i; if (gm >= M) continue;
        #pragma unroll
        for (int jj = 0; jj < 8; ++jj){
            int gn = bn + tn + jj; if (gn >= N) continue;
            float v = acc[i][jj];
            if (EPI == EPI_BIAS)            v += bias[gn];
            else if (EPI == EPI_BIAS_ADD)   v += bias[gn] + D[(size_t)gm*N + gn];
            else if (EPI == EPI_ABS_DIAG1)  v = (gm == gn) ? 1.0f : fabsf(v);
            else if (EPI == EPI_RELU)       v = fmaxf(v, 0.0f);
            C[(size_t)gm*N + gn] = v;
        }
    }
}

// ============================ small kernels ============================
__global__ __launch_bounds__(256) void rowsum_rsqrt_k(const float* __restrict__ lr, double* __restrict__ r64, int n)
{
    __shared__ double sm[256];
    int row = blockIdx.x;
    double s = 0.0;
    for (int j = threadIdx.x; j < n; j += 256) s += (double)lr[(size_t)row*n + j];
    sm[threadIdx.x] = s; __syncthreads();
    for (int o = 128; o; o >>= 1){ if (threadIdx.x < o) sm[threadIdx.x] += sm[threadIdx.x + o]; __syncthreads(); }
    if (threadIdx.x == 0){
        double t = sm[0];
        r64[row] = (t > 0.0) ? 1.0/sqrt(t) : 0.0;
    }
}

__global__ __launch_bounds__(256) void build_A_k(const float* __restrict__ lr, const double* __restrict__ r64,
                                                 float* __restrict__ A32, double* __restrict__ A64, int n)
{
    size_t idx = (size_t)blockIdx.x*256 + threadIdx.x;
    if (idx >= (size_t)n*n) return;
    int i = (int)(idx / n), j = (int)(idx % n);
    if (j < i) return;
    double v = (double)lr[(size_t)j*n + i] * r64[i] * r64[j];
    A64[(size_t)i*n + j] = v; A64[(size_t)j*n + i] = v;
    float vf = (float)v;
    A32[(size_t)i*n + j] = vf; A32[(size_t)j*n + i] = vf;
}

__global__ __launch_bounds__(256) void score_k(const float* __restrict__ X, const float* __restrict__ pw,
                                               const float* __restrict__ pb, float* __restrict__ out,
                                               int n, int dim)
{
    int row = blockIdx.x*4 + (threadIdx.x >> 6);
    int lane = threadIdx.x & 63;
    if (row >= n) return;
    float acc = 0.f;
    for (int c = lane; c < dim; c += 64) acc += X[(size_t)row*dim + c]*pw[c];
    #pragma unroll
    for (int o = 32; o; o >>= 1) acc += __shfl_down(acc, o);
    if (lane == 0){
        float t = (acc + pb[0]) * 0.01f;
        out[row] = 1.0f/(1.0f + expf(-t));
    }
}

// jax.lax.top_k semantics: descending value, ties -> lower index first
__global__ __launch_bounds__(256) void topk_k(const float* __restrict__ scores, int n, int k,
                                              int* __restrict__ idxo, float* __restrict__ valo)
{
    __shared__ float s[1024];
    int tid = threadIdx.x;
    for (int i = tid; i < n; i += 256) s[i] = scores[i];
    __syncthreads();
    for (int i = tid; i < n; i += 256){
        float si = s[i]; int r = 0;
        for (int j = 0; j < n; ++j){
            float sj = s[j];
            r += (sj > si) || (sj == si && j < i);
        }
        if (r < k){ idxo[r] = i; valo[r] = si; }
    }
}

__global__ __launch_bounds__(256) void gatherX_k(const float* __restrict__ X, const int* __restrict__ idx,
                                                 const float* __restrict__ vals, float* __restrict__ Xo,
                                                 int k, int dim)
{
    size_t t = (size_t)blockIdx.x*256 + threadIdx.x;
    if (t >= (size_t)k*dim) return;
    int m = (int)(t / dim), c = (int)(t % dim);
    Xo[t] = X[(size_t)idx[m]*dim + c] * vals[m];
}

__global__ __launch_bounds__(256) void scatterX_k(const float* __restrict__ Xs, const int* __restrict__ idx,
                                                  float* __restrict__ Xu, int k, int dim)
{
    size_t t = (size_t)blockIdx.x*256 + threadIdx.x;
    if (t >= (size_t)k*dim) return;
    int m = (int)(t / dim), c = (int)(t % dim);
    Xu[(size_t)idx[m]*dim + c] = Xs[t];
}

__global__ __launch_bounds__(256) void gatherA_k(const float* __restrict__ A, const int* __restrict__ idx,
                                                 float* __restrict__ Ao, int k, int n)
{
    size_t t = (size_t)blockIdx.x*256 + threadIdx.x;
    if (t >= (size_t)k*k) return;
    int m1 = (int)(t / k), m2 = (int)(t % k);
    Ao[t] = A[(size_t)idx[m1]*n + idx[m2]];
}

__global__ __launch_bounds__(256) void fill0_k(float* __restrict__ p, size_t cnt)
{
    size_t t = (size_t)blockIdx.x*256 + threadIdx.x;
    if (t < cnt) p[t] = 0.f;
}

__global__ __launch_bounds__(256) void filld0_k(double* __restrict__ p, size_t cnt)
{
    size_t t = (size_t)blockIdx.x*256 + threadIdx.x;
    if (t < cnt) p[t] = 0.0;
}

__global__ __launch_bounds__(256) void init_sytrd_k(double* __restrict__ pv, unsigned* __restrict__ bar, int n)
{
    int t = blockIdx.x*256 + threadIdx.x;
    if (t < n) pv[t] = 0.0;
    if (t < 1024) bar[t] = 0u;
}

__global__ __launch_bounds__(256) void concat_k(const float* __restrict__ X, const float* __restrict__ orgX,
                                                float* __restrict__ Xc, int n, int dim)
{
    size_t t = (size_t)blockIdx.x*256 + threadIdx.x;
    size_t tot = (size_t)n*2*dim;
    if (t >= tot) return;
    int i = (int)(t / (2*dim)), c = (int)(t % (2*dim));
    Xc[t] = (c < dim) ? X[(size_t)i*dim + c] : orgX[(size_t)i*dim + (c - dim)];
}

__global__ __launch_bounds__(256) void build_a_k(const float* __restrict__ gsr, float* __restrict__ a)
{
    size_t idx = (size_t)blockIdx.x*256 + threadIdx.x;
    if (idx >= (size_t)HRD*NN) return;
    int i = (int)(idx >> 10), k = (int)(idx & 1023);
    a[idx] = gsr[(size_t)i*HRD + k] + gsr[(size_t)i*HRD + NN + k];
}

__global__ __launch_bounds__(256) void symabs1_k(float* __restrict__ Z, int n)
{
    size_t idx = (size_t)blockIdx.x*256 + threadIdx.x;
    if (idx >= (size_t)n*n) return;
    int i = (int)(idx / n), j = (int)(idx % n);
    if (i > j) return;
    float a = Z[(size_t)i*n + j], b = Z[(size_t)j*n + i];
    float v = 0.5f*(a + b);
    float o = (i == j) ? 1.0f : fabsf(v);
    Z[(size_t)i*n + j] = o; Z[(size_t)j*n + i] = o;
}

__global__ __launch_bounds__(256) void final_z_k(const float* __restrict__ h2, float* __restrict__ z, int n)
{
    size_t idx = (size_t)blockIdx.x*256 + threadIdx.x;
    if (idx >= (size_t)n*n) return;
    int i = (int)(idx / n), j = (int)(idx % n);
    if (i > j) return;
    float v = 0.5f*(h2[(size_t)i*n + j] + h2[(size_t)j*n + i]);
    float o = (i == j) ? 1.0f : fabsf(v);
    z[(size_t)i*n + j] = o; z[(size_t)j*n + i] = o;
}

// dst[c][r] = (float)src[r][c]   (n x n, n % 32 == 0)
__global__ __launch_bounds__(256) void transpose_cast_k(const double* __restrict__ src, float* __restrict__ dst, int n)
{
    __shared__ float tile[32][33];
    int r0 = blockIdx.y*32, c0 = blockIdx.x*32;
    int tx = threadIdx.x & 31, ty = threadIdx.x >> 5;
    for (int i = ty; i < 32; i += 8)
        tile[i][tx] = (float)src[(size_t)(r0 + i)*n + (c0 + tx)];
    __syncthreads();
    for (int i = ty; i < 32; i += 8)
        dst[(size_t)(c0 + i)*n + (r0 + tx)] = tile[tx][i];
}

// dst[c][r] = src[r][c]  (n x n, n % 32 == 0)
__global__ __launch_bounds__(256) void transpose32_k(const float* __restrict__ src, float* __restrict__ dst, int n)
{
    __shared__ float tile[32][33];
    int r0 = blockIdx.y*32, c0 = blockIdx.x*32;
    int tx = threadIdx.x & 31, ty = threadIdx.x >> 5;
    for (int i = ty; i < 32; i += 8)
        tile[i][tx] = src[(size_t)(r0 + i)*n + (c0 + tx)];
    __syncthreads();
    for (int i = ty; i < 32; i += 8)
        dst[(size_t)(c0 + i)*n + (r0 + tx)] = tile[tx][i];
}

// ============================ persistent Householder tridiagonalization ============================
// Barrier: RELAXED arrivals + RELAXED spin. __syncthreads() drains vmcnt(0) per wave
// (compiler-emitted before s_barrier), which completes all sc1 stores and atomics at the
// coherent point -> no __threadfence needed. Deliberately NOT device-fencing: owner-private
// A rows stay DIRTY in the owner's per-XCD L2 (that locality is the whole point).
__device__ __forceinline__ void gbar4(unsigned* __restrict__ bar, unsigned epoch)
{
    __syncthreads();
    if (threadIdx.x == 0){
        int g = blockIdx.x >> 5;   // / BPG
        unsigned t = __hip_atomic_fetch_add(&bar[g*32], 1u, __ATOMIC_RELAXED, __HIP_MEMORY_SCOPE_AGENT);
        if ((t & (unsigned)(BPG - 1)) == (unsigned)(BPG - 1))
            __hip_atomic_fetch_add(&bar[256], 1u, __ATOMIC_RELAXED, __HIP_MEMORY_SCOPE_AGENT);
        unsigned target = epoch * (unsigned)NGRP;
        while (__hip_atomic_load(&bar[256], __ATOMIC_RELAXED, __HIP_MEMORY_SCOPE_AGENT) < target)
            __builtin_amdgcn_s_sleep(2);
    }
    __syncthreads();
}

// One-barrier-per-column fused sytrd, FIXED row ownership:
//   warp-quad u (4 waves) owns physical row u for the whole factorization, so all
//   trailing-matrix read-modify-write traffic is block-private -> plain cached
//   loads/stores (L1/L2-resident), no agent-scope path.
// Cross-block traffic per column (sc1/atomic only):
//   - Rstage[(j+1)&1][*]: next pivot row published by its owner during phase B
//   - P[j][*], pvA[j]: matvec accumulation via device atomicAdd
// Phase A's reflector row (old rowp gloads) is replaced by VJ_prev, still in LDS.
__global__ __launch_bounds__(BT2) void sytrd_coop5(
    double* __restrict__ A, double* __restrict__ e, double* __restrict__ tauA,
    double* __restrict__ sclA, double* __restrict__ P, double* __restrict__ pvA,
    double* __restrict__ Rst, unsigned* __restrict__ bar, int n, int jend)
{
    __shared__ double VP[1024], WP[1024], VJ[1024];
    __shared__ double red16[16];
    __shared__ double sh_b;
    const int tid   = threadIdx.x;
    const int bid   = blockIdx.x;
    const int lane  = tid & 63;
    const int wid   = tid >> 6;
    const int gw    = bid*(BT2/64) + wid;
    const int u     = gw >> 2;        // fixed physical row owned by this warp-quad
    const int chunk = gw & 3;

    double tau_p = 0.0, sc_p = 0.0;
    unsigned ep = 0;

    for (int j = 0; j < jend; ++j){
        // retired block (all owned rows <= j, and not the row-j writeback owner):
        // nothing to compute, just keep the barrier sequence.
        if (((bid << 2) | 3) < j){ ++ep; gbar4(bar, ep); continue; }

        const int m = n - 1 - j;
        double c2_p = 0.0;
        // ---- phase A: build VP/WP for pending reflector j-1 (VP from LDS VJ_prev) ----
        if (j > 0){
            c2_p = 0.5*tau_p*tau_p*gload(&pvA[j-1]);
            const double* __restrict__ pp = P + (size_t)(j-1)*NN;
            for (int i = tid; i <= m; i += BT2){
                double vp = (i == 0) ? 1.0 : VJ[i]*sc_p;
                VP[i] = vp;
                WP[i] = tau_p*gload(&pp[i]) - c2_p*vp;
            }
            __syncthreads();
        }
        // ---- pivot row j -> VJ (redundant in every active block) ----
        double s = 0.0;
        if (j > 0){
            const double* __restrict__ rs = Rst + (size_t)(j & 1)*NN;  // published last column
            double wp0 = WP[0];
            for (int t = tid; t < m; t += BT2){
                double x = gload(&rs[1+t]) - WP[1+t] - wp0*VP[1+t];
                VJ[t] = x;
                if (t >= 1) s += x*x;
            }
        } else {
            const double* __restrict__ row0 = A + 1;   // row 0, cols 1..n-1 (plain: fresh from build_A_k)
            for (int t = tid; t < m; t += BT2){
                double x = row0[t];
                VJ[t] = x;
                if (t >= 1) s += x*x;
            }
        }
        #pragma unroll
        for (int o = 32; o; o >>= 1) s += __shfl_down(s, o);
        if (lane == 0) red16[wid] = s;
        __syncthreads();
        if (tid == 0){
            double t2 = 0.0;
            #pragma unroll
            for (int i = 0; i < 16; ++i) t2 += red16[i];
            sh_b = t2;
        }
        __syncthreads();
        double sigma2 = sh_b;
        double alpha = VJ[0];
        double beta, tl, sc;
        if (sigma2 == 0.0){ beta = alpha; tl = 0.0; sc = 0.0; }
        else {
            beta = -copysign(sqrt(alpha*alpha + sigma2), alpha);
            tl = (beta - alpha)/beta;
            sc = 1.0/(alpha - beta);
        }
        // ---- owner-block writeback of row j (plain stores over its own L2 lines) ----
        if (bid == (j >> 2)){
            double* __restrict__ row = A + (size_t)j*n + (j+1);
            for (int t = tid; t < m; t += BT2) row[t] = VJ[t];
            if (tid == 0){
                e[j] = beta; tauA[j] = tl; sclA[j] = sc;
                if (j > 0) A[(size_t)j*n + j] -= 2.0*WP[0];
            }
        }
        // ---- phase B: owner-private trailing update + matvec; publish next pivot row ----
        double pvloc = 0.0;
        if (u > j){
            const int r = u - (j+1);
            double* __restrict__ Ar   = A + (size_t)u*n + (j+1);
            double* __restrict__ rs_w = Rst + (size_t)((j+1) & 1)*NN;
            const bool pub = (r == 0);   // row j+1 is next column's pivot
            double acc = 0.0;
            if (j > 0){
                double vpr = VP[1+r], wpr = WP[1+r];
                for (int c = chunk*64 + lane; c < m; c += 256){
                    double a = Ar[c] - (vpr*WP[1+c] + wpr*VP[1+c]);
                    Ar[c] = a;
                    if (pub) gstore(&rs_w[c], a);
                    double vj = (c == 0) ? 1.0 : VJ[c]*sc;
                    acc += a*vj;
                }
            } else {
                for (int c = chunk*64 + lane; c < m; c += 256){
                    double a = Ar[c];
                    if (pub) gstore(&rs_w[c], a);
                    double vj = (c == 0) ? 1.0 : VJ[c]*sc;
                    acc += a*vj;
                }
            }
            #pragma unroll
            for (int o = 32; o; o >>= 1) acc += __shfl_down(acc, o);
            if (lane == 0){
                atomicAdd(&P[(size_t)j*NN + r], acc);
                double vr = (r == 0) ? 1.0 : VJ[r]*sc;
                pvloc = acc*vr;
            }
        }
        if (lane == 0) red16[wid] = pvloc;
        __syncthreads();
        if (tid == 0){
            double t2 = 0.0;
            #pragma unroll
            for (int i = 0; i < 16; ++i) t2 += red16[i];
            if (t2 != 0.0) atomicAdd(&pvA[j], t2);
        }
        ++ep; gbar4(bar, ep);
        tau_p = tl; sc_p = sc;
    }
    // ---- apply final pending update (column jend-1) on the TB x TB tail, owner-only ----
    // (blocks owning tail rows never hit the skip path: their VJ/tau_p/sc_p are current)
    if (u >= jend){
        const int tb = n - jend;
        double c2f = 0.5*tau_p*tau_p*gload(&pvA[jend-1]);
        const double* __restrict__ pp = P + (size_t)(jend-1)*NN;
        const int ri = u - jend;
        double vpr = (ri == 0) ? 1.0 : VJ[ri]*sc_p;
        double wpr = tau_p*gload(&pp[ri]) - c2f*vpr;
        double* __restrict__ Ar = A + (size_t)u*n + jend;
        for (int ci = chunk*64 + lane; ci < tb; ci += 256){
            double vpc = (ci == 0) ? 1.0 : VJ[ci]*sc_p;
            double wpc = tau_p*gload(&pp[ci]) - c2f*vpc;
            Ar[ci] -= vpr*wpc + wpr*vpc;
        }
    }
}

// Tail: remaining (TB-2) Householder steps entirely in LDS (single block).
__global__ __launch_bounds__(256) void hh_tail(double* __restrict__ A64, double* __restrict__ e,
                                               double* __restrict__ tau, double* __restrict__ scaleg, int n)
{
    __shared__ double T[TB][TB+2];
    __shared__ double v[TB], p[TB], red[256];
    const int base = n - TB;
    const int tid = threadIdx.x;
    for (int t = tid; t < TB*TB; t += 256){
        int r = t / TB, c = t % TB;
        T[r][c] = A64[(size_t)(base + r)*n + base + c];
    }
    __syncthreads();
    for (int l = 0; l <= TB - 3; ++l){
        const int m = TB - 1 - l;
        double s = 0.0;
        for (int i = 1 + tid; i < m; i += 256){ double x = T[l+1+i][l]; s += x*x; }
        red[tid] = s; __syncthreads();
        for (int o = 128; o; o >>= 1){ if (tid < o) red[tid] += red[tid + o]; __syncthreads(); }
        double sigma2 = red[0];
        double alpha = T[l+1][l];
        double beta, tl, sc;
        if (sigma2 == 0.0){ beta = alpha; tl = 0.0; sc = 0.0; }
        else {
            beta = -copysign(sqrt(alpha*alpha + sigma2), alpha);
            tl = (beta - alpha)/beta;
            sc = 1.0/(alpha - beta);
        }
        for (int i = tid; i < m; i += 256) v[i] = (i == 0) ? 1.0 : T[l+1+i][l]*sc;
        __syncthreads();
        for (int i = tid; i < m; i += 256){
            double acc = 0.0;
            for (int c = 0; c < m; ++c) acc += T[l+1+i][l+1+c]*v[c];
            p[i] = acc;
        }
        __syncthreads();
        double s2 = 0.0;
        for (int i = tid; i < m; i += 256) s2 += p[i]*v[i];
        red[tid] = s2; __syncthreads();
        for (int o = 128; o; o >>= 1){ if (tid < o) red[tid] += red[tid + o]; __syncthreads(); }
        double pvv = red[0];
        double c2 = 0.5*tl*tl*pvv;
        for (int t2 = tid; t2 < m*m; t2 += 256){
            int r = t2 / m, c = t2 % m;
            double wr = tl*p[r] - c2*v[r];
            double wc = tl*p[c] - c2*v[c];
            T[l+1+r][l+1+c] -= v[r]*wc + wr*v[c];
        }
        if (tid == 0){ int j = base + l; e[j] = beta; tau[j] = tl; scaleg[j] = 1.0; }
        for (int i = tid; i < m; i += 256) A64[(size_t)(base + l)*n + (base + l + 1) + i] = v[i];
        __syncthreads();
    }
    for (int r = tid; r < TB; r += 256) A64[(size_t)(base + r)*n + base + r] = T[r][r];
    if (tid == 0) A64[(size_t)(n-1)*n + (n-2)] = T[TB-1][TB-2];
}

__global__ __launch_bounds__(256) void extract_de_k(const double* __restrict__ A64, double* __restrict__ d,
                                                    double* __restrict__ e, int n)
{
    int i = blockIdx.x*256 + threadIdx.x;
    if (i < n) d[i] = A64[(size_t)i*n + i];
    if (i == 0) e[n-2] = A64[(size_t)(n-1)*n + (n-2)];
}

// ============================ tridiagonal eigensolver ============================
// Multiplication-form Sturm count (no division in the dependent chain):
//   p_i = (d_i - x) p_{i-1} - e_{i-1}^2 p_{i-2};  q_i = p_i/p_{i-1};
//   count = #{i : q_i < 0} = # sign changes; pair-rescaled to avoid under/overflow.
__global__ __launch_bounds__(256) void bisect_k(const double* __restrict__ d, const double* __restrict__ e,
                                                double* __restrict__ w, int n)
{
    __shared__ double ds[1024], e2s[1024];
    const int tid = threadIdx.x;
    for (int i = tid; i < n; i += 256) ds[i] = d[i];
    for (int i = tid; i < n-1; i += 256){ double ei = e[i]; e2s[i] = ei*ei; }
    __syncthreads();
    int k = blockIdx.x*256 + tid;
    if (k >= n) return;
    double gl = 1e300, gu = -1e300;
    for (int i = 0; i < n; ++i){
        double em = (i > 0) ? sqrt(e2s[i-1]) : 0.0, ep2 = (i < n-1) ? sqrt(e2s[i]) : 0.0;
        double lo2 = ds[i] - em - ep2, hi2 = ds[i] + em + ep2;
        gl = fmin(gl, lo2); gu = fmax(gu, hi2);
    }
    double lo = gl - 1e-10, hi = gu + 1e-10;
    for (int it = 0; it < 42; ++it){
        double mid = 0.5*(lo + hi);
        int cnt = 0;
        double p0 = 1.0;
        double p1 = ds[0] - mid;
        if (p1 <= 0.0){ ++cnt; if (p1 == 0.0) p1 = -1e-300; }
        for (int i = 1; i < n; ++i){
            double pn = (ds[i] - mid)*p1 - e2s[i-1]*p0;
            bool neg = ((pn < 0.0) != (p1 < 0.0)) || (pn == 0.0);
            cnt += neg;
            if (pn == 0.0) pn = (p1 > 0.0) ? -1e-300 : 1e-300;
            p0 = p1; p1 = pn;
            double ap = fabs(p1);
            if (ap > 1e120){ p1 *= 1e-200; p0 *= 1e-200; }
            else if (ap < 1e-120){ p1 *= 1e200; p0 *= 1e200; }
        }
        if (cnt <= k) lo = mid; else hi = mid;
    }
    w[k] = 0.5*(lo + hi);
}

__global__ __launch_bounds__(256) void invit_k(const double* __restrict__ d, const double* __restrict__ e,
                                               const double* __restrict__ w,
                                               double* __restrict__ FD, double* __restrict__ FL,
                                               double* __restrict__ FU, double* __restrict__ FU2,
                                               signed char* __restrict__ PIV, double* __restrict__ Z, int n)
{
    int k = blockIdx.x*256 + threadIdx.x;
    if (k >= n) return;
    const double lam = w[k];
    const double tiny = 1e-280;
    double dcur = d[0] - lam;
    double ucur = e[0];
    for (int i = 0; i < n-1; ++i){
        double dli = e[i];
        double dnext_init = d[i+1] - lam;
        double unext_init = (i < n-2) ? e[i+1] : 0.0;
        size_t o = (size_t)i*n + k;
        if (fabs(dcur) >= fabs(dli)){
            if (dcur == 0.0) dcur = tiny;
            double f = dli/dcur;
            FD[o] = dcur; FL[o] = f; FU[o] = ucur; FU2[o] = 0.0; PIV[o] = 0;
            dcur = dnext_init - f*ucur;
            ucur = unext_init;
        } else {
            double f = dcur/dli;
            FD[o] = dli; FL[o] = f; FU[o] = dnext_init; FU2[o] = unext_init; PIV[o] = 1;
            dcur = ucur - f*dnext_init;
            ucur = -f*unext_init;
        }
    }
    if (dcur == 0.0) dcur = tiny;
    FD[(size_t)(n-1)*n + k] = dcur;
    for (int i = 0; i < n; ++i){
        unsigned h = (unsigned)(i + 1)*0x9E3779B9u + (unsigned)(k + 1)*0x85EBCA6Bu;
        h ^= h >> 16; h *= 0x7FEB352Du; h ^= h >> 15; h *= 0x846CA68Bu; h ^= h >> 16;
        Z[(size_t)i*n + k] = (double)(h >> 8)*(1.0/16777216.0) - 0.5;
    }
    for (int iter = 0; iter < 2; ++iter){
        double zc = Z[k];
        for (int i = 0; i < n-1; ++i){
            size_t o = (size_t)i*n + k;
            double fl = FL[o];
            double zn = Z[o + n];
            if (!PIV[o]){
                Z[o] = zc;
                zc = zn - fl*zc;
            } else {
                Z[o] = zn;
                zc = zc - fl*zn;
            }
        }
        double za = zc / FD[(size_t)(n-1)*n + k];
        Z[(size_t)(n-1)*n + k] = za;
        size_t o2 = (size_t)(n-2)*n + k;
        double zaa = (Z[o2] - FU[o2]*za) / FD[o2];
        Z[o2] = zaa;
        double zb = za;
        for (int i = n-3; i >= 0; --i){
            size_t o = (size_t)i*n + k;
            double znew = (Z[o] - FU[o]*zaa - FU2[o]*zb) / FD[o];
            Z[o] = znew;
            zb = zaa; zaa = znew;
        }
        double mx = 0.0;
        for (int i = 0; i < n; ++i) mx = fmax(mx, fabs(Z[(size_t)i*n + k]));
        double s = (mx > 0.0) ? 1.0/mx : 1.0;
        for (int i = 0; i < n; ++i) Z[(size_t)i*n + k] *= s;
    }
    double nrm = 0.0;
    for (int i = 0; i < n; ++i){ double v = Z[(size_t)i*n + k]; nrm += v*v; }
    double s = 1.0/sqrt(nrm);
    for (int i = 0; i < n; ++i) Z[(size_t)i*n + k] *= s;
}

// ============================ batched blocked-WY back-transform ============================
__global__ __launch_bounds__(256) void wy_buildV_k(const double* __restrict__ A64, const double* __restrict__ scaleg,
                                                   double* __restrict__ Vbig, int n)
{
    size_t idx = (size_t)blockIdx.x*256 + threadIdx.x;
    if (idx >= (size_t)NWY*1024*64) return;
    int g = (int)(idx >> 16);
    int r = (int)((idx >> 6) & 1023);
    int t = (int)(idx & 63);
    int b0 = g*64;
    int nbsz = (n - 2) - b0; if (nbsz > 64) nbsz = 64;
    double v = 0.0;
    if (t < nbsz){
        int j = b0 + t;
        if (r == j + 1) v = 1.0;
        else if (r > j + 1) v = A64[(size_t)j*n + r]*scaleg[j];
    }
    Vbig[idx] = v;
}

__global__ __launch_bounds__(256) void wy_buildT_k(const double* __restrict__ Vbig, const double* __restrict__ tau,
                                                   double* __restrict__ Tbig, int n)
{
    __shared__ double G[64][65];
    __shared__ double Ts[64][65];
    __shared__ double Vs[32][65];
    const int g = blockIdx.x;
    const int tid = threadIdx.x;
    const double* __restrict__ V = Vbig + ((size_t)g << 16);
    const int b0 = g*64;
    int nbsz = (n - 2) - b0; if (nbsz > 64) nbsz = 64;
    for (int p = tid; p < 64*64; p += 256) G[p >> 6][p & 63] = 0.0;
    __syncthreads();
    for (int rb = b0; rb < n; rb += 32){
        for (int s = tid; s < 2048; s += 256){
            int rr = s >> 6, tt = s & 63;
            Vs[rr][tt] = V[((size_t)(rb + rr) << 6) + tt];
        }
        __syncthreads();
        for (int p = tid; p < 4096; p += 256){
            int t = p >> 6, s2 = p & 63;
            if (t < s2 && s2 < nbsz){
                double acc = 0.0;
                #pragma unroll 8
                for (int rr = 0; rr < 32; ++rr) acc += Vs[rr][t]*Vs[rr][s2];
                G[t][s2] += acc;
            }
        }
        __syncthreads();
    }
    for (int t = nbsz - 1; t >= 0; --t){
        for (int u = tid; u < 64; u += 256){
            double val = 0.0;
            if (u == t) val = tau[b0 + t];
            else if (u > t && u < nbsz){
                double s = 0.0;
                for (int s2 = t + 1; s2 <= u; ++s2) s += G[t][s2]*Ts[s2][u];
                val = -tau[b0 + t]*s;
            }
            Ts[t][u] = val;
        }
        __syncthreads();
    }
    for (int p = tid; p < 64*64; p += 256){
        int t = p >> 6, u = p & 63;
        Tbig[((size_t)g << 12) + p] = (t < nbsz) ? Ts[t][u] : 0.0;
    }
}

__global__ __launch_bounds__(256) void wy_apply_k(const double* __restrict__ Vbig, const double* __restrict__ Tbig,
                                                  double* __restrict__ Z, int n)
{
    __shared__ double Vs[32][65];
    __shared__ double Zs[32][17];
    __shared__ double Y[64][17];
    __shared__ double W[64][17];
    const int tid = threadIdx.x;
    const int c   = tid & 15;
    const int tq  = tid >> 4;
    const int c0  = blockIdx.x * 16;

    for (int g = NWY - 1; g >= 0; --g){
        const double* __restrict__ V = Vbig + ((size_t)g << 16);
        const double* __restrict__ T = Tbig + ((size_t)g << 12);
        const int b0 = g*64;
        double acc0 = 0.0, acc1 = 0.0, acc2 = 0.0, acc3 = 0.0;
        for (int rb = b0; rb < n; rb += 32){
            for (int s = tid; s < 2048; s += 256){
                int rr = s >> 6, tt = s & 63;
                Vs[rr][tt] = V[((size_t)(rb + rr) << 6) + tt];
            }
            for (int s = tid; s < 512; s += 256){
                int rr = s >> 4, cc = s & 15;
                Zs[rr][cc] = Z[(size_t)(rb + rr)*n + c0 + cc];
            }
            __syncthreads();
            #pragma unroll 8
            for (int rr = 0; rr < 32; ++rr){
                double z = Zs[rr][c];
                acc0 += Vs[rr][tq*4+0]*z;
                acc1 += Vs[rr][tq*4+1]*z;
                acc2 += Vs[rr][tq*4+2]*z;
                acc3 += Vs[rr][tq*4+3]*z;
            }
            __syncthreads();
        }
        Y[tq*4+0][c] = acc0; Y[tq*4+1][c] = acc1; Y[tq*4+2][c] = acc2; Y[tq*4+3][c] = acc3;
        __syncthreads();
        #pragma unroll
        for (int i = 0; i < 4; ++i){
            int t = tq*4 + i;
            double a = 0.0;
            for (int s = t; s < 64; ++s) a += T[(t << 6) + s]*Y[s][c];
            W[t][c] = a;
        }
        __syncthreads();
        for (int rb = b0; rb < n; rb += 32){
            for (int s = tid; s < 2048; s += 256){
                int rr = s >> 6, tt = s & 63;
                Vs[rr][tt] = V[((size_t)(rb + rr) << 6) + tt];
            }
            __syncthreads();
            #pragma unroll
            for (int half = 0; half < 2; ++half){
                int item = tid + half*256;
                int rr = item >> 4, cc = item & 15;
                double s = 0.0;
                #pragma unroll 16
                for (int t = 0; t < 64; ++t) s += Vs[rr][t]*W[t][cc];
                Z[(size_t)(rb + rr)*n + c0 + cc] -= s;
            }
            __syncthreads();
        }
        __syncthreads();
    }
}

// ============================ host dispatch helpers ============================
static void gemmf32(hipStream_t st, int epi,
                    const float* A, const float* B, float* C, int M, int N, int K,
                    const float* bias, const float* D)
{
    if ((K & 15) == 0 && (N & 7) == 0){
        dim3 g((N + 127)/128, (M + 127)/128), b(256);
        switch (epi){
        case EPI_NONE:      gemm128<EPI_NONE><<<g, b, 0, st>>>(A, B, C, M, N, K, bias, D); break;
        case EPI_BIAS:      gemm128<EPI_BIAS><<<g, b, 0, st>>>(A, B, C, M, N, K, bias, D); break;
        case EPI_BIAS_ADD:  gemm128<EPI_BIAS_ADD><<<g, b, 0, st>>>(A, B, C, M, N, K, bias, D); break;
        case EPI_ABS_DIAG1: gemm128<EPI_ABS_DIAG1><<<g, b, 0, st>>>(A, B, C, M, N, K, bias, D); break;
        case EPI_RELU:      gemm128<EPI_RELU><<<g, b, 0, st>>>(A, B, C, M, N, K, bias, D); break;
        }
    } else {
        dim3 g((N + 63)/64, (M + 63)/64), b(256);
        switch (epi){
        case EPI_NONE:      gemm32<EPI_NONE><<<g, b, 0, st>>>(A, B, C, M, N, K, bias, D); break;
        case EPI_BIAS:      gemm32<EPI_BIAS><<<g, b, 0, st>>>(A, B, C, M, N, K, bias, D); break;
        case EPI_BIAS_ADD:  gemm32<EPI_BIAS_ADD><<<g, b, 0, st>>>(A, B, C, M, N, K, bias, D); break;
        case EPI_ABS_DIAG1: gemm32<EPI_ABS_DIAG1><<<g, b, 0, st>>>(A, B, C, M, N, K, bias, D); break;
        case EPI_RELU:      gemm32<EPI_RELU><<<g, b, 0, st>>>(A, B, C, M, N, K, bias, D); break;
        }
    }
}

// ============================ kernel_launch ============================
extern "C" void kernel_launch(void* const* d_in, const int* in_sizes, int n_in,
                              void* d_out, int out_size, void* d_ws, size_t ws_size,
                              hipStream_t stream)
{
    (void)in_sizes; (void)n_in; (void)out_size; (void)ws_size;
    const float* lr       = (const float*)d_in[0];
    const float* gsr_w    = (const float*)d_in[1];
    const float* start_w  = (const float*)d_in[2];
    const float* start_b  = (const float*)d_in[3];
    const float* down_w   = (const float*)d_in[4];
    const float* down_b   = (const float*)d_in[5];
    const float* pool_w   = (const float*)d_in[6];
    const float* pool_b   = (const float*)d_in[7];
    const float* bottom_w = (const float*)d_in[8];
    const float* bottom_b = (const float*)d_in[9];
    const float* end_w    = (const float*)d_in[10];
    const float* end_b    = (const float*)d_in[11];
    const float* up_w     = (const float*)d_in[12];
    const float* up_b     = (const float*)d_in[13];
    const float* gc1      = (const float*)d_in[14];
    const float* gc2      = (const float*)d_in[15];

    float* out_z     = (float*)d_out;                       // [2048,2048]
    float* out_net   = out_z + (size_t)HRD*HRD;             // [1024,2048]
    float* out_start = out_net + (size_t)NN*HRD;            // [1024,320]
    float* out_adj   = out_start + (size_t)NN*DIMF;         // [2048,2048]

    static const int LVL_N[4] = {1024, 921, 644, 386};
    static const int LVL_K[4] = {921, 644, 386, 193};

    // -------- workspace arena --------
    char* Wb = (char*)d_ws;
    size_t off = 0;
    auto alloc = [&](size_t bb)->char*{ char* p = Wb + off; off = (off + bb + 255) & ~(size_t)255; return p; };

    float*  A32  = (float*) alloc((size_t)NN*NN*4);
    double* A64  = (double*)alloc((size_t)NN*NN*8);
    float*  UfT  = (float*) alloc((size_t)NN*NN*4);   // U^T as [k][j] fp32
    double* r64  = (double*)alloc(NN*8);
    double* dD   = (double*)alloc(NN*8);
    double* dE   = (double*)alloc(NN*8);
    double* dTau = (double*)alloc(NN*8);
    double* dScl = (double*)alloc(NN*8);
    double* dWev = (double*)alloc(NN*8);
    double* pvA  = (double*)alloc(NN*8);
    double* Rst  = (double*)alloc((size_t)2*NN*8);    // double-buffered pivot-row stage (sc1)
    unsigned* barcnt = (unsigned*)alloc(8192);
    char* SBASE = Wb + off;

    // P2 overlay (U-Net)
    size_t so = 0;
    auto salloc = [&](size_t bb)->char*{ char* p = SBASE + so; so = (so + bb + 255) & ~(size_t)255; return p; };
    float* XT  = (float*)salloc((size_t)NN*DIMF*4);
    float* XP1 = (float*)salloc((size_t)NN*DIMF*4);
    float* XP2 = (float*)salloc((size_t)NN*DIMF*4);
    float* XU  = (float*)salloc((size_t)NN*DIMF*4);
    float* DN[4]; for (int l = 0; l < 4; ++l) DN[l] = (float*)salloc((size_t)NN*DIMF*4);
    float* Asub[4];
    for (int l = 0; l < 4; ++l) Asub[l] = (float*)salloc((size_t)LVL_K[l]*LVL_K[l]*4);
    float* SC = (float*)salloc(NN*4);
    int*   IDX[4]; for (int l = 0; l < 4; ++l) IDX[l] = (int*)salloc(NN*4);
    float* VAL[4]; for (int l = 0; l < 4; ++l) VAL[l] = (float*)salloc(NN*4);
    float* XC  = (float*)salloc((size_t)NN*2*DIMF*4);
    float* AXC = (float*)salloc((size_t)NN*2*DIMF*4);

    // P3 overlay (eigensolver scratch)
    const size_t PL = (size_t)NN*NN*8;
    double* Z64 = (double*)(SBASE);
    double* FD  = (double*)(SBASE + PL);       // doubles as Pmat during sytrd, Vbig during WY
    double* FL  = (double*)(SBASE + 2*PL);     // doubles as Tbig during WY
    double* FU  = (double*)(SBASE + 3*PL);
    double* FU2 = (double*)(SBASE + 4*PL);
    signed char* FPIV = (signed char*)(SBASE + 5*PL);
    double* Pmat = FD;
    double* Vbig = FD;
    double* Tbig = FL;

    // P4 overlay (GSR / refinement)
    const size_t MB8  = (size_t)HRD*NN*4;    // 8 MiB
    const size_t MB16 = (size_t)HRD*HRD*4;   // 16 MiB
    float* P4a   = (float*)(SBASE);
    float* P4t1  = (float*)(SBASE + MB8);
    float* P4adT = (float*)(SBASE);
    float* P4Zb  = (float*)(SBASE + MB16);
    float* P4ZG  = (float*)(SBASE);
    float* P4h1  = (float*)(SBASE + MB8);
    float* P4HG  = (float*)(SBASE + MB16);
    float* P4h2  = (float*)(SBASE);

    // =============== P1: normalized adjacency ===============
    rowsum_rsqrt_k<<<NN, 256, 0, stream>>>(lr, r64, NN);
    build_A_k<<<(NN*NN + 255)/256, 256, 0, stream>>>(lr, r64, A32, A64, NN);

    // =============== P2: graph U-Net (fp32) ===============
    gemmf32(stream, EPI_BIAS, A32, start_w, out_start, NN, DIMF, NN, start_b, nullptr);

    const float* Xcur = out_start;
    const float* Acur = A32;
    float* ping = XP1; float* pong = XP2;
    for (int l = 0; l < 4; ++l){
        int nl = LVL_N[l], kl = LVL_K[l];
        gemmf32(stream, EPI_NONE, Acur, Xcur, XT, nl, DIMF, nl, nullptr, nullptr);
        gemmf32(stream, EPI_BIAS, XT, down_w + (size_t)l*DIMF*DIMF, DN[l], nl, DIMF, DIMF,
                down_b + (size_t)l*DIMF, nullptr);
        score_k<<<(nl + 3)/4, 256, 0, stream>>>(DN[l], pool_w + (size_t)l*DIMF, pool_b + l, SC, nl, DIMF);
        topk_k<<<1, 256, 0, stream>>>(SC, nl, kl, IDX[l], VAL[l]);
        gatherX_k<<<(unsigned)(((size_t)kl*DIMF + 255)/256), 256, 0, stream>>>(DN[l], IDX[l], VAL[l], ping, kl, DIMF);
        gatherA_k<<<(unsigned)(((size_t)kl*kl + 255)/256), 256, 0, stream>>>(Acur, IDX[l], Asub[l], kl, nl);
        Xcur = ping; Acur = Asub[l];
        float* t = ping; ping = pong; pong = t;
    }
    gemmf32(stream, EPI_NONE, Acur, Xcur, XT, 193, DIMF, 193, nullptr, nullptr);
    float* Xb = ping;
    gemmf32(stream, EPI_BIAS, XT, bottom_w, Xb, 193, DIMF, DIMF, bottom_b, nullptr);
    const float* Xup = Xb;
    float* upbuf[2] = { (Xb == XP1) ? XP2 : XP1, (Xb == XP1) ? XP1 : XP2 };
    for (int i2 = 0; i2 < 4; ++i2){
        int jl = 3 - i2;
        int nj = LVL_N[jl];
        int kj = LVL_K[jl];
        fill0_k<<<(unsigned)(((size_t)nj*DIMF + 255)/256), 256, 0, stream>>>(XU, (size_t)nj*DIMF);
        scatterX_k<<<(unsigned)(((size_t)kj*DIMF + 255)/256), 256, 0, stream>>>(Xup, IDX[jl], XU, kj, DIMF);
        const float* Aj = (jl == 0) ? A32 : Asub[jl - 1];
        gemmf32(stream, EPI_NONE, Aj, XU, XT, nj, DIMF, nj, nullptr, nullptr);
        float* Xn = upbuf[i2 & 1];
        gemmf32(stream, EPI_BIAS_ADD, XT, up_w + (size_t)i2*DIMF*DIMF, Xn, nj, DIMF, DIMF,
                up_b + (size_t)i2*DIMF, DN[jl]);
        Xup = Xn;
    }
    concat_k<<<(unsigned)(((size_t)NN*2*DIMF + 255)/256), 256, 0, stream>>>(Xup, out_start, XC, NN, DIMF);
    gemmf32(stream, EPI_NONE, A32, XC, AXC, NN, 2*DIMF, NN, nullptr, nullptr);
    gemmf32(stream, EPI_BIAS, AXC, end_w, out_net, NN, HRD, 2*DIMF, end_b, nullptr);

    // =============== P3: eigendecomposition of A (fp64) ===============
    const int JEND = NN - TB;
    init_sytrd_k<<<4, 256, 0, stream>>>(pvA, barcnt, NN);
    filld0_k<<<(unsigned)(((size_t)JEND*NN + 255)/256), 256, 0, stream>>>(Pmat, (size_t)JEND*NN);
    sytrd_coop5<<<CB2, BT2, 0, stream>>>(A64, dE, dTau, dScl, Pmat, pvA, Rst, barcnt, NN, JEND);
    hh_tail<<<1, 256, 0, stream>>>(A64, dE, dTau, dScl, NN);
    extract_de_k<<<4, 256, 0, stream>>>(A64, dD, dE, NN);
    bisect_k<<<4, 256, 0, stream>>>(dD, dE, dWev, NN);
    invit_k<<<4, 256, 0, stream>>>(dD, dE, dWev, FD, FL, FU, FU2, FPIV, Z64, NN);
    wy_buildV_k<<<(unsigned)(((size_t)NWY*1024*64 + 255)/256), 256, 0, stream>>>(A64, dScl, Vbig, NN);
    wy_buildT_k<<<NWY, 256, 0, stream>>>(Vbig, dTau, Tbig, NN);
    wy_apply_k<<<NN/16, 256, 0, stream>>>(Vbig, Tbig, Z64, NN);
    {
        dim3 g(NN/32, NN/32), b(256);
        transpose_cast_k<<<g, b, 0, stream>>>(Z64, UfT, NN);
    }

    // =============== P4: GSR layer + refinement (fp32) ===============
    build_a_k<<<(unsigned)(((size_t)HRD*NN + 255)/256), 256, 0, stream>>>(gsr_w, P4a);
    gemmf32(stream, EPI_NONE, P4a, UfT, P4t1, HRD, NN, NN, nullptr, nullptr);               // a @ U^T
    gemmf32(stream, EPI_ABS_DIAG1, P4t1, out_net, out_adj, HRD, HRD, NN, nullptr, nullptr); // adj
    {
        dim3 g(HRD/32, HRD/32), b(256);
        transpose32_k<<<g, b, 0, stream>>>(out_adj, P4adT, HRD);                            // adj^T
    }
    gemmf32(stream, EPI_NONE, out_adj, P4adT, P4Zb, HRD, HRD, HRD, nullptr, nullptr);       // adj @ adj^T
    symabs1_k<<<(unsigned)(((size_t)HRD*HRD + 255)/256), 256, 0, stream>>>(P4Zb, HRD);      // Z
    gemmf32(stream, EPI_NONE, P4Zb, gc1, P4ZG, HRD, NN, HRD, nullptr, nullptr);             // Z @ gc1
    gemmf32(stream, EPI_RELU, out_adj, P4ZG, P4h1, HRD, NN, HRD, nullptr, nullptr);         // h1
    gemmf32(stream, EPI_NONE, P4h1, gc2, P4HG, HRD, HRD, NN, nullptr, nullptr);             // h1 @ gc2
    gemmf32(stream, EPI_RELU, out_adj, P4HG, P4h2, HRD, HRD, HRD, nullptr, nullptr);        // h2
    final_z_k<<<(unsigned)(((size_t)HRD*HRD + 255)/256), 256, 0, stream>>>(P4h2, out_z, HRD); // z
}

// Round 2
// 20533.212 us; speedup vs baseline: 1.1696x; 1.0171x over previous
//
#include <hip/hip_runtime.h>
#include <cstddef>
#include <cstdint>
#include <math.h>

// ============================ constants ============================
static constexpr int NN   = 1024;   // lr_dim
static constexpr int HRD  = 2048;   // hr_dim
static constexpr int DIMF = 320;
static constexpr int TB   = 85;     // sytrd LDS tail block (85x87 fp64 = 59 KB LDS)
static constexpr int CB3  = 128;    // persistent sytrd blocks (8 rows each)
static constexpr int BT3  = 1024;   // threads per sytrd block (16 waves)
static constexpr int NWY  = 16;     // WY reflector groups (64 each)

#define EPI_NONE      0
#define EPI_BIAS      1
#define EPI_BIAS_ADD  2
#define EPI_ABS_DIAG1 3
#define EPI_RELU      4

// agent-scope coherent access helpers (sc1): bypass stale per-XCD L2 without fences.
// Carries ONLY small cross-block traffic (P row, pvA, Rst pivot stage, barrier).
// Bulk trailing-matrix traffic is owner-private plain cached loads/stores.
__device__ __forceinline__ double gload(const double* p){
    return __hip_atomic_load(p, __ATOMIC_RELAXED, __HIP_MEMORY_SCOPE_AGENT);
}
__device__ __forceinline__ void gstore(double* p, double v){
    __hip_atomic_store(p, v, __ATOMIC_RELAXED, __HIP_MEMORY_SCOPE_AGENT);
}

// ============================ fp32 GEMM 64-tile (fallback, odd K) ============================
template<int EPI>
__global__ __launch_bounds__(256) void gemm32(
    const float* __restrict__ A, const float* __restrict__ B, float* __restrict__ C,
    int M, int N, int K, const float* __restrict__ bias, const float* __restrict__ D)
{
    __shared__ float As[16][65];
    __shared__ float Bs[16][65];
    const int bm = blockIdx.y << 6, bn = blockIdx.x << 6;
    const int tid = threadIdx.x;
    const int tm = (tid >> 4) << 2, tn = (tid & 15) << 2;
    float acc[4][4] = {};
    const int kt = (K + 15) >> 4;
    for (int k0 = 0; k0 < kt; ++k0){
        const int kb = k0 << 4;
        for (int t = tid; t < 1024; t += 256){
            int m = t >> 4, k = t & 15;
            int gm = bm + m, gk = kb + k;
            As[k][m] = (gm < M && gk < K) ? A[(size_t)gm*K + gk] : 0.f;
        }
        for (int t = tid; t < 1024; t += 256){
            int k = t >> 6, nn2 = t & 63;
            int gk = kb + k, gn = bn + nn2;
            Bs[k][nn2] = (gk < K && gn < N) ? B[(size_t)gk*N + gn] : 0.f;
        }
        __syncthreads();
        #pragma unroll
        for (int k = 0; k < 16; ++k){
            float a0 = As[k][tm], a1 = As[k][tm+1], a2 = As[k][tm+2], a3 = As[k][tm+3];
            float b0 = Bs[k][tn], b1 = Bs[k][tn+1], b2 = Bs[k][tn+2], b3 = Bs[k][tn+3];
            acc[0][0] += a0*b0; acc[0][1] += a0*b1; acc[0][2] += a0*b2; acc[0][3] += a0*b3;
            acc[1][0] += a1*b0; acc[1][1] += a1*b1; acc[1][2] += a1*b2; acc[1][3] += a1*b3;
            acc[2][0] += a2*b0; acc[2][1] += a2*b1; acc[2][2] += a2*b2; acc[2][3] += a2*b3;
            acc[3][0] += a3*b0; acc[3][1] += a3*b1; acc[3][2] += a3*b2; acc[3][3] += a3*b3;
        }
        __syncthreads();
    }
    #pragma unroll
    for (int r = 0; r < 4; ++r){
        int gm = bm + tm + r; if (gm >= M) continue;
        #pragma unroll
        for (int c = 0; c < 4; ++c){
            int gn = bn + tn + c; if (gn >= N) continue;
            float v = acc[r][c];
            if (EPI == EPI_BIAS)            v += bias[gn];
            else if (EPI == EPI_BIAS_ADD)   v += bias[gn] + D[(size_t)gm*N + gn];
            else if (EPI == EPI_ABS_DIAG1)  v = (gm == gn) ? 1.0f : fabsf(v);
            else if (EPI == EPI_RELU)       v = fmaxf(v, 0.0f);
            C[(size_t)gm*N + gn] = v;
        }
    }
}

// ============================ fp32 GEMM 128-tile (K%16==0, N%8==0) ============================
template<int EPI>
__global__ __launch_bounds__(256) void gemm128(
    const float* __restrict__ A, const float* __restrict__ B, float* __restrict__ C,
    int M, int N, int K, const float* __restrict__ bias, const float* __restrict__ D)
{
    __shared__ float As[16][132];
    __shared__ float Bs[16][132];
    const int bm = blockIdx.y << 7, bn = blockIdx.x << 7;
    const int tid = threadIdx.x;
    const int tm = (tid >> 4) << 3;
    const int tn = (tid & 15) << 3;
    const int ar = tid >> 1;
    const int ak = (tid & 1) << 3;
    const int br = tid >> 4;
    const int bc = (tid & 15) << 3;
    float acc[8][8] = {};
    for (int kb = 0; kb < K; kb += 16){
        {
            int gm = bm + ar, gk = kb + ak;
            float4 a0, a1;
            if (gm < M){
                const float* p = A + (size_t)gm*K + gk;
                a0 = *(const float4*)p; a1 = *(const float4*)(p + 4);
            } else { a0 = make_float4(0.f,0.f,0.f,0.f); a1 = a0; }
            As[ak+0][ar]=a0.x; As[ak+1][ar]=a0.y; As[ak+2][ar]=a0.z; As[ak+3][ar]=a0.w;
            As[ak+4][ar]=a1.x; As[ak+5][ar]=a1.y; As[ak+6][ar]=a1.z; As[ak+7][ar]=a1.w;
        }
        {
            int gk = kb + br, gn = bn + bc;
            float4 b0, b1;
            if (gn + 7 < N){
                const float* p = B + (size_t)gk*N + gn;
                b0 = *(const float4*)p; b1 = *(const float4*)(p + 4);
            } else {
                float t0[8];
                #pragma unroll
                for (int i = 0; i < 8; ++i){ int g = gn + i; t0[i] = (g < N) ? B[(size_t)gk*N + g] : 0.f; }
                b0 = make_float4(t0[0],t0[1],t0[2],t0[3]); b1 = make_float4(t0[4],t0[5],t0[6],t0[7]);
            }
            *(float4*)&Bs[br][bc] = b0; *(float4*)&Bs[br][bc+4] = b1;
        }
        __syncthreads();
        #pragma unroll
        for (int k = 0; k < 16; ++k){
            float4 a0 = *(const float4*)&As[k][tm];
            float4 a1 = *(const float4*)&As[k][tm+4];
            float4 b0 = *(const float4*)&Bs[k][tn];
            float4 b1 = *(const float4*)&Bs[k][tn+4];
            float av[8] = {a0.x,a0.y,a0.z,a0.w,a1.x,a1.y,a1.z,a1.w};
            float bv[8] = {b0.x,b0.y,b0.z,b0.w,b1.x,b1.y,b1.z,b1.w};
            #pragma unroll
            for (int i = 0; i < 8; ++i)
                #pragma unroll
                for (int jj = 0; jj < 8; ++jj) acc[i][jj] += av[i]*bv[jj];
        }
        __syncthreads();
    }
    #pragma unroll
    for (int i = 0; i < 8; ++i){
        int gm = bm + tm + i; if (gm >= M) continue;
        #pragma unroll
        for (int jj = 0; jj < 8; ++jj){
            int gn = bn + tn + jj; if (gn >= N) continue;
            float v = acc[i][jj];
            if (EPI == EPI_BIAS)            v += bias[gn];
            else if (EPI == EPI_BIAS_ADD)   v += bias[gn] + D[(size_t)gm*N + gn];
            else if (EPI == EPI_ABS_DIAG1)  v = (gm == gn) ? 1.0f : fabsf(v);
            else if (EPI == EPI_RELU)       v = fmaxf(v, 0.0f);
            C[(size_t)gm*N + gn] = v;
        }
    }
}

// ============================ small kernels ============================
__global__ __launch_bounds__(256) void rowsum_rsqrt_k(const float* __restrict__ lr, double* __restrict__ r64, int n)
{
    __shared__ double sm[256];
    int row = blockIdx.x;
    double s = 0.0;
    for (int j = threadIdx.x; j < n; j += 256) s += (double)lr[(size_t)row*n + j];
    sm[threadIdx.x] = s; __syncthreads();
    for (int o = 128; o; o >>= 1){ if (threadIdx.x < o) sm[threadIdx.x] += sm[threadIdx.x + o]; __syncthreads(); }
    if (threadIdx.x == 0){
        double t = sm[0];
        r64[row] = (t > 0.0) ? 1.0/sqrt(t) : 0.0;
    }
}

__global__ __launch_bounds__(256) void build_A_k(const float* __restrict__ lr, const double* __restrict__ r64,
                                                 float* __restrict__ A32, double* __restrict__ A64, int n)
{
    size_t idx = (size_t)blockIdx.x*256 + threadIdx.x;
    if (idx >= (size_t)n*n) return;
    int i = (int)(idx / n), j = (int)(idx % n);
    if (j < i) return;
    double v = (double)lr[(size_t)j*n + i] * r64[i] * r64[j];
    A64[(size_t)i*n + j] = v; A64[(size_t)j*n + i] = v;
    float vf = (float)v;
    A32[(size_t)i*n + j] = vf; A32[(size_t)j*n + i] = vf;
}

__global__ __launch_bounds__(256) void score_k(const float* __restrict__ X, const float* __restrict__ pw,
                                               const float* __restrict__ pb, float* __restrict__ out,
                                               int n, int dim)
{
    int row = blockIdx.x*4 + (threadIdx.x >> 6);
    int lane = threadIdx.x & 63;
    if (row >= n) return;
    float acc = 0.f;
    for (int c = lane; c < dim; c += 64) acc += X[(size_t)row*dim + c]*pw[c];
    #pragma unroll
    for (int o = 32; o; o >>= 1) acc += __shfl_down(acc, o);
    if (lane == 0){
        float t = (acc + pb[0]) * 0.01f;
        out[row] = 1.0f/(1.0f + expf(-t));
    }
}

// jax.lax.top_k semantics: descending value, ties -> lower index first
__global__ __launch_bounds__(256) void topk_k(const float* __restrict__ scores, int n, int k,
                                              int* __restrict__ idxo, float* __restrict__ valo)
{
    __shared__ float s[1024];
    int tid = threadIdx.x;
    for (int i = tid; i < n; i += 256) s[i] = scores[i];
    __syncthreads();
    for (int i = tid; i < n; i += 256){
        float si = s[i]; int r = 0;
        for (int j = 0; j < n; ++j){
            float sj = s[j];
            r += (sj > si) || (sj == si && j < i);
        }
        if (r < k){ idxo[r] = i; valo[r] = si; }
    }
}

__global__ __launch_bounds__(256) void gatherX_k(const float* __restrict__ X, const int* __restrict__ idx,
                                                 const float* __restrict__ vals, float* __restrict__ Xo,
                                                 int k, int dim)
{
    size_t t = (size_t)blockIdx.x*256 + threadIdx.x;
    if (t >= (size_t)k*dim) return;
    int m = (int)(t / dim), c = (int)(t % dim);
    Xo[t] = X[(size_t)idx[m]*dim + c] * vals[m];
}

__global__ __launch_bounds__(256) void scatterX_k(const float* __restrict__ Xs, const int* __restrict__ idx,
                                                  float* __restrict__ Xu, int k, int dim)
{
    size_t t = (size_t)blockIdx.x*256 + threadIdx.x;
    if (t >= (size_t)k*dim) return;
    int m = (int)(t / dim), c = (int)(t % dim);
    Xu[(size_t)idx[m]*dim + c] = Xs[t];
}

__global__ __launch_bounds__(256) void gatherA_k(const float* __restrict__ A, const int* __restrict__ idx,
                                                 float* __restrict__ Ao, int k, int n)
{
    size_t t = (size_t)blockIdx.x*256 + threadIdx.x;
    if (t >= (size_t)k*k) return;
    int m1 = (int)(t / k), m2 = (int)(t % k);
    Ao[t] = A[(size_t)idx[m1]*n + idx[m2]];
}

__global__ __launch_bounds__(256) void fill0_k(float* __restrict__ p, size_t cnt)
{
    size_t t = (size_t)blockIdx.x*256 + threadIdx.x;
    if (t < cnt) p[t] = 0.f;
}

__global__ __launch_bounds__(256) void filld0_k(double* __restrict__ p, size_t cnt)
{
    size_t t = (size_t)blockIdx.x*256 + threadIdx.x;
    if (t < cnt) p[t] = 0.0;
}

__global__ __launch_bounds__(256) void init_sytrd_k(double* __restrict__ pv, unsigned* __restrict__ bar, int n)
{
    int t = blockIdx.x*256 + threadIdx.x;
    if (t < n) pv[t] = 0.0;
    if (t < 1024) bar[t] = 0u;
}

__global__ __launch_bounds__(256) void concat_k(const float* __restrict__ X, const float* __restrict__ orgX,
                                                float* __restrict__ Xc, int n, int dim)
{
    size_t t = (size_t)blockIdx.x*256 + threadIdx.x;
    size_t tot = (size_t)n*2*dim;
    if (t >= tot) return;
    int i = (int)(t / (2*dim)), c = (int)(t % (2*dim));
    Xc[t] = (c < dim) ? X[(size_t)i*dim + c] : orgX[(size_t)i*dim + (c - dim)];
}

__global__ __launch_bounds__(256) void build_a_k(const float* __restrict__ gsr, float* __restrict__ a)
{
    size_t idx = (size_t)blockIdx.x*256 + threadIdx.x;
    if (idx >= (size_t)HRD*NN) return;
    int i = (int)(idx >> 10), k = (int)(idx & 1023);
    a[idx] = gsr[(size_t)i*HRD + k] + gsr[(size_t)i*HRD + NN + k];
}

__global__ __launch_bounds__(256) void symabs1_k(float* __restrict__ Z, int n)
{
    size_t idx = (size_t)blockIdx.x*256 + threadIdx.x;
    if (idx >= (size_t)n*n) return;
    int i = (int)(idx / n), j = (int)(idx % n);
    if (i > j) return;
    float a = Z[(size_t)i*n + j], b = Z[(size_t)j*n + i];
    float v = 0.5f*(a + b);
    float o = (i == j) ? 1.0f : fabsf(v);
    Z[(size_t)i*n + j] = o; Z[(size_t)j*n + i] = o;
}

__global__ __launch_bounds__(256) void final_z_k(const float* __restrict__ h2, float* __restrict__ z, int n)
{
    size_t idx = (size_t)blockIdx.x*256 + threadIdx.x;
    if (idx >= (size_t)n*n) return;
    int i = (int)(idx / n), j = (int)(idx % n);
    if (i > j) return;
    float v = 0.5f*(h2[(size_t)i*n + j] + h2[(size_t)j*n + i]);
    float o = (i == j) ? 1.0f : fabsf(v);
    z[(size_t)i*n + j] = o; z[(size_t)j*n + i] = o;
}

// dst[c][r] = (float)src[r][c]   (n x n, n % 32 == 0)
__global__ __launch_bounds__(256) void transpose_cast_k(const double* __restrict__ src, float* __restrict__ dst, int n)
{
    __shared__ float tile[32][33];
    int r0 = blockIdx.y*32, c0 = blockIdx.x*32;
    int tx = threadIdx.x & 31, ty = threadIdx.x >> 5;
    for (int i = ty; i < 32; i += 8)
        tile[i][tx] = (float)src[(size_t)(r0 + i)*n + (c0 + tx)];
    __syncthreads();
    for (int i = ty; i < 32; i += 8)
        dst[(size_t)(c0 + i)*n + (r0 + tx)] = tile[tx][i];
}

// dst[c][r] = src[r][c]  (n x n, n % 32 == 0)
__global__ __launch_bounds__(256) void transpose32_k(const float* __restrict__ src, float* __restrict__ dst, int n)
{
    __shared__ float tile[32][33];
    int r0 = blockIdx.y*32, c0 = blockIdx.x*32;
    int tx = threadIdx.x & 31, ty = threadIdx.x >> 5;
    for (int i = ty; i < 32; i += 8)
        tile[i][tx] = src[(size_t)(r0 + i)*n + (c0 + tx)];
    __syncthreads();
    for (int i = ty; i < 32; i += 8)
        dst[(size_t)(c0 + i)*n + (r0 + tx)] = tile[tx][i];
}

// ============================ persistent Householder tridiagonalization ============================
// sytrd_coop6: fixed row ownership (block bid owns rows [8bid, 8bid+8)), FUSED phase-A+pivot
// (single concurrent sc1-load round per column), dynamic block retirement (blocks exit after
// their last owned column; barrier targets are closed-form in j).
//
// Per column j (one global barrier):
//   fused pass:  per-thread i: VP[i]=VJold[i]*sc_p; WP[i]=tau_p*P[j-1][i]-c2_p*VP[i];
//                x=Rst[i]-WP[i]-wp0*VP[i] -> VJnew[i-1]; accumulate sigma2.  (P,Rst loads concurrent)
//   reduce:      wave shfl -> redA -> one __syncthreads -> every thread sums redA (broadcast).
//   phase B:     owner-private trailing row update (plain, L2-dirty) + matvec; row j+1 owner
//                publishes next pivot row to Rst (sc1); partial dots atomicAdd'd into P/pvA.
//   barrier:     group counter (16 blocks) -> central counter; targets cumG/cumC accumulate
//                active(j)=128-(j>>3) per group / ngact(j)=8-(j>>7) centrally.
__global__ __launch_bounds__(BT3) void sytrd_coop6(
    double* __restrict__ A, double* __restrict__ e, double* __restrict__ tauA,
    double* __restrict__ sclA, double* __restrict__ P, double* __restrict__ pvA,
    double* __restrict__ Rst, unsigned* __restrict__ bar, int n, int jend)
{
    __shared__ double VP[1024], WP[1024], VJ2[2][1024];
    __shared__ double redA[16], redB[16];
    const int tid   = threadIdx.x;
    const int bid   = blockIdx.x;
    const int lane  = tid & 63;
    const int wid   = tid >> 6;
    const int rwav  = wid >> 1;            // 0..7 row slot
    const int half  = wid & 1;             // half-row (2 waves per row)
    const int u     = (bid << 3) + rwav;   // owned physical row
    const int g     = bid >> 4;            // barrier group (8 groups x 16 blocks)
    const int mylast = (bid << 3) + 7;     // last column this block participates in

    double tau_p = 0.0, sc_p = 0.0;
    unsigned cumG = 0, cumC = 0;

    for (int j = 0; j < jend; ++j){
        const int m = n - 1 - j;
        double* __restrict__ VJnew = VJ2[j & 1];
        const double* __restrict__ VJold = VJ2[(j & 1) ^ 1];

        // barrier bookkeeping (pure function of j; all alive blocks agree)
        {
            const int retired = j >> 3;
            int d = retired - (g << 4);
            d = (d < 0) ? 0 : (d > 16 ? 16 : d);
            cumG += (unsigned)(16 - d);
            cumC += (unsigned)(8 - (j >> 7));
        }

        // ---- fused phase A + pivot row (one sc1 round) ----
        double s = 0.0, wp0 = 0.0;
        if (j > 0){
            const double* __restrict__ Prow = P + (size_t)(j-1)*NN;
            const double* __restrict__ rs   = Rst + ((size_t)(j & 1) << 10);
            const double pv_prev = gload(&pvA[j-1]);
            const double p0      = gload(&Prow[0]);
            const double c2_p = 0.5*tau_p*tau_p*pv_prev;
            wp0 = tau_p*p0 - c2_p;
            if (tid == 0){ VP[0] = 1.0; WP[0] = wp0; }
            if (tid >= 1 && tid <= m){
                double pi  = gload(&Prow[tid]);
                double rsi = gload(&rs[tid]);
                double vp  = VJold[tid]*sc_p;
                double wp  = tau_p*pi - c2_p*vp;
                VP[tid] = vp; WP[tid] = wp;
                double x = rsi - wp - wp0*vp;
                VJnew[tid-1] = x;
                if (tid >= 2) s += x*x;
            }
        } else {
            if (tid < m){
                double x = A[1 + tid];   // row 0, fresh from build_A_k
                VJnew[tid] = x;
                if (tid >= 1) s += x*x;
            }
        }
        #pragma unroll
        for (int o = 32; o; o >>= 1) s += __shfl_down(s, o);
        if (lane == 0) redA[wid] = s;
        __syncthreads();     // VP/WP/VJnew visible + redA ready

        double sigma2 = 0.0;
        #pragma unroll
        for (int i = 0; i < 16; ++i) sigma2 += redA[i];
        double alpha = VJnew[0];
        double beta, tl, sc;
        if (sigma2 == 0.0){ beta = alpha; tl = 0.0; sc = 0.0; }
        else {
            beta = -copysign(sqrt(alpha*alpha + sigma2), alpha);
            tl = (beta - alpha)/beta;
            sc = 1.0/(alpha - beta);
        }

        // ---- owner-block writeback of row j (plain stores, own L2 lines) ----
        if (bid == (j >> 3)){
            double* __restrict__ row = A + (size_t)j*n + (j+1);
            if (tid < m) row[tid] = VJnew[tid];
            if (tid == 0){
                e[j] = beta; tauA[j] = tl; sclA[j] = sc;
                if (j > 0) A[(size_t)j*n + j] -= 2.0*wp0;
            }
        }

        // ---- phase B: owner-private trailing update + matvec; publish next pivot row ----
        double pvloc = 0.0;
        if (u > j){
            const int r = u - (j+1);
            double* __restrict__ Ar   = A + (size_t)u*n + (j+1);
            double* __restrict__ rs_w = Rst + ((size_t)((j+1) & 1) << 10);
            const bool pub = (r == 0);
            double acc = 0.0;
            if (j > 0){
                double vpr = VP[1+r], wpr = WP[1+r];
                for (int c = half*64 + lane; c < m; c += 128){
                    double a = Ar[c] - (vpr*WP[1+c] + wpr*VP[1+c]);
                    Ar[c] = a;
                    if (pub) gstore(&rs_w[c], a);
                    double vj = (c == 0) ? 1.0 : VJnew[c]*sc;
                    acc += a*vj;
                }
            } else {
                for (int c = half*64 + lane; c < m; c += 128){
                    double a = Ar[c];
                    if (pub) gstore(&rs_w[c], a);
                    double vj = (c == 0) ? 1.0 : VJnew[c]*sc;
                    acc += a*vj;
                }
            }
            #pragma unroll
            for (int o = 32; o; o >>= 1) acc += __shfl_down(acc, o);
            if (lane == 0){
                atomicAdd(&P[(size_t)j*NN + r], acc);   // partial (half-row)
                double vr = (r == 0) ? 1.0 : VJnew[r]*sc;
                pvloc = acc*vr;
            }
        }
        if (lane == 0) redB[wid] = pvloc;
        __syncthreads();     // redB ready + ALL waves' phase-B global ops drained (vmcnt(0) pre-barrier)

        if (tid == 0){
            double t2 = 0.0;
            #pragma unroll
            for (int i = 0; i < 16; ++i) t2 += redB[i];
            if (t2 != 0.0) atomicAdd(&pvA[j], t2);
            asm volatile("s_waitcnt vmcnt(0)" ::: "memory");   // pvA add complete before arrival
            unsigned t = __hip_atomic_fetch_add(&bar[g*32], 1u, __ATOMIC_RELAXED, __HIP_MEMORY_SCOPE_AGENT);
            if (t == cumG - 1u)
                __hip_atomic_fetch_add(&bar[256], 1u, __ATOMIC_RELAXED, __HIP_MEMORY_SCOPE_AGENT);
            if (j != mylast){
                while (__hip_atomic_load(&bar[256], __ATOMIC_RELAXED, __HIP_MEMORY_SCOPE_AGENT) < cumC)
                    __builtin_amdgcn_s_sleep(1);
            }
        }
        if (j == mylast) break;    // retired: all owned rows finalized; exit (uniform)
        __syncthreads();           // release after spin
        tau_p = tl; sc_p = sc;
    }

    // ---- apply final pending update (column jend-1) on the TB x TB tail, owner-only ----
    // Only blocks with mylast >= jend reach here un-broken with live state (bids 117..127).
    if (u >= jend){
        const int tb = n - jend;
        const double* __restrict__ VJf = VJ2[(jend-1) & 1];
        const double* __restrict__ pp  = P + (size_t)(jend-1)*NN;
        double c2f = 0.5*tau_p*tau_p*gload(&pvA[jend-1]);
        const int ri = u - jend;
        double vpr = (ri == 0) ? 1.0 : VJf[ri]*sc_p;
        double wpr = tau_p*gload(&pp[ri]) - c2f*vpr;
        double* __restrict__ Ar = A + (size_t)u*n + jend;
        for (int ci = half*64 + lane; ci < tb; ci += 128){
            double vpc = (ci == 0) ? 1.0 : VJf[ci]*sc_p;
            double wpc = tau_p*gload(&pp[ci]) - c2f*vpc;
            Ar[ci] -= vpr*wpc + wpr*vpc;
        }
    }
}

// Tail: remaining (TB-2) Householder steps entirely in LDS (single block).
__global__ __launch_bounds__(256) void hh_tail(double* __restrict__ A64, double* __restrict__ e,
                                               double* __restrict__ tau, double* __restrict__ scaleg, int n)
{
    __shared__ double T[TB][TB+2];
    __shared__ double v[TB], p[TB], red[256];
    const int base = n - TB;
    const int tid = threadIdx.x;
    for (int t = tid; t < TB*TB; t += 256){
        int r = t / TB, c = t % TB;
        T[r][c] = A64[(size_t)(base + r)*n + base + c];
    }
    __syncthreads();
    for (int l = 0; l <= TB - 3; ++l){
        const int m = TB - 1 - l;
        double s = 0.0;
        for (int i = 1 + tid; i < m; i += 256){ double x = T[l+1+i][l]; s += x*x; }
        red[tid] = s; __syncthreads();
        for (int o = 128; o; o >>= 1){ if (tid < o) red[tid] += red[tid + o]; __syncthreads(); }
        double sigma2 = red[0];
        double alpha = T[l+1][l];
        double beta, tl, sc;
        if (sigma2 == 0.0){ beta = alpha; tl = 0.0; sc = 0.0; }
        else {
            beta = -copysign(sqrt(alpha*alpha + sigma2), alpha);
            tl = (beta - alpha)/beta;
            sc = 1.0/(alpha - beta);
        }
        for (int i = tid; i < m; i += 256) v[i] = (i == 0) ? 1.0 : T[l+1+i][l]*sc;
        __syncthreads();
        for (int i = tid; i < m; i += 256){
            double acc = 0.0;
            for (int c = 0; c < m; ++c) acc += T[l+1+i][l+1+c]*v[c];
            p[i] = acc;
        }
        __syncthreads();
        double s2 = 0.0;
        for (int i = tid; i < m; i += 256) s2 += p[i]*v[i];
        red[tid] = s2; __syncthreads();
        for (int o = 128; o; o >>= 1){ if (tid < o) red[tid] += red[tid + o]; __syncthreads(); }
        double pvv = red[0];
        double c2 = 0.5*tl*tl*pvv;
        for (int t2 = tid; t2 < m*m; t2 += 256){
            int r = t2 / m, c = t2 % m;
            double wr = tl*p[r] - c2*v[r];
            double wc = tl*p[c] - c2*v[c];
            T[l+1+r][l+1+c] -= v[r]*wc + wr*v[c];
        }
        if (tid == 0){ int j = base + l; e[j] = beta; tau[j] = tl; scaleg[j] = 1.0; }
        for (int i = tid; i < m; i += 256) A64[(size_t)(base + l)*n + (base + l + 1) + i] = v[i];
        __syncthreads();
    }
    for (int r = tid; r < TB; r += 256) A64[(size_t)(base + r)*n + base + r] = T[r][r];
    if (tid == 0) A64[(size_t)(n-1)*n + (n-2)] = T[TB-1][TB-2];
}

__global__ __launch_bounds__(256) void extract_de_k(const double* __restrict__ A64, double* __restrict__ d,
                                                    double* __restrict__ e, int n)
{
    int i = blockIdx.x*256 + threadIdx.x;
    if (i < n) d[i] = A64[(size_t)i*n + i];
    if (i == 0) e[n-2] = A64[(size_t)(n-1)*n + (n-2)];
}

// ============================ tridiagonal eigensolver ============================
// Multiplication-form Sturm count (no division in the dependent chain):
//   p_i = (d_i - x) p_{i-1} - e_{i-1}^2 p_{i-2};  q_i = p_i/p_{i-1};
//   count = #{i : q_i < 0} = # sign changes; pair-rescaled to avoid under/overflow.
__global__ __launch_bounds__(256) void bisect_k(const double* __restrict__ d, const double* __restrict__ e,
                                                double* __restrict__ w, int n)
{
    __shared__ double ds[1024], e2s[1024];
    const int tid = threadIdx.x;
    for (int i = tid; i < n; i += 256) ds[i] = d[i];
    for (int i = tid; i < n-1; i += 256){ double ei = e[i]; e2s[i] = ei*ei; }
    __syncthreads();
    int k = blockIdx.x*256 + tid;
    if (k >= n) return;
    double gl = 1e300, gu = -1e300;
    for (int i = 0; i < n; ++i){
        double em = (i > 0) ? sqrt(e2s[i-1]) : 0.0, ep2 = (i < n-1) ? sqrt(e2s[i]) : 0.0;
        double lo2 = ds[i] - em - ep2, hi2 = ds[i] + em + ep2;
        gl = fmin(gl, lo2); gu = fmax(gu, hi2);
    }
    double lo = gl - 1e-10, hi = gu + 1e-10;
    for (int it = 0; it < 42; ++it){
        double mid = 0.5*(lo + hi);
        int cnt = 0;
        double p0 = 1.0;
        double p1 = ds[0] - mid;
        if (p1 <= 0.0){ ++cnt; if (p1 == 0.0) p1 = -1e-300; }
        for (int i = 1; i < n; ++i){
            double pn = (ds[i] - mid)*p1 - e2s[i-1]*p0;
            bool neg = ((pn < 0.0) != (p1 < 0.0)) || (pn == 0.0);
            cnt += neg;
            if (pn == 0.0) pn = (p1 > 0.0) ? -1e-300 : 1e-300;
            p0 = p1; p1 = pn;
            double ap = fabs(p1);
            if (ap > 1e120){ p1 *= 1e-200; p0 *= 1e-200; }
            else if (ap < 1e-120){ p1 *= 1e200; p0 *= 1e200; }
        }
        if (cnt <= k) lo = mid; else hi = mid;
    }
    w[k] = 0.5*(lo + hi);
}

__global__ __launch_bounds__(256) void invit_k(const double* __restrict__ d, const double* __restrict__ e,
                                               const double* __restrict__ w,
                                               double* __restrict__ FD, double* __restrict__ FL,
                                               double* __restrict__ FU, double* __restrict__ FU2,
                                               signed char* __restrict__ PIV, double* __restrict__ Z, int n)
{
    int k = blockIdx.x*256 + threadIdx.x;
    if (k >= n) return;
    const double lam = w[k];
    const double tiny = 1e-280;
    double dcur = d[0] - lam;
    double ucur = e[0];
    for (int i = 0; i < n-1; ++i){
        double dli = e[i];
        double dnext_init = d[i+1] - lam;
        double unext_init = (i < n-2) ? e[i+1] : 0.0;
        size_t o = (size_t)i*n + k;
        if (fabs(dcur) >= fabs(dli)){
            if (dcur == 0.0) dcur = tiny;
            double f = dli/dcur;
            FD[o] = dcur; FL[o] = f; FU[o] = ucur; FU2[o] = 0.0; PIV[o] = 0;
            dcur = dnext_init - f*ucur;
            ucur = unext_init;
        } else {
            double f = dcur/dli;
            FD[o] = dli; FL[o] = f; FU[o] = dnext_init; FU2[o] = unext_init; PIV[o] = 1;
            dcur = ucur - f*dnext_init;
            ucur = -f*unext_init;
        }
    }
    if (dcur == 0.0) dcur = tiny;
    FD[(size_t)(n-1)*n + k] = dcur;
    for (int i = 0; i < n; ++i){
        unsigned h = (unsigned)(i + 1)*0x9E3779B9u + (unsigned)(k + 1)*0x85EBCA6Bu;
        h ^= h >> 16; h *= 0x7FEB352Du; h ^= h >> 15; h *= 0x846CA68Bu; h ^= h >> 16;
        Z[(size_t)i*n + k] = (double)(h >> 8)*(1.0/16777216.0) - 0.5;
    }
    for (int iter = 0; iter < 2; ++iter){
        double zc = Z[k];
        for (int i = 0; i < n-1; ++i){
            size_t o = (size_t)i*n + k;
            double fl = FL[o];
            double zn = Z[o + n];
            if (!PIV[o]){
                Z[o] = zc;
                zc = zn - fl*zc;
            } else {
                Z[o] = zn;
                zc = zc - fl*zn;
            }
        }
        double za = zc / FD[(size_t)(n-1)*n + k];
        Z[(size_t)(n-1)*n + k] = za;
        size_t o2 = (size_t)(n-2)*n + k;
        double zaa = (Z[o2] - FU[o2]*za) / FD[o2];
        Z[o2] = zaa;
        double zb = za;
        for (int i = n-3; i >= 0; --i){
            size_t o = (size_t)i*n + k;
            double znew = (Z[o] - FU[o]*zaa - FU2[o]*zb) / FD[o];
            Z[o] = znew;
            zb = zaa; zaa = znew;
        }
        double mx = 0.0;
        for (int i = 0; i < n; ++i) mx = fmax(mx, fabs(Z[(size_t)i*n + k]));
        double s = (mx > 0.0) ? 1.0/mx : 1.0;
        for (int i = 0; i < n; ++i) Z[(size_t)i*n + k] *= s;
    }
    double nrm = 0.0;
    for (int i = 0; i < n; ++i){ double v = Z[(size_t)i*n + k]; nrm += v*v; }
    double s = 1.0/sqrt(nrm);
    for (int i = 0; i < n; ++i) Z[(size_t)i*n + k] *= s;
}

// ============================ batched blocked-WY back-transform ============================
__global__ __launch_bounds__(256) void wy_buildV_k(const double* __restrict__ A64, const double* __restrict__ scaleg,
                                                   double* __restrict__ Vbig, int n)
{
    size_t idx = (size_t)blockIdx.x*256 + threadIdx.x;
    if (idx >= (size_t)NWY*1024*64) return;
    int g = (int)(idx >> 16);
    int r = (int)((idx >> 6) & 1023);
    int t = (int)(idx & 63);
    int b0 = g*64;
    int nbsz = (n - 2) - b0; if (nbsz > 64) nbsz = 64;
    double v = 0.0;
    if (t < nbsz){
        int j = b0 + t;
        if (r == j + 1) v = 1.0;
        else if (r > j + 1) v = A64[(size_t)j*n + r]*scaleg[j];
    }
    Vbig[idx] = v;
}

__global__ __launch_bounds__(256) void wy_buildT_k(const double* __restrict__ Vbig, const double* __restrict__ tau,
                                                   double* __restrict__ Tbig, int n)
{
    __shared__ double G[64][65];
    __shared__ double Ts[64][65];
    __shared__ double Vs[32][65];
    const int g = blockIdx.x;
    const int tid = threadIdx.x;
    const double* __restrict__ V = Vbig + ((size_t)g << 16);
    const int b0 = g*64;
    int nbsz = (n - 2) - b0; if (nbsz > 64) nbsz = 64;
    for (int p = tid; p < 64*64; p += 256) G[p >> 6][p & 63] = 0.0;
    __syncthreads();
    for (int rb = b0; rb < n; rb += 32){
        for (int s = tid; s < 2048; s += 256){
            int rr = s >> 6, tt = s & 63;
            Vs[rr][tt] = V[((size_t)(rb + rr) << 6) + tt];
        }
        __syncthreads();
        for (int p = tid; p < 4096; p += 256){
            int t = p >> 6, s2 = p & 63;
            if (t < s2 && s2 < nbsz){
                double acc = 0.0;
                #pragma unroll 8
                for (int rr = 0; rr < 32; ++rr) acc += Vs[rr][t]*Vs[rr][s2];
                G[t][s2] += acc;
            }
        }
        __syncthreads();
    }
    for (int t = nbsz - 1; t >= 0; --t){
        for (int u = tid; u < 64; u += 256){
            double val = 0.0;
            if (u == t) val = tau[b0 + t];
            else if (u > t && u < nbsz){
                double s = 0.0;
                for (int s2 = t + 1; s2 <= u; ++s2) s += G[t][s2]*Ts[s2][u];
                val = -tau[b0 + t]*s;
            }
            Ts[t][u] = val;
        }
        __syncthreads();
    }
    for (int p = tid; p < 64*64; p += 256){
        int t = p >> 6, u = p & 63;
        Tbig[((size_t)g << 12) + p] = (t < nbsz) ? Ts[t][u] : 0.0;
    }
}

__global__ __launch_bounds__(256) void wy_apply_k(const double* __restrict__ Vbig, const double* __restrict__ Tbig,
                                                  double* __restrict__ Z, int n)
{
    __shared__ double Vs[32][65];
    __shared__ double Zs[32][17];
    __shared__ double Y[64][17];
    __shared__ double W[64][17];
    const int tid = threadIdx.x;
    const int c   = tid & 15;
    const int tq  = tid >> 4;
    const int c0  = blockIdx.x * 16;

    for (int g = NWY - 1; g >= 0; --g){
        const double* __restrict__ V = Vbig + ((size_t)g << 16);
        const double* __restrict__ T = Tbig + ((size_t)g << 12);
        const int b0 = g*64;
        double acc0 = 0.0, acc1 = 0.0, acc2 = 0.0, acc3 = 0.0;
        for (int rb = b0; rb < n; rb += 32){
            for (int s = tid; s < 2048; s += 256){
                int rr = s >> 6, tt = s & 63;
                Vs[rr][tt] = V[((size_t)(rb + rr) << 6) + tt];
            }
            for (int s = tid; s < 512; s += 256){
                int rr = s >> 4, cc = s & 15;
                Zs[rr][cc] = Z[(size_t)(rb + rr)*n + c0 + cc];
            }
            __syncthreads();
            #pragma unroll 8
            for (int rr = 0; rr < 32; ++rr){
                double z = Zs[rr][c];
                acc0 += Vs[rr][tq*4+0]*z;
                acc1 += Vs[rr][tq*4+1]*z;
                acc2 += Vs[rr][tq*4+2]*z;
                acc3 += Vs[rr][tq*4+3]*z;
            }
            __syncthreads();
        }
        Y[tq*4+0][c] = acc0; Y[tq*4+1][c] = acc1; Y[tq*4+2][c] = acc2; Y[tq*4+3][c] = acc3;
        __syncthreads();
        #pragma unroll
        for (int i = 0; i < 4; ++i){
            int t = tq*4 + i;
            double a = 0.0;
            for (int s = t; s < 64; ++s) a += T[(t << 6) + s]*Y[s][c];
            W[t][c] = a;
        }
        __syncthreads();
        for (int rb = b0; rb < n; rb += 32){
            for (int s = tid; s < 2048; s += 256){
                int rr = s >> 6, tt = s & 63;
                Vs[rr][tt] = V[((size_t)(rb + rr) << 6) + tt];
            }
            __syncthreads();
            #pragma unroll
            for (int half = 0; half < 2; ++half){
                int item = tid + half*256;
                int rr = item >> 4, cc = item & 15;
                double s = 0.0;
                #pragma unroll 16
                for (int t = 0; t < 64; ++t) s += Vs[rr][t]*W[t][cc];
                Z[(size_t)(rb + rr)*n + c0 + cc] -= s;
            }
            __syncthreads();
        }
        __syncthreads();
    }
}

// ============================ host dispatch helpers ============================
static void gemmf32(hipStream_t st, int epi,
                    const float* A, const float* B, float* C, int M, int N, int K,
                    const float* bias, const float* D)
{
    if ((K & 15) == 0 && (N & 7) == 0){
        dim3 g((N + 127)/128, (M + 127)/128), b(256);
        switch (epi){
        case EPI_NONE:      gemm128<EPI_NONE><<<g, b, 0, st>>>(A, B, C, M, N, K, bias, D); break;
        case EPI_BIAS:      gemm128<EPI_BIAS><<<g, b, 0, st>>>(A, B, C, M, N, K, bias, D); break;
        case EPI_BIAS_ADD:  gemm128<EPI_BIAS_ADD><<<g, b, 0, st>>>(A, B, C, M, N, K, bias, D); break;
        case EPI_ABS_DIAG1: gemm128<EPI_ABS_DIAG1><<<g, b, 0, st>>>(A, B, C, M, N, K, bias, D); break;
        case EPI_RELU:      gemm128<EPI_RELU><<<g, b, 0, st>>>(A, B, C, M, N, K, bias, D); break;
        }
    } else {
        dim3 g((N + 63)/64, (M + 63)/64), b(256);
        switch (epi){
        case EPI_NONE:      gemm32<EPI_NONE><<<g, b, 0, st>>>(A, B, C, M, N, K, bias, D); break;
        case EPI_BIAS:      gemm32<EPI_BIAS><<<g, b, 0, st>>>(A, B, C, M, N, K, bias, D); break;
        case EPI_BIAS_ADD:  gemm32<EPI_BIAS_ADD><<<g, b, 0, st>>>(A, B, C, M, N, K, bias, D); break;
        case EPI_ABS_DIAG1: gemm32<EPI_ABS_DIAG1><<<g, b, 0, st>>>(A, B, C, M, N, K, bias, D); break;
        case EPI_RELU:      gemm32<EPI_RELU><<<g, b, 0, st>>>(A, B, C, M, N, K, bias, D); break;
        }
    }
}

// ============================ kernel_launch ============================
extern "C" void kernel_launch(void* const* d_in, const int* in_sizes, int n_in,
                              void* d_out, int out_size, void* d_ws, size_t ws_size,
                              hipStream_t stream)
{
    (void)in_sizes; (void)n_in; (void)out_size; (void)ws_size;
    const float* lr       = (const float*)d_in[0];
    const float* gsr_w    = (const float*)d_in[1];
    const float* start_w  = (const float*)d_in[2];
    const float* start_b  = (const float*)d_in[3];
    const float* down_w   = (const float*)d_in[4];
    const float* down_b   = (const float*)d_in[5];
    const float* pool_w   = (const float*)d_in[6];
    const float* pool_b   = (const float*)d_in[7];
    const float* bottom_w = (const float*)d_in[8];
    const float* bottom_b = (const float*)d_in[9];
    const float* end_w    = (const float*)d_in[10];
    const float* end_b    = (const float*)d_in[11];
    const float* up_w     = (const float*)d_in[12];
    const float* up_b     = (const float*)d_in[13];
    const float* gc1      = (const float*)d_in[14];
    const float* gc2      = (const float*)d_in[15];

    float* out_z     = (float*)d_out;                       // [2048,2048]
    float* out_net   = out_z + (size_t)HRD*HRD;             // [1024,2048]
    float* out_start = out_net + (size_t)NN*HRD;            // [1024,320]
    float* out_adj   = out_start + (size_t)NN*DIMF;         // [2048,2048]

    static const int LVL_N[4] = {1024, 921, 644, 386};
    static const int LVL_K[4] = {921, 644, 386, 193};

    // -------- workspace arena --------
    char* Wb = (char*)d_ws;
    size_t off = 0;
    auto alloc = [&](size_t bb)->char*{ char* p = Wb + off; off = (off + bb + 255) & ~(size_t)255; return p; };

    float*  A32  = (float*) alloc((size_t)NN*NN*4);
    double* A64  = (double*)alloc((size_t)NN*NN*8);
    float*  UfT  = (float*) alloc((size_t)NN*NN*4);   // U^T as [k][j] fp32
    double* r64  = (double*)alloc(NN*8);
    double* dD   = (double*)alloc(NN*8);
    double* dE   = (double*)alloc(NN*8);
    double* dTau = (double*)alloc(NN*8);
    double* dScl = (double*)alloc(NN*8);
    double* dWev = (double*)alloc(NN*8);
    double* pvA  = (double*)alloc(NN*8);
    double* Rst  = (double*)alloc((size_t)2*NN*8);    // double-buffered pivot-row stage (sc1)
    unsigned* barcnt = (unsigned*)alloc(8192);
    char* SBASE = Wb + off;

    // P2 overlay (U-Net)
    size_t so = 0;
    auto salloc = [&](size_t bb)->char*{ char* p = SBASE + so; so = (so + bb + 255) & ~(size_t)255; return p; };
    float* XT  = (float*)salloc((size_t)NN*DIMF*4);
    float* XP1 = (float*)salloc((size_t)NN*DIMF*4);
    float* XP2 = (float*)salloc((size_t)NN*DIMF*4);
    float* XU  = (float*)salloc((size_t)NN*DIMF*4);
    float* DN[4]; for (int l = 0; l < 4; ++l) DN[l] = (float*)salloc((size_t)NN*DIMF*4);
    float* Asub[4];
    for (int l = 0; l < 4; ++l) Asub[l] = (float*)salloc((size_t)LVL_K[l]*LVL_K[l]*4);
    float* SC = (float*)salloc(NN*4);
    int*   IDX[4]; for (int l = 0; l < 4; ++l) IDX[l] = (int*)salloc(NN*4);
    float* VAL[4]; for (int l = 0; l < 4; ++l) VAL[l] = (float*)salloc(NN*4);
    float* XC  = (float*)salloc((size_t)NN*2*DIMF*4);
    float* AXC = (float*)salloc((size_t)NN*2*DIMF*4);

    // P3 overlay (eigensolver scratch)
    const size_t PL = (size_t)NN*NN*8;
    double* Z64 = (double*)(SBASE);
    double* FD  = (double*)(SBASE + PL);       // doubles as Pmat during sytrd, Vbig during WY
    double* FL  = (double*)(SBASE + 2*PL);     // doubles as Tbig during WY
    double* FU  = (double*)(SBASE + 3*PL);
    double* FU2 = (double*)(SBASE + 4*PL);
    signed char* FPIV = (signed char*)(SBASE + 5*PL);
    double* Pmat = FD;
    double* Vbig = FD;
    double* Tbig = FL;

    // P4 overlay (GSR / refinement)
    const size_t MB8  = (size_t)HRD*NN*4;    // 8 MiB
    const size_t MB16 = (size_t)HRD*HRD*4;   // 16 MiB
    float* P4a   = (float*)(SBASE);
    float* P4t1  = (float*)(SBASE + MB8);
    float* P4adT = (float*)(SBASE);
    float* P4Zb  = (float*)(SBASE + MB16);
    float* P4ZG  = (float*)(SBASE);
    float* P4h1  = (float*)(SBASE + MB8);
    float* P4HG  = (float*)(SBASE + MB16);
    float* P4h2  = (float*)(SBASE);

    // =============== P1: normalized adjacency ===============
    rowsum_rsqrt_k<<<NN, 256, 0, stream>>>(lr, r64, NN);
    build_A_k<<<(NN*NN + 255)/256, 256, 0, stream>>>(lr, r64, A32, A64, NN);

    // =============== P2: graph U-Net (fp32) ===============
    gemmf32(stream, EPI_BIAS, A32, start_w, out_start, NN, DIMF, NN, start_b, nullptr);

    const float* Xcur = out_start;
    const float* Acur = A32;
    float* ping = XP1; float* pong = XP2;
    for (int l = 0; l < 4; ++l){
        int nl = LVL_N[l], kl = LVL_K[l];
        gemmf32(stream, EPI_NONE, Acur, Xcur, XT, nl, DIMF, nl, nullptr, nullptr);
        gemmf32(stream, EPI_BIAS, XT, down_w + (size_t)l*DIMF*DIMF, DN[l], nl, DIMF, DIMF,
                down_b + (size_t)l*DIMF, nullptr);
        score_k<<<(nl + 3)/4, 256, 0, stream>>>(DN[l], pool_w + (size_t)l*DIMF, pool_b + l, SC, nl, DIMF);
        topk_k<<<1, 256, 0, stream>>>(SC, nl, kl, IDX[l], VAL[l]);
        gatherX_k<<<(unsigned)(((size_t)kl*DIMF + 255)/256), 256, 0, stream>>>(DN[l], IDX[l], VAL[l], ping, kl, DIMF);
        gatherA_k<<<(unsigned)(((size_t)kl*kl + 255)/256), 256, 0, stream>>>(Acur, IDX[l], Asub[l], kl, nl);
        Xcur = ping; Acur = Asub[l];
        float* t = ping; ping = pong; pong = t;
    }
    gemmf32(stream, EPI_NONE, Acur, Xcur, XT, 193, DIMF, 193, nullptr, nullptr);
    float* Xb = ping;
    gemmf32(stream, EPI_BIAS, XT, bottom_w, Xb, 193, DIMF, DIMF, bottom_b, nullptr);
    const float* Xup = Xb;
    float* upbuf[2] = { (Xb == XP1) ? XP2 : XP1, (Xb == XP1) ? XP1 : XP2 };
    for (int i2 = 0; i2 < 4; ++i2){
        int jl = 3 - i2;
        int nj = LVL_N[jl];
        int kj = LVL_K[jl];
        fill0_k<<<(unsigned)(((size_t)nj*DIMF + 255)/256), 256, 0, stream>>>(XU, (size_t)nj*DIMF);
        scatterX_k<<<(unsigned)(((size_t)kj*DIMF + 255)/256), 256, 0, stream>>>(Xup, IDX[jl], XU, kj, DIMF);
        const float* Aj = (jl == 0) ? A32 : Asub[jl - 1];
        gemmf32(stream, EPI_NONE, Aj, XU, XT, nj, DIMF, nj, nullptr, nullptr);
        float* Xn = upbuf[i2 & 1];
        gemmf32(stream, EPI_BIAS_ADD, XT, up_w + (size_t)i2*DIMF*DIMF, Xn, nj, DIMF, DIMF,
                up_b + (size_t)i2*DIMF, DN[jl]);
        Xup = Xn;
    }
    concat_k<<<(unsigned)(((size_t)NN*2*DIMF + 255)/256), 256, 0, stream>>>(Xup, out_start, XC, NN, DIMF);
    gemmf32(stream, EPI_NONE, A32, XC, AXC, NN, 2*DIMF, NN, nullptr, nullptr);
    gemmf32(stream, EPI_BIAS, AXC, end_w, out_net, NN, HRD, 2*DIMF, end_b, nullptr);

    // =============== P3: eigendecomposition of A (fp64) ===============
    const int JEND = NN - TB;
    init_sytrd_k<<<4, 256, 0, stream>>>(pvA, barcnt, NN);
    filld0_k<<<(unsigned)(((size_t)JEND*NN + 255)/256), 256, 0, stream>>>(Pmat, (size_t)JEND*NN);
    sytrd_coop6<<<CB3, BT3, 0, stream>>>(A64, dE, dTau, dScl, Pmat, pvA, Rst, barcnt, NN, JEND);
    hh_tail<<<1, 256, 0, stream>>>(A64, dE, dTau, dScl, NN);
    extract_de_k<<<4, 256, 0, stream>>>(A64, dD, dE, NN);
    bisect_k<<<4, 256, 0, stream>>>(dD, dE, dWev, NN);
    invit_k<<<4, 256, 0, stream>>>(dD, dE, dWev, FD, FL, FU, FU2, FPIV, Z64, NN);
    wy_buildV_k<<<(unsigned)(((size_t)NWY*1024*64 + 255)/256), 256, 0, stream>>>(A64, dScl, Vbig, NN);
    wy_buildT_k<<<NWY, 256, 0, stream>>>(Vbig, dTau, Tbig, NN);
    wy_apply_k<<<NN/16, 256, 0, stream>>>(Vbig, Tbig, Z64, NN);
    {
        dim3 g(NN/32, NN/32), b(256);
        transpose_cast_k<<<g, b, 0, stream>>>(Z64, UfT, NN);
    }

    // =============== P4: GSR layer + refinement (fp32) ===============
    build_a_k<<<(unsigned)(((size_t)HRD*NN + 255)/256), 256, 0, stream>>>(gsr_w, P4a);
    gemmf32(stream, EPI_NONE, P4a, UfT, P4t1, HRD, NN, NN, nullptr, nullptr);               // a @ U^T
    gemmf32(stream, EPI_ABS_DIAG1, P4t1, out_net, out_adj, HRD, HRD, NN, nullptr, nullptr); // adj
    {
        dim3 g(HRD/32, HRD/32), b(256);
        transpose32_k<<<g, b, 0, stream>>>(out_adj, P4adT, HRD);                            // adj^T
    }
    gemmf32(stream, EPI_NONE, out_adj, P4adT, P4Zb, HRD, HRD, HRD, nullptr, nullptr);       // adj @ adj^T
    symabs1_k<<<(unsigned)(((size_t)HRD*HRD + 255)/256), 256, 0, stream>>>(P4Zb, HRD);      // Z
    gemmf32(stream, EPI_NONE, P4Zb, gc1, P4ZG, HRD, NN, HRD, nullptr, nullptr);             // Z @ gc1
    gemmf32(stream, EPI_RELU, out_adj, P4ZG, P4h1, HRD, NN, HRD, nullptr, nullptr);         // h1
    gemmf32(stream, EPI_NONE, P4h1, gc2, P4HG, HRD, HRD, NN, nullptr, nullptr);             // h1 @ gc2
    gemmf32(stream, EPI_RELU, out_adj, P4HG, P4h2, HRD, HRD, HRD, nullptr, nullptr);        // h2
    final_z_k<<<(unsigned)(((size_t)HRD*HRD + 255)/256), 256, 0, stream>>>(P4h2, out_z, HRD); // z
}

// Round 3
// 19301.709 us; speedup vs baseline: 1.2442x; 1.0638x over previous
//
#include <hip/hip_runtime.h>
#include <cstddef>
#include <cstdint>
#include <math.h>

// ============================ constants ============================
static constexpr int NN   = 1024;   // lr_dim
static constexpr int HRD  = 2048;   // hr_dim
static constexpr int DIMF = 320;
static constexpr int TB   = 85;     // sytrd LDS tail block (85x87 fp64 = 59 KB LDS)
static constexpr int CB3  = 128;    // persistent sytrd blocks (8 rows each)
static constexpr int BT3  = 1024;   // threads per sytrd block (16 waves)
static constexpr int NWY  = 16;     // WY reflector groups (64 each)

#define EPI_NONE      0
#define EPI_BIAS      1
#define EPI_BIAS_ADD  2
#define EPI_ABS_DIAG1 3
#define EPI_RELU      4

// agent-scope coherent access helpers (sc1): bypass stale per-XCD L2 without fences.
// Carries ONLY small cross-block traffic (P row, pvA, Rst pivot stage, barrier).
// Bulk trailing-matrix traffic is owner-private plain cached loads/stores.
__device__ __forceinline__ double gload(const double* p){
    return __hip_atomic_load(p, __ATOMIC_RELAXED, __HIP_MEMORY_SCOPE_AGENT);
}
__device__ __forceinline__ void gstore(double* p, double v){
    __hip_atomic_store(p, v, __ATOMIC_RELAXED, __HIP_MEMORY_SCOPE_AGENT);
}

// ============================ fp32 GEMM 64-tile (fallback, odd K) ============================
template<int EPI>
__global__ __launch_bounds__(256) void gemm32(
    const float* __restrict__ A, const float* __restrict__ B, float* __restrict__ C,
    int M, int N, int K, const float* __restrict__ bias, const float* __restrict__ D)
{
    __shared__ float As[16][65];
    __shared__ float Bs[16][65];
    const int bm = blockIdx.y << 6, bn = blockIdx.x << 6;
    const int tid = threadIdx.x;
    const int tm = (tid >> 4) << 2, tn = (tid & 15) << 2;
    float acc[4][4] = {};
    const int kt = (K + 15) >> 4;
    for (int k0 = 0; k0 < kt; ++k0){
        const int kb = k0 << 4;
        for (int t = tid; t < 1024; t += 256){
            int m = t >> 4, k = t & 15;
            int gm = bm + m, gk = kb + k;
            As[k][m] = (gm < M && gk < K) ? A[(size_t)gm*K + gk] : 0.f;
        }
        for (int t = tid; t < 1024; t += 256){
            int k = t >> 6, nn2 = t & 63;
            int gk = kb + k, gn = bn + nn2;
            Bs[k][nn2] = (gk < K && gn < N) ? B[(size_t)gk*N + gn] : 0.f;
        }
        __syncthreads();
        #pragma unroll
        for (int k = 0; k < 16; ++k){
            float a0 = As[k][tm], a1 = As[k][tm+1], a2 = As[k][tm+2], a3 = As[k][tm+3];
            float b0 = Bs[k][tn], b1 = Bs[k][tn+1], b2 = Bs[k][tn+2], b3 = Bs[k][tn+3];
            acc[0][0] += a0*b0; acc[0][1] += a0*b1; acc[0][2] += a0*b2; acc[0][3] += a0*b3;
            acc[1][0] += a1*b0; acc[1][1] += a1*b1; acc[1][2] += a1*b2; acc[1][3] += a1*b3;
            acc[2][0] += a2*b0; acc[2][1] += a2*b1; acc[2][2] += a2*b2; acc[2][3] += a2*b3;
            acc[3][0] += a3*b0; acc[3][1] += a3*b1; acc[3][2] += a3*b2; acc[3][3] += a3*b3;
        }
        __syncthreads();
    }
    #pragma unroll
    for (int r = 0; r < 4; ++r){
        int gm = bm + tm + r; if (gm >= M) continue;
        #pragma unroll
        for (int c = 0; c < 4; ++c){
            int gn = bn + tn + c; if (gn >= N) continue;
            float v = acc[r][c];
            if (EPI == EPI_BIAS)            v += bias[gn];
            else if (EPI == EPI_BIAS_ADD)   v += bias[gn] + D[(size_t)gm*N + gn];
            else if (EPI == EPI_ABS_DIAG1)  v = (gm == gn) ? 1.0f : fabsf(v);
            else if (EPI == EPI_RELU)       v = fmaxf(v, 0.0f);
            C[(size_t)gm*N + gn] = v;
        }
    }
}

// ============================ fp32 GEMM 64x128 double-buffered (K%16==0, N%8==0) ============================
// 128 threads, 8x8 acc, LDS ping-pong, ONE sync per K-tile; next tile's global loads
// issued into registers BEFORE compute so HBM/L2 latency hides under the 16-k FMA block.
// Per-element k-summation order identical to the old gemm128 (tiles ascending, k ascending).
template<int EPI>
__global__ __launch_bounds__(128) void gemm_db(
    const float* __restrict__ A, const float* __restrict__ B, float* __restrict__ C,
    int M, int N, int K, const float* __restrict__ bias, const float* __restrict__ D)
{
    __shared__ float As[2][16][68];
    __shared__ float Bs[2][16][132];
    const int bm = blockIdx.y << 6;       // 64-row tile
    const int bn = blockIdx.x << 7;       // 128-col tile
    const int tid = threadIdx.x;          // 0..127
    const int tm = (tid >> 4) << 3;       // 0..56
    const int tn = (tid & 15) << 3;       // 0..120
    const int ar = tid >> 2;              // A stage: row 0..31 (+32 for q=1)
    const int af = tid & 3;               // A stage: float4 idx 0..3
    const int br = tid >> 5;              // B stage: row 0..3 (+4 per q)
    const int bf = tid & 31;              // B stage: float4 idx 0..31

    float4 a_reg[2], b_reg[4];

    auto loadA = [&](int kb, int q) -> float4 {
        int gm = bm + ar + (q << 5);
        int gk = kb + (af << 2);
        if (gm < M) return *(const float4*)(A + (size_t)gm*K + gk);
        return make_float4(0.f,0.f,0.f,0.f);
    };
    auto loadB = [&](int kb, int q) -> float4 {
        int gk = kb + br + (q << 2);
        int gn = bn + (bf << 2);
        if (gn < N) return *(const float4*)(B + (size_t)gk*N + gn);
        return make_float4(0.f,0.f,0.f,0.f);
    };
    auto stash = [&](int p){
        #pragma unroll
        for (int q = 0; q < 2; ++q){
            int r = ar + (q << 5);
            As[p][(af<<2)+0][r] = a_reg[q].x; As[p][(af<<2)+1][r] = a_reg[q].y;
            As[p][(af<<2)+2][r] = a_reg[q].z; As[p][(af<<2)+3][r] = a_reg[q].w;
        }
        #pragma unroll
        for (int q = 0; q < 4; ++q)
            *(float4*)&Bs[p][br + (q<<2)][bf << 2] = b_reg[q];
    };

    // prologue: tile 0 -> LDS[0]
    #pragma unroll
    for (int q = 0; q < 2; ++q) a_reg[q] = loadA(0, q);
    #pragma unroll
    for (int q = 0; q < 4; ++q) b_reg[q] = loadB(0, q);
    stash(0);
    __syncthreads();

    float acc[8][8] = {};
    int p = 0;
    for (int kb = 16; ; kb += 16){
        const bool more = (kb < K);
        if (more){
            #pragma unroll
            for (int q = 0; q < 2; ++q) a_reg[q] = loadA(kb, q);
            #pragma unroll
            for (int q = 0; q < 4; ++q) b_reg[q] = loadB(kb, q);
        }
        #pragma unroll
        for (int k = 0; k < 16; ++k){
            float4 a0 = *(const float4*)&As[p][k][tm];
            float4 a1 = *(const float4*)&As[p][k][tm+4];
            float4 b0 = *(const float4*)&Bs[p][k][tn];
            float4 b1 = *(const float4*)&Bs[p][k][tn+4];
            float av[8] = {a0.x,a0.y,a0.z,a0.w,a1.x,a1.y,a1.z,a1.w};
            float bv[8] = {b0.x,b0.y,b0.z,b0.w,b1.x,b1.y,b1.z,b1.w};
            #pragma unroll
            for (int i = 0; i < 8; ++i)
                #pragma unroll
                for (int jj = 0; jj < 8; ++jj) acc[i][jj] += av[i]*bv[jj];
        }
        if (!more) break;
        stash(p ^ 1);          // writes target the buffer everyone finished reading last tile
        __syncthreads();       // single barrier per tile
        p ^= 1;
    }
    #pragma unroll
    for (int i = 0; i < 8; ++i){
        int gm = bm + tm + i; if (gm >= M) continue;
        #pragma unroll
        for (int jj = 0; jj < 8; ++jj){
            int gn = bn + tn + jj; if (gn >= N) continue;
            float v = acc[i][jj];
            if (EPI == EPI_BIAS)            v += bias[gn];
            else if (EPI == EPI_BIAS_ADD)   v += bias[gn] + D[(size_t)gm*N + gn];
            else if (EPI == EPI_ABS_DIAG1)  v = (gm == gn) ? 1.0f : fabsf(v);
            else if (EPI == EPI_RELU)       v = fmaxf(v, 0.0f);
            C[(size_t)gm*N + gn] = v;
        }
    }
}

// ============================ small kernels ============================
__global__ __launch_bounds__(256) void rowsum_rsqrt_k(const float* __restrict__ lr, double* __restrict__ r64, int n)
{
    __shared__ double sm[256];
    int row = blockIdx.x;
    double s = 0.0;
    for (int j = threadIdx.x; j < n; j += 256) s += (double)lr[(size_t)row*n + j];
    sm[threadIdx.x] = s; __syncthreads();
    for (int o = 128; o; o >>= 1){ if (threadIdx.x < o) sm[threadIdx.x] += sm[threadIdx.x + o]; __syncthreads(); }
    if (threadIdx.x == 0){
        double t = sm[0];
        r64[row] = (t > 0.0) ? 1.0/sqrt(t) : 0.0;
    }
}

__global__ __launch_bounds__(256) void build_A_k(const float* __restrict__ lr, const double* __restrict__ r64,
                                                 float* __restrict__ A32, double* __restrict__ A64, int n)
{
    size_t idx = (size_t)blockIdx.x*256 + threadIdx.x;
    if (idx >= (size_t)n*n) return;
    int i = (int)(idx / n), j = (int)(idx % n);
    if (j < i) return;
    double v = (double)lr[(size_t)j*n + i] * r64[i] * r64[j];
    A64[(size_t)i*n + j] = v; A64[(size_t)j*n + i] = v;
    float vf = (float)v;
    A32[(size_t)i*n + j] = vf; A32[(size_t)j*n + i] = vf;
}

__global__ __launch_bounds__(256) void score_k(const float* __restrict__ X, const float* __restrict__ pw,
                                               const float* __restrict__ pb, float* __restrict__ out,
                                               int n, int dim)
{
    int row = blockIdx.x*4 + (threadIdx.x >> 6);
    int lane = threadIdx.x & 63;
    if (row >= n) return;
    float acc = 0.f;
    for (int c = lane; c < dim; c += 64) acc += X[(size_t)row*dim + c]*pw[c];
    #pragma unroll
    for (int o = 32; o; o >>= 1) acc += __shfl_down(acc, o);
    if (lane == 0){
        float t = (acc + pb[0]) * 0.01f;
        out[row] = 1.0f/(1.0f + expf(-t));
    }
}

// jax.lax.top_k semantics: descending value, ties -> lower index first
__global__ __launch_bounds__(256) void topk_k(const float* __restrict__ scores, int n, int k,
                                              int* __restrict__ idxo, float* __restrict__ valo)
{
    __shared__ float s[1024];
    int tid = threadIdx.x;
    for (int i = tid; i < n; i += 256) s[i] = scores[i];
    __syncthreads();
    for (int i = tid; i < n; i += 256){
        float si = s[i]; int r = 0;
        for (int j = 0; j < n; ++j){
            float sj = s[j];
            r += (sj > si) || (sj == si && j < i);
        }
        if (r < k){ idxo[r] = i; valo[r] = si; }
    }
}

__global__ __launch_bounds__(256) void gatherX_k(const float* __restrict__ X, const int* __restrict__ idx,
                                                 const float* __restrict__ vals, float* __restrict__ Xo,
                                                 int k, int dim)
{
    size_t t = (size_t)blockIdx.x*256 + threadIdx.x;
    if (t >= (size_t)k*dim) return;
    int m = (int)(t / dim), c = (int)(t % dim);
    Xo[t] = X[(size_t)idx[m]*dim + c] * vals[m];
}

__global__ __launch_bounds__(256) void scatterX_k(const float* __restrict__ Xs, const int* __restrict__ idx,
                                                  float* __restrict__ Xu, int k, int dim)
{
    size_t t = (size_t)blockIdx.x*256 + threadIdx.x;
    if (t >= (size_t)k*dim) return;
    int m = (int)(t / dim), c = (int)(t % dim);
    Xu[(size_t)idx[m]*dim + c] = Xs[t];
}

__global__ __launch_bounds__(256) void gatherA_k(const float* __restrict__ A, const int* __restrict__ idx,
                                                 float* __restrict__ Ao, int k, int n)
{
    size_t t = (size_t)blockIdx.x*256 + threadIdx.x;
    if (t >= (size_t)k*k) return;
    int m1 = (int)(t / k), m2 = (int)(t % k);
    Ao[t] = A[(size_t)idx[m1]*n + idx[m2]];
}

__global__ __launch_bounds__(256) void fill0_k(float* __restrict__ p, size_t cnt)
{
    size_t t = (size_t)blockIdx.x*256 + threadIdx.x;
    if (t < cnt) p[t] = 0.f;
}

__global__ __launch_bounds__(256) void filld0_k(double* __restrict__ p, size_t cnt)
{
    size_t t = (size_t)blockIdx.x*256 + threadIdx.x;
    if (t < cnt) p[t] = 0.0;
}

__global__ __launch_bounds__(256) void init_sytrd_k(double* __restrict__ pv, unsigned* __restrict__ bar, int n)
{
    int t = blockIdx.x*256 + threadIdx.x;
    if (t < n) pv[t] = 0.0;
    if (t < 1024) bar[t] = 0u;
}

__global__ __launch_bounds__(256) void concat_k(const float* __restrict__ X, const float* __restrict__ orgX,
                                                float* __restrict__ Xc, int n, int dim)
{
    size_t t = (size_t)blockIdx.x*256 + threadIdx.x;
    size_t tot = (size_t)n*2*dim;
    if (t >= tot) return;
    int i = (int)(t / (2*dim)), c = (int)(t % (2*dim));
    Xc[t] = (c < dim) ? X[(size_t)i*dim + c] : orgX[(size_t)i*dim + (c - dim)];
}

__global__ __launch_bounds__(256) void build_a_k(const float* __restrict__ gsr, float* __restrict__ a)
{
    size_t idx = (size_t)blockIdx.x*256 + threadIdx.x;
    if (idx >= (size_t)HRD*NN) return;
    int i = (int)(idx >> 10), k = (int)(idx & 1023);
    a[idx] = gsr[(size_t)i*HRD + k] + gsr[(size_t)i*HRD + NN + k];
}

__global__ __launch_bounds__(256) void symabs1_k(float* __restrict__ Z, int n)
{
    size_t idx = (size_t)blockIdx.x*256 + threadIdx.x;
    if (idx >= (size_t)n*n) return;
    int i = (int)(idx / n), j = (int)(idx % n);
    if (i > j) return;
    float a = Z[(size_t)i*n + j], b = Z[(size_t)j*n + i];
    float v = 0.5f*(a + b);
    float o = (i == j) ? 1.0f : fabsf(v);
    Z[(size_t)i*n + j] = o; Z[(size_t)j*n + i] = o;
}

__global__ __launch_bounds__(256) void final_z_k(const float* __restrict__ h2, float* __restrict__ z, int n)
{
    size_t idx = (size_t)blockIdx.x*256 + threadIdx.x;
    if (idx >= (size_t)n*n) return;
    int i = (int)(idx / n), j = (int)(idx % n);
    if (i > j) return;
    float v = 0.5f*(h2[(size_t)i*n + j] + h2[(size_t)j*n + i]);
    float o = (i == j) ? 1.0f : fabsf(v);
    z[(size_t)i*n + j] = o; z[(size_t)j*n + i] = o;
}

// dst[c][r] = (float)src[r][c]   (n x n, n % 32 == 0)
__global__ __launch_bounds__(256) void transpose_cast_k(const double* __restrict__ src, float* __restrict__ dst, int n)
{
    __shared__ float tile[32][33];
    int r0 = blockIdx.y*32, c0 = blockIdx.x*32;
    int tx = threadIdx.x & 31, ty = threadIdx.x >> 5;
    for (int i = ty; i < 32; i += 8)
        tile[i][tx] = (float)src[(size_t)(r0 + i)*n + (c0 + tx)];
    __syncthreads();
    for (int i = ty; i < 32; i += 8)
        dst[(size_t)(c0 + i)*n + (r0 + tx)] = tile[tx][i];
}

// dst[c][r] = src[r][c]  (n x n, n % 32 == 0)
__global__ __launch_bounds__(256) void transpose32_k(const float* __restrict__ src, float* __restrict__ dst, int n)
{
    __shared__ float tile[32][33];
    int r0 = blockIdx.y*32, c0 = blockIdx.x*32;
    int tx = threadIdx.x & 31, ty = threadIdx.x >> 5;
    for (int i = ty; i < 32; i += 8)
        tile[i][tx] = src[(size_t)(r0 + i)*n + (c0 + tx)];
    __syncthreads();
    for (int i = ty; i < 32; i += 8)
        dst[(size_t)(c0 + i)*n + (r0 + tx)] = tile[tx][i];
}

// ============================ persistent Householder tridiagonalization ============================
// sytrd_coop6: fixed row ownership (block bid owns rows [8bid, 8bid+8)), FUSED phase-A+pivot
// (single concurrent sc1-load round per column), dynamic block retirement (blocks exit after
// their last owned column; barrier targets are closed-form in j).
__global__ __launch_bounds__(BT3) void sytrd_coop6(
    double* __restrict__ A, double* __restrict__ e, double* __restrict__ tauA,
    double* __restrict__ sclA, double* __restrict__ P, double* __restrict__ pvA,
    double* __restrict__ Rst, unsigned* __restrict__ bar, int n, int jend)
{
    __shared__ double VP[1024], WP[1024], VJ2[2][1024];
    __shared__ double redA[16], redB[16];
    const int tid   = threadIdx.x;
    const int bid   = blockIdx.x;
    const int lane  = tid & 63;
    const int wid   = tid >> 6;
    const int rwav  = wid >> 1;            // 0..7 row slot
    const int half  = wid & 1;             // half-row (2 waves per row)
    const int u     = (bid << 3) + rwav;   // owned physical row
    const int g     = bid >> 4;            // barrier group (8 groups x 16 blocks)
    const int mylast = (bid << 3) + 7;     // last column this block participates in

    double tau_p = 0.0, sc_p = 0.0;
    unsigned cumG = 0, cumC = 0;

    for (int j = 0; j < jend; ++j){
        const int m = n - 1 - j;
        double* __restrict__ VJnew = VJ2[j & 1];
        const double* __restrict__ VJold = VJ2[(j & 1) ^ 1];

        // barrier bookkeeping (pure function of j; all alive blocks agree)
        {
            const int retired = j >> 3;
            int d = retired - (g << 4);
            d = (d < 0) ? 0 : (d > 16 ? 16 : d);
            cumG += (unsigned)(16 - d);
            cumC += (unsigned)(8 - (j >> 7));
        }

        // ---- fused phase A + pivot row (one sc1 round) ----
        double s = 0.0, wp0 = 0.0;
        if (j > 0){
            const double* __restrict__ Prow = P + (size_t)(j-1)*NN;
            const double* __restrict__ rs   = Rst + ((size_t)(j & 1) << 10);
            const double pv_prev = gload(&pvA[j-1]);
            const double p0      = gload(&Prow[0]);
            const double c2_p = 0.5*tau_p*tau_p*pv_prev;
            wp0 = tau_p*p0 - c2_p;
            if (tid == 0){ VP[0] = 1.0; WP[0] = wp0; }
            if (tid >= 1 && tid <= m){
                double pi  = gload(&Prow[tid]);
                double rsi = gload(&rs[tid]);
                double vp  = VJold[tid]*sc_p;
                double wp  = tau_p*pi - c2_p*vp;
                VP[tid] = vp; WP[tid] = wp;
                double x = rsi - wp - wp0*vp;
                VJnew[tid-1] = x;
                if (tid >= 2) s += x*x;
            }
        } else {
            if (tid < m){
                double x = A[1 + tid];   // row 0, fresh from build_A_k
                VJnew[tid] = x;
                if (tid >= 1) s += x*x;
            }
        }
        #pragma unroll
        for (int o = 32; o; o >>= 1) s += __shfl_down(s, o);
        if (lane == 0) redA[wid] = s;
        __syncthreads();     // VP/WP/VJnew visible + redA ready

        double sigma2 = 0.0;
        #pragma unroll
        for (int i = 0; i < 16; ++i) sigma2 += redA[i];
        double alpha = VJnew[0];
        double beta, tl, sc;
        if (sigma2 == 0.0){ beta = alpha; tl = 0.0; sc = 0.0; }
        else {
            beta = -copysign(sqrt(alpha*alpha + sigma2), alpha);
            tl = (beta - alpha)/beta;
            sc = 1.0/(alpha - beta);
        }

        // ---- owner-block writeback of row j (plain stores, own L2 lines) ----
        if (bid == (j >> 3)){
            double* __restrict__ row = A + (size_t)j*n + (j+1);
            if (tid < m) row[tid] = VJnew[tid];
            if (tid == 0){
                e[j] = beta; tauA[j] = tl; sclA[j] = sc;
                if (j > 0) A[(size_t)j*n + j] -= 2.0*wp0;
            }
        }

        // ---- phase B: owner-private trailing update + matvec; publish next pivot row ----
        double pvloc = 0.0;
        if (u > j){
            const int r = u - (j+1);
            double* __restrict__ Ar   = A + (size_t)u*n + (j+1);
            double* __restrict__ rs_w = Rst + ((size_t)((j+1) & 1) << 10);
            const bool pub = (r == 0);
            double acc = 0.0;
            if (j > 0){
                double vpr = VP[1+r], wpr = WP[1+r];
                for (int c = half*64 + lane; c < m; c += 128){
                    double a = Ar[c] - (vpr*WP[1+c] + wpr*VP[1+c]);
                    Ar[c] = a;
                    if (pub) gstore(&rs_w[c], a);
                    double vj = (c == 0) ? 1.0 : VJnew[c]*sc;
                    acc += a*vj;
                }
            } else {
                for (int c = half*64 + lane; c < m; c += 128){
                    double a = Ar[c];
                    if (pub) gstore(&rs_w[c], a);
                    double vj = (c == 0) ? 1.0 : VJnew[c]*sc;
                    acc += a*vj;
                }
            }
            #pragma unroll
            for (int o = 32; o; o >>= 1) acc += __shfl_down(acc, o);
            if (lane == 0){
                atomicAdd(&P[(size_t)j*NN + r], acc);   // partial (half-row)
                double vr = (r == 0) ? 1.0 : VJnew[r]*sc;
                pvloc = acc*vr;
            }
        }
        if (lane == 0) redB[wid] = pvloc;
        __syncthreads();     // redB ready + ALL waves' phase-B global ops drained (vmcnt(0) pre-barrier)

        if (tid == 0){
            double t2 = 0.0;
            #pragma unroll
            for (int i = 0; i < 16; ++i) t2 += redB[i];
            if (t2 != 0.0) atomicAdd(&pvA[j], t2);
            asm volatile("s_waitcnt vmcnt(0)" ::: "memory");   // pvA add complete before arrival
            unsigned t = __hip_atomic_fetch_add(&bar[g*32], 1u, __ATOMIC_RELAXED, __HIP_MEMORY_SCOPE_AGENT);
            if (t == cumG - 1u)
                __hip_atomic_fetch_add(&bar[256], 1u, __ATOMIC_RELAXED, __HIP_MEMORY_SCOPE_AGENT);
            if (j != mylast){
                while (__hip_atomic_load(&bar[256], __ATOMIC_RELAXED, __HIP_MEMORY_SCOPE_AGENT) < cumC)
                    __builtin_amdgcn_s_sleep(1);
            }
        }
        if (j == mylast) break;    // retired: all owned rows finalized; exit (uniform)
        __syncthreads();           // release after spin
        tau_p = tl; sc_p = sc;
    }

    // ---- apply final pending update (column jend-1) on the TB x TB tail, owner-only ----
    if (u >= jend){
        const int tb = n - jend;
        const double* __restrict__ VJf = VJ2[(jend-1) & 1];
        const double* __restrict__ pp  = P + (size_t)(jend-1)*NN;
        double c2f = 0.5*tau_p*tau_p*gload(&pvA[jend-1]);
        const int ri = u - jend;
        double vpr = (ri == 0) ? 1.0 : VJf[ri]*sc_p;
        double wpr = tau_p*gload(&pp[ri]) - c2f*vpr;
        double* __restrict__ Ar = A + (size_t)u*n + jend;
        for (int ci = half*64 + lane; ci < tb; ci += 128){
            double vpc = (ci == 0) ? 1.0 : VJf[ci]*sc_p;
            double wpc = tau_p*gload(&pp[ci]) - c2f*vpc;
            Ar[ci] -= vpr*wpc + wpr*vpc;
        }
    }
}

// Tail: remaining (TB-2) Householder steps entirely in LDS (single block).
__global__ __launch_bounds__(256) void hh_tail(double* __restrict__ A64, double* __restrict__ e,
                                               double* __restrict__ tau, double* __restrict__ scaleg, int n)
{
    __shared__ double T[TB][TB+2];
    __shared__ double v[TB], p[TB], red[256];
    const int base = n - TB;
    const int tid = threadIdx.x;
    for (int t = tid; t < TB*TB; t += 256){
        int r = t / TB, c = t % TB;
        T[r][c] = A64[(size_t)(base + r)*n + base + c];
    }
    __syncthreads();
    for (int l = 0; l <= TB - 3; ++l){
        const int m = TB - 1 - l;
        double s = 0.0;
        for (int i = 1 + tid; i < m; i += 256){ double x = T[l+1+i][l]; s += x*x; }
        red[tid] = s; __syncthreads();
        for (int o = 128; o; o >>= 1){ if (tid < o) red[tid] += red[tid + o]; __syncthreads(); }
        double sigma2 = red[0];
        double alpha = T[l+1][l];
        double beta, tl, sc;
        if (sigma2 == 0.0){ beta = alpha; tl = 0.0; sc = 0.0; }
        else {
            beta = -copysign(sqrt(alpha*alpha + sigma2), alpha);
            tl = (beta - alpha)/beta;
            sc = 1.0/(alpha - beta);
        }
        for (int i = tid; i < m; i += 256) v[i] = (i == 0) ? 1.0 : T[l+1+i][l]*sc;
        __syncthreads();
        for (int i = tid; i < m; i += 256){
            double acc = 0.0;
            for (int c = 0; c < m; ++c) acc += T[l+1+i][l+1+c]*v[c];
            p[i] = acc;
        }
        __syncthreads();
        double s2 = 0.0;
        for (int i = tid; i < m; i += 256) s2 += p[i]*v[i];
        red[tid] = s2; __syncthreads();
        for (int o = 128; o; o >>= 1){ if (tid < o) red[tid] += red[tid + o]; __syncthreads(); }
        double pvv = red[0];
        double c2 = 0.5*tl*tl*pvv;
        for (int t2 = tid; t2 < m*m; t2 += 256){
            int r = t2 / m, c = t2 % m;
            double wr = tl*p[r] - c2*v[r];
            double wc = tl*p[c] - c2*v[c];
            T[l+1+r][l+1+c] -= v[r]*wc + wr*v[c];
        }
        if (tid == 0){ int j = base + l; e[j] = beta; tau[j] = tl; scaleg[j] = 1.0; }
        for (int i = tid; i < m; i += 256) A64[(size_t)(base + l)*n + (base + l + 1) + i] = v[i];
        __syncthreads();
    }
    for (int r = tid; r < TB; r += 256) A64[(size_t)(base + r)*n + base + r] = T[r][r];
    if (tid == 0) A64[(size_t)(n-1)*n + (n-2)] = T[TB-1][TB-2];
}

__global__ __launch_bounds__(256) void extract_de_k(const double* __restrict__ A64, double* __restrict__ d,
                                                    double* __restrict__ e, int n)
{
    int i = blockIdx.x*256 + threadIdx.x;
    if (i < n) d[i] = A64[(size_t)i*n + i];
    if (i == 0) e[n-2] = A64[(size_t)(n-1)*n + (n-2)];
}

// ============================ tridiagonal eigensolver ============================
__global__ __launch_bounds__(256) void bisect_k(const double* __restrict__ d, const double* __restrict__ e,
                                                double* __restrict__ w, int n)
{
    __shared__ double ds[1024], e2s[1024];
    const int tid = threadIdx.x;
    for (int i = tid; i < n; i += 256) ds[i] = d[i];
    for (int i = tid; i < n-1; i += 256){ double ei = e[i]; e2s[i] = ei*ei; }
    __syncthreads();
    int k = blockIdx.x*256 + tid;
    if (k >= n) return;
    double gl = 1e300, gu = -1e300;
    for (int i = 0; i < n; ++i){
        double em = (i > 0) ? sqrt(e2s[i-1]) : 0.0, ep2 = (i < n-1) ? sqrt(e2s[i]) : 0.0;
        double lo2 = ds[i] - em - ep2, hi2 = ds[i] + em + ep2;
        gl = fmin(gl, lo2); gu = fmax(gu, hi2);
    }
    double lo = gl - 1e-10, hi = gu + 1e-10;
    for (int it = 0; it < 42; ++it){
        double mid = 0.5*(lo + hi);
        int cnt = 0;
        double p0 = 1.0;
        double p1 = ds[0] - mid;
        if (p1 <= 0.0){ ++cnt; if (p1 == 0.0) p1 = -1e-300; }
        for (int i = 1; i < n; ++i){
            double pn = (ds[i] - mid)*p1 - e2s[i-1]*p0;
            bool neg = ((pn < 0.0) != (p1 < 0.0)) || (pn == 0.0);
            cnt += neg;
            if (pn == 0.0) pn = (p1 > 0.0) ? -1e-300 : 1e-300;
            p0 = p1; p1 = pn;
            double ap = fabs(p1);
            if (ap > 1e120){ p1 *= 1e-200; p0 *= 1e-200; }
            else if (ap < 1e-120){ p1 *= 1e200; p0 *= 1e200; }
        }
        if (cnt <= k) lo = mid; else hi = mid;
    }
    w[k] = 0.5*(lo + hi);
}

// Inverse iteration with explicit 8-deep load prefetch in every dependent pass.
// Only 1024 threads exist (parallelism = #eigenvalues); without batched loads the
// solves are one-outstanding-load latency chains (~30 GB/s). Prefetch-8 gives ~8x MLP.
// Arithmetic order of each recurrence is preserved exactly.
__global__ __launch_bounds__(256) void invit_k(const double* __restrict__ d, const double* __restrict__ e,
                                               const double* __restrict__ w,
                                               double* __restrict__ FD, double* __restrict__ FL,
                                               double* __restrict__ FU, double* __restrict__ FU2,
                                               signed char* __restrict__ PIV, double* __restrict__ Z, int n)
{
    __shared__ double dsm[1024], esm[1024];
    const int tid = threadIdx.x;
    for (int i = tid; i < n; i += 256) dsm[i] = d[i];
    for (int i = tid; i < n-1; i += 256) esm[i] = e[i];
    __syncthreads();
    int k = blockIdx.x*256 + tid;
    if (k >= n) return;
    const double lam = w[k];
    const double tiny = 1e-280;
    double dcur = dsm[0] - lam;
    double ucur = esm[0];
    for (int i = 0; i < n-1; ++i){
        double dli = esm[i];
        double dnext_init = dsm[i+1] - lam;
        double unext_init = (i < n-2) ? esm[i+1] : 0.0;
        size_t o = (size_t)i*n + k;
        if (fabs(dcur) >= fabs(dli)){
            if (dcur == 0.0) dcur = tiny;
            double f = dli/dcur;
            FD[o] = dcur; FL[o] = f; FU[o] = ucur; FU2[o] = 0.0; PIV[o] = 0;
            dcur = dnext_init - f*ucur;
            ucur = unext_init;
        } else {
            double f = dcur/dli;
            FD[o] = dli; FL[o] = f; FU[o] = dnext_init; FU2[o] = unext_init; PIV[o] = 1;
            dcur = ucur - f*dnext_init;
            ucur = -f*unext_init;
        }
    }
    if (dcur == 0.0) dcur = tiny;
    FD[(size_t)(n-1)*n + k] = dcur;
    for (int i = 0; i < n; ++i){
        unsigned h = (unsigned)(i + 1)*0x9E3779B9u + (unsigned)(k + 1)*0x85EBCA6Bu;
        h ^= h >> 16; h *= 0x7FEB352Du; h ^= h >> 15; h *= 0x846CA68Bu; h ^= h >> 16;
        Z[(size_t)i*n + k] = (double)(h >> 8)*(1.0/16777216.0) - 0.5;
    }
    const double fdlast = FD[(size_t)(n-1)*n + k];
    for (int iter = 0; iter < 2; ++iter){
        // ---- forward substitution (prefetch-8) ----
        double zc = Z[k];
        int i = 0;
        const int nm1 = n - 1;
        for (; i + 8 <= nm1; i += 8){
            double fl[8], zn[8]; int pv[8];
            #pragma unroll
            for (int u2 = 0; u2 < 8; ++u2){
                size_t o = (size_t)(i+u2)*n + k;
                fl[u2] = FL[o]; zn[u2] = Z[o + n]; pv[u2] = PIV[o];
            }
            #pragma unroll
            for (int u2 = 0; u2 < 8; ++u2){
                size_t o = (size_t)(i+u2)*n + k;
                if (!pv[u2]){ Z[o] = zc; zc = zn[u2] - fl[u2]*zc; }
                else        { Z[o] = zn[u2]; zc = zc - fl[u2]*zn[u2]; }
            }
        }
        for (; i < nm1; ++i){
            size_t o = (size_t)i*n + k;
            double fl = FL[o], zn = Z[o + n];
            if (!PIV[o]){ Z[o] = zc; zc = zn - fl*zc; }
            else        { Z[o] = zn; zc = zc - fl*zn; }
        }
        // ---- backward substitution (prefetch-8) ----
        double za = zc / fdlast;
        Z[(size_t)(n-1)*n + k] = za;
        size_t o2 = (size_t)(n-2)*n + k;
        double zaa = (Z[o2] - FU[o2]*za) / FD[o2];
        Z[o2] = zaa;
        double zb = za;
        int i2 = n - 3;
        for (; i2 >= 7; i2 -= 8){
            double zv[8], fu[8], fu2v[8], fd[8];
            #pragma unroll
            for (int u2 = 0; u2 < 8; ++u2){
                size_t o = (size_t)(i2-u2)*n + k;
                zv[u2] = Z[o]; fu[u2] = FU[o]; fu2v[u2] = FU2[o]; fd[u2] = FD[o];
            }
            #pragma unroll
            for (int u2 = 0; u2 < 8; ++u2){
                size_t o = (size_t)(i2-u2)*n + k;
                double znew = (zv[u2] - fu[u2]*zaa - fu2v[u2]*zb) / fd[u2];
                Z[o] = znew;
                zb = zaa; zaa = znew;
            }
        }
        for (; i2 >= 0; --i2){
            size_t o = (size_t)i2*n + k;
            double znew = (Z[o] - FU[o]*zaa - FU2[o]*zb) / FD[o];
            Z[o] = znew;
            zb = zaa; zaa = znew;
        }
        // ---- max-normalize (prefetch-8, 8 partial maxes) ----
        double m0=0,m1=0,m2=0,m3=0,m4=0,m5=0,m6=0,m7=0;
        int i3 = 0;
        for (; i3 + 8 <= n; i3 += 8){
            m0 = fmax(m0, fabs(Z[(size_t)(i3+0)*n + k]));
            m1 = fmax(m1, fabs(Z[(size_t)(i3+1)*n + k]));
            m2 = fmax(m2, fabs(Z[(size_t)(i3+2)*n + k]));
            m3 = fmax(m3, fabs(Z[(size_t)(i3+3)*n + k]));
            m4 = fmax(m4, fabs(Z[(size_t)(i3+4)*n + k]));
            m5 = fmax(m5, fabs(Z[(size_t)(i3+5)*n + k]));
            m6 = fmax(m6, fabs(Z[(size_t)(i3+6)*n + k]));
            m7 = fmax(m7, fabs(Z[(size_t)(i3+7)*n + k]));
        }
        double mx = fmax(fmax(fmax(m0,m1),fmax(m2,m3)), fmax(fmax(m4,m5),fmax(m6,m7)));
        for (; i3 < n; ++i3) mx = fmax(mx, fabs(Z[(size_t)i3*n + k]));
        double s = (mx > 0.0) ? 1.0/mx : 1.0;
        for (int i4 = 0; i4 + 8 <= n; i4 += 8){
            double zv[8];
            #pragma unroll
            for (int u2 = 0; u2 < 8; ++u2) zv[u2] = Z[(size_t)(i4+u2)*n + k];
            #pragma unroll
            for (int u2 = 0; u2 < 8; ++u2) Z[(size_t)(i4+u2)*n + k] = zv[u2]*s;
        }
    }
    // ---- 2-norm normalize (prefetch-8) ----
    double n0=0,n1=0,n2=0,n3=0,n4=0,n5=0,n6=0,n7=0;
    int i5 = 0;
    for (; i5 + 8 <= n; i5 += 8){
        double zv[8];
        #pragma unroll
        for (int u2 = 0; u2 < 8; ++u2) zv[u2] = Z[(size_t)(i5+u2)*n + k];
        n0 += zv[0]*zv[0]; n1 += zv[1]*zv[1]; n2 += zv[2]*zv[2]; n3 += zv[3]*zv[3];
        n4 += zv[4]*zv[4]; n5 += zv[5]*zv[5]; n6 += zv[6]*zv[6]; n7 += zv[7]*zv[7];
    }
    double nrm = ((n0+n1)+(n2+n3)) + ((n4+n5)+(n6+n7));
    for (; i5 < n; ++i5){ double v = Z[(size_t)i5*n + k]; nrm += v*v; }
    double s = 1.0/sqrt(nrm);
    for (int i6 = 0; i6 + 8 <= n; i6 += 8){
        double zv[8];
        #pragma unroll
        for (int u2 = 0; u2 < 8; ++u2) zv[u2] = Z[(size_t)(i6+u2)*n + k];
        #pragma unroll
        for (int u2 = 0; u2 < 8; ++u2) Z[(size_t)(i6+u2)*n + k] = zv[u2]*s;
    }
}

// ============================ batched blocked-WY back-transform ============================
__global__ __launch_bounds__(256) void wy_buildV_k(const double* __restrict__ A64, const double* __restrict__ scaleg,
                                                   double* __restrict__ Vbig, int n)
{
    size_t idx = (size_t)blockIdx.x*256 + threadIdx.x;
    if (idx >= (size_t)NWY*1024*64) return;
    int g = (int)(idx >> 16);
    int r = (int)((idx >> 6) & 1023);
    int t = (int)(idx & 63);
    int b0 = g*64;
    int nbsz = (n - 2) - b0; if (nbsz > 64) nbsz = 64;
    double v = 0.0;
    if (t < nbsz){
        int j = b0 + t;
        if (r == j + 1) v = 1.0;
        else if (r > j + 1) v = A64[(size_t)j*n + r]*scaleg[j];
    }
    Vbig[idx] = v;
}

__global__ __launch_bounds__(256) void wy_buildT_k(const double* __restrict__ Vbig, const double* __restrict__ tau,
                                                   double* __restrict__ Tbig, int n)
{
    __shared__ double G[64][65];
    __shared__ double Ts[64][65];
    __shared__ double Vs[32][65];
    const int g = blockIdx.x;
    const int tid = threadIdx.x;
    const double* __restrict__ V = Vbig + ((size_t)g << 16);
    const int b0 = g*64;
    int nbsz = (n - 2) - b0; if (nbsz > 64) nbsz = 64;
    for (int p = tid; p < 64*64; p += 256) G[p >> 6][p & 63] = 0.0;
    __syncthreads();
    for (int rb = b0; rb < n; rb += 32){
        for (int s = tid; s < 2048; s += 256){
            int rr = s >> 6, tt = s & 63;
            Vs[rr][tt] = V[((size_t)(rb + rr) << 6) + tt];
        }
        __syncthreads();
        for (int p = tid; p < 4096; p += 256){
            int t = p >> 6, s2 = p & 63;
            if (t < s2 && s2 < nbsz){
                double acc = 0.0;
                #pragma unroll 8
                for (int rr = 0; rr < 32; ++rr) acc += Vs[rr][t]*Vs[rr][s2];
                G[t][s2] += acc;
            }
        }
        __syncthreads();
    }
    for (int t = nbsz - 1; t >= 0; --t){
        for (int u = tid; u < 64; u += 256){
            double val = 0.0;
            if (u == t) val = tau[b0 + t];
            else if (u > t && u < nbsz){
                double s = 0.0;
                for (int s2 = t + 1; s2 <= u; ++s2) s += G[t][s2]*Ts[s2][u];
                val = -tau[b0 + t]*s;
            }
            Ts[t][u] = val;
        }
        __syncthreads();
    }
    for (int p = tid; p < 64*64; p += 256){
        int t = p >> 6, u = p & 63;
        Tbig[((size_t)g << 12) + p] = (t < nbsz) ? Ts[t][u] : 0.0;
    }
}

__global__ __launch_bounds__(256) void wy_apply_k(const double* __restrict__ Vbig, const double* __restrict__ Tbig,
                                                  double* __restrict__ Z, int n)
{
    __shared__ double Vs[32][65];
    __shared__ double Zs[32][17];
    __shared__ double Y[64][17];
    __shared__ double W[64][17];
    const int tid = threadIdx.x;
    const int c   = tid & 15;
    const int tq  = tid >> 4;
    const int c0  = blockIdx.x * 16;

    for (int g = NWY - 1; g >= 0; --g){
        const double* __restrict__ V = Vbig + ((size_t)g << 16);
        const double* __restrict__ T = Tbig + ((size_t)g << 12);
        const int b0 = g*64;
        double acc0 = 0.0, acc1 = 0.0, acc2 = 0.0, acc3 = 0.0;
        for (int rb = b0; rb < n; rb += 32){
            for (int s = tid; s < 2048; s += 256){
                int rr = s >> 6, tt = s & 63;
                Vs[rr][tt] = V[((size_t)(rb + rr) << 6) + tt];
            }
            for (int s = tid; s < 512; s += 256){
                int rr = s >> 4, cc = s & 15;
                Zs[rr][cc] = Z[(size_t)(rb + rr)*n + c0 + cc];
            }
            __syncthreads();
            #pragma unroll 8
            for (int rr = 0; rr < 32; ++rr){
                double z = Zs[rr][c];
                acc0 += Vs[rr][tq*4+0]*z;
                acc1 += Vs[rr][tq*4+1]*z;
                acc2 += Vs[rr][tq*4+2]*z;
                acc3 += Vs[rr][tq*4+3]*z;
            }
            __syncthreads();
        }
        Y[tq*4+0][c] = acc0; Y[tq*4+1][c] = acc1; Y[tq*4+2][c] = acc2; Y[tq*4+3][c] = acc3;
        __syncthreads();
        #pragma unroll
        for (int i = 0; i < 4; ++i){
            int t = tq*4 + i;
            double a = 0.0;
            for (int s = t; s < 64; ++s) a += T[(t << 6) + s]*Y[s][c];
            W[t][c] = a;
        }
        __syncthreads();
        for (int rb = b0; rb < n; rb += 32){
            for (int s = tid; s < 2048; s += 256){
                int rr = s >> 6, tt = s & 63;
                Vs[rr][tt] = V[((size_t)(rb + rr) << 6) + tt];
            }
            __syncthreads();
            #pragma unroll
            for (int half = 0; half < 2; ++half){
                int item = tid + half*256;
                int rr = item >> 4, cc = item & 15;
                double s = 0.0;
                #pragma unroll 16
                for (int t = 0; t < 64; ++t) s += Vs[rr][t]*W[t][cc];
                Z[(size_t)(rb + rr)*n + c0 + cc] -= s;
            }
            __syncthreads();
        }
        __syncthreads();
    }
}

// ============================ host dispatch helpers ============================
static void gemmf32(hipStream_t st, int epi,
                    const float* A, const float* B, float* C, int M, int N, int K,
                    const float* bias, const float* D)
{
    if ((K & 15) == 0 && (N & 7) == 0){
        dim3 g((N + 127)/128, (M + 63)/64), b(128);
        switch (epi){
        case EPI_NONE:      gemm_db<EPI_NONE><<<g, b, 0, st>>>(A, B, C, M, N, K, bias, D); break;
        case EPI_BIAS:      gemm_db<EPI_BIAS><<<g, b, 0, st>>>(A, B, C, M, N, K, bias, D); break;
        case EPI_BIAS_ADD:  gemm_db<EPI_BIAS_ADD><<<g, b, 0, st>>>(A, B, C, M, N, K, bias, D); break;
        case EPI_ABS_DIAG1: gemm_db<EPI_ABS_DIAG1><<<g, b, 0, st>>>(A, B, C, M, N, K, bias, D); break;
        case EPI_RELU:      gemm_db<EPI_RELU><<<g, b, 0, st>>>(A, B, C, M, N, K, bias, D); break;
        }
    } else {
        dim3 g((N + 63)/64, (M + 63)/64), b(256);
        switch (epi){
        case EPI_NONE:      gemm32<EPI_NONE><<<g, b, 0, st>>>(A, B, C, M, N, K, bias, D); break;
        case EPI_BIAS:      gemm32<EPI_BIAS><<<g, b, 0, st>>>(A, B, C, M, N, K, bias, D); break;
        case EPI_BIAS_ADD:  gemm32<EPI_BIAS_ADD><<<g, b, 0, st>>>(A, B, C, M, N, K, bias, D); break;
        case EPI_ABS_DIAG1: gemm32<EPI_ABS_DIAG1><<<g, b, 0, st>>>(A, B, C, M, N, K, bias, D); break;
        case EPI_RELU:      gemm32<EPI_RELU><<<g, b, 0, st>>>(A, B, C, M, N, K, bias, D); break;
        }
    }
}

// ============================ kernel_launch ============================
extern "C" void kernel_launch(void* const* d_in, const int* in_sizes, int n_in,
                              void* d_out, int out_size, void* d_ws, size_t ws_size,
                              hipStream_t stream)
{
    (void)in_sizes; (void)n_in; (void)out_size; (void)ws_size;
    const float* lr       = (const float*)d_in[0];
    const float* gsr_w    = (const float*)d_in[1];
    const float* start_w  = (const float*)d_in[2];
    const float* start_b  = (const float*)d_in[3];
    const float* down_w   = (const float*)d_in[4];
    const float* down_b   = (const float*)d_in[5];
    const float* pool_w   = (const float*)d_in[6];
    const float* pool_b   = (const float*)d_in[7];
    const float* bottom_w = (const float*)d_in[8];
    const float* bottom_b = (const float*)d_in[9];
    const float* end_w    = (const float*)d_in[10];
    const float* end_b    = (const float*)d_in[11];
    const float* up_w     = (const float*)d_in[12];
    const float* up_b     = (const float*)d_in[13];
    const float* gc1      = (const float*)d_in[14];
    const float* gc2      = (const float*)d_in[15];

    float* out_z     = (float*)d_out;                       // [2048,2048]
    float* out_net   = out_z + (size_t)HRD*HRD;             // [1024,2048]
    float* out_start = out_net + (size_t)NN*HRD;            // [1024,320]
    float* out_adj   = out_start + (size_t)NN*DIMF;         // [2048,2048]

    static const int LVL_N[4] = {1024, 921, 644, 386};
    static const int LVL_K[4] = {921, 644, 386, 193};

    // -------- workspace arena --------
    char* Wb = (char*)d_ws;
    size_t off = 0;
    auto alloc = [&](size_t bb)->char*{ char* p = Wb + off; off = (off + bb + 255) & ~(size_t)255; return p; };

    float*  A32  = (float*) alloc((size_t)NN*NN*4);
    double* A64  = (double*)alloc((size_t)NN*NN*8);
    float*  UfT  = (float*) alloc((size_t)NN*NN*4);   // U^T as [k][j] fp32
    double* r64  = (double*)alloc(NN*8);
    double* dD   = (double*)alloc(NN*8);
    double* dE   = (double*)alloc(NN*8);
    double* dTau = (double*)alloc(NN*8);
    double* dScl = (double*)alloc(NN*8);
    double* dWev = (double*)alloc(NN*8);
    double* pvA  = (double*)alloc(NN*8);
    double* Rst  = (double*)alloc((size_t)2*NN*8);    // double-buffered pivot-row stage (sc1)
    unsigned* barcnt = (unsigned*)alloc(8192);
    char* SBASE = Wb + off;

    // P2 overlay (U-Net)
    size_t so = 0;
    auto salloc = [&](size_t bb)->char*{ char* p = SBASE + so; so = (so + bb + 255) & ~(size_t)255; return p; };
    float* XT  = (float*)salloc((size_t)NN*DIMF*4);
    float* XP1 = (float*)salloc((size_t)NN*DIMF*4);
    float* XP2 = (float*)salloc((size_t)NN*DIMF*4);
    float* XU  = (float*)salloc((size_t)NN*DIMF*4);
    float* DN[4]; for (int l = 0; l < 4; ++l) DN[l] = (float*)salloc((size_t)NN*DIMF*4);
    float* Asub[4];
    for (int l = 0; l < 4; ++l) Asub[l] = (float*)salloc((size_t)LVL_K[l]*LVL_K[l]*4);
    float* SC = (float*)salloc(NN*4);
    int*   IDX[4]; for (int l = 0; l < 4; ++l) IDX[l] = (int*)salloc(NN*4);
    float* VAL[4]; for (int l = 0; l < 4; ++l) VAL[l] = (float*)salloc(NN*4);
    float* XC  = (float*)salloc((size_t)NN*2*DIMF*4);
    float* AXC = (float*)salloc((size_t)NN*2*DIMF*4);

    // P3 overlay (eigensolver scratch)
    const size_t PL = (size_t)NN*NN*8;
    double* Z64 = (double*)(SBASE);
    double* FD  = (double*)(SBASE + PL);       // doubles as Pmat during sytrd, Vbig during WY
    double* FL  = (double*)(SBASE + 2*PL);     // doubles as Tbig during WY
    double* FU  = (double*)(SBASE + 3*PL);
    double* FU2 = (double*)(SBASE + 4*PL);
    signed char* FPIV = (signed char*)(SBASE + 5*PL);
    double* Pmat = FD;
    double* Vbig = FD;
    double* Tbig = FL;

    // P4 overlay (GSR / refinement)
    const size_t MB8  = (size_t)HRD*NN*4;    // 8 MiB
    const size_t MB16 = (size_t)HRD*HRD*4;   // 16 MiB
    float* P4a   = (float*)(SBASE);
    float* P4t1  = (float*)(SBASE + MB8);
    float* P4adT = (float*)(SBASE);
    float* P4Zb  = (float*)(SBASE + MB16);
    float* P4ZG  = (float*)(SBASE);
    float* P4h1  = (float*)(SBASE + MB8);
    float* P4HG  = (float*)(SBASE + MB16);
    float* P4h2  = (float*)(SBASE);

    // =============== P1: normalized adjacency ===============
    rowsum_rsqrt_k<<<NN, 256, 0, stream>>>(lr, r64, NN);
    build_A_k<<<(NN*NN + 255)/256, 256, 0, stream>>>(lr, r64, A32, A64, NN);

    // =============== P2: graph U-Net (fp32) ===============
    gemmf32(stream, EPI_BIAS, A32, start_w, out_start, NN, DIMF, NN, start_b, nullptr);

    const float* Xcur = out_start;
    const float* Acur = A32;
    float* ping = XP1; float* pong = XP2;
    for (int l = 0; l < 4; ++l){
        int nl = LVL_N[l], kl = LVL_K[l];
        gemmf32(stream, EPI_NONE, Acur, Xcur, XT, nl, DIMF, nl, nullptr, nullptr);
        gemmf32(stream, EPI_BIAS, XT, down_w + (size_t)l*DIMF*DIMF, DN[l], nl, DIMF, DIMF,
                down_b + (size_t)l*DIMF, nullptr);
        score_k<<<(nl + 3)/4, 256, 0, stream>>>(DN[l], pool_w + (size_t)l*DIMF, pool_b + l, SC, nl, DIMF);
        topk_k<<<1, 256, 0, stream>>>(SC, nl, kl, IDX[l], VAL[l]);
        gatherX_k<<<(unsigned)(((size_t)kl*DIMF + 255)/256), 256, 0, stream>>>(DN[l], IDX[l], VAL[l], ping, kl, DIMF);
        gatherA_k<<<(unsigned)(((size_t)kl*kl + 255)/256), 256, 0, stream>>>(Acur, IDX[l], Asub[l], kl, nl);
        Xcur = ping; Acur = Asub[l];
        float* t = ping; ping = pong; pong = t;
    }
    gemmf32(stream, EPI_NONE, Acur, Xcur, XT, 193, DIMF, 193, nullptr, nullptr);
    float* Xb = ping;
    gemmf32(stream, EPI_BIAS, XT, bottom_w, Xb, 193, DIMF, DIMF, bottom_b, nullptr);
    const float* Xup = Xb;
    float* upbuf[2] = { (Xb == XP1) ? XP2 : XP1, (Xb == XP1) ? XP1 : XP2 };
    for (int i2 = 0; i2 < 4; ++i2){
        int jl = 3 - i2;
        int nj = LVL_N[jl];
        int kj = LVL_K[jl];
        fill0_k<<<(unsigned)(((size_t)nj*DIMF + 255)/256), 256, 0, stream>>>(XU, (size_t)nj*DIMF);
        scatterX_k<<<(unsigned)(((size_t)kj*DIMF + 255)/256), 256, 0, stream>>>(Xup, IDX[jl], XU, kj, DIMF);
        const float* Aj = (jl == 0) ? A32 : Asub[jl - 1];
        gemmf32(stream, EPI_NONE, Aj, XU, XT, nj, DIMF, nj, nullptr, nullptr);
        float* Xn = upbuf[i2 & 1];
        gemmf32(stream, EPI_BIAS_ADD, XT, up_w + (size_t)i2*DIMF*DIMF, Xn, nj, DIMF, DIMF,
                up_b + (size_t)i2*DIMF, DN[jl]);
        Xup = Xn;
    }
    concat_k<<<(unsigned)(((size_t)NN*2*DIMF + 255)/256), 256, 0, stream>>>(Xup, out_start, XC, NN, DIMF);
    gemmf32(stream, EPI_NONE, A32, XC, AXC, NN, 2*DIMF, NN, nullptr, nullptr);
    gemmf32(stream, EPI_BIAS, AXC, end_w, out_net, NN, HRD, 2*DIMF, end_b, nullptr);

    // =============== P3: eigendecomposition of A (fp64) ===============
    const int JEND = NN - TB;
    init_sytrd_k<<<4, 256, 0, stream>>>(pvA, barcnt, NN);
    filld0_k<<<(unsigned)(((size_t)JEND*NN + 255)/256), 256, 0, stream>>>(Pmat, (size_t)JEND*NN);
    sytrd_coop6<<<CB3, BT3, 0, stream>>>(A64, dE, dTau, dScl, Pmat, pvA, Rst, barcnt, NN, JEND);
    hh_tail<<<1, 256, 0, stream>>>(A64, dE, dTau, dScl, NN);
    extract_de_k<<<4, 256, 0, stream>>>(A64, dD, dE, NN);
    bisect_k<<<4, 256, 0, stream>>>(dD, dE, dWev, NN);
    invit_k<<<4, 256, 0, stream>>>(dD, dE, dWev, FD, FL, FU, FU2, FPIV, Z64, NN);
    wy_buildV_k<<<(unsigned)(((size_t)NWY*1024*64 + 255)/256), 256, 0, stream>>>(A64, dScl, Vbig, NN);
    wy_buildT_k<<<NWY, 256, 0, stream>>>(Vbig, dTau, Tbig, NN);
    wy_apply_k<<<NN/16, 256, 0, stream>>>(Vbig, Tbig, Z64, NN);
    {
        dim3 g(NN/32, NN/32), b(256);
        transpose_cast_k<<<g, b, 0, stream>>>(Z64, UfT, NN);
    }

    // =============== P4: GSR layer + refinement (fp32) ===============
    build_a_k<<<(unsigned)(((size_t)HRD*NN + 255)/256), 256, 0, stream>>>(gsr_w, P4a);
    gemmf32(stream, EPI_NONE, P4a, UfT, P4t1, HRD, NN, NN, nullptr, nullptr);               // a @ U^T
    gemmf32(stream, EPI_ABS_DIAG1, P4t1, out_net, out_adj, HRD, HRD, NN, nullptr, nullptr); // adj
    {
        dim3 g(HRD/32, HRD/32), b(256);
        transpose32_k<<<g, b, 0, stream>>>(out_adj, P4adT, HRD);                            // adj^T
    }
    gemmf32(stream, EPI_NONE, out_adj, P4adT, P4Zb, HRD, HRD, HRD, nullptr, nullptr);       // adj @ adj^T
    symabs1_k<<<(unsigned)(((size_t)HRD*HRD + 255)/256), 256, 0, stream>>>(P4Zb, HRD);      // Z
    gemmf32(stream, EPI_NONE, P4Zb, gc1, P4ZG, HRD, NN, HRD, nullptr, nullptr);             // Z @ gc1
    gemmf32(stream, EPI_RELU, out_adj, P4ZG, P4h1, HRD, NN, HRD, nullptr, nullptr);         // h1
    gemmf32(stream, EPI_NONE, P4h1, gc2, P4HG, HRD, HRD, NN, nullptr, nullptr);             // h1 @ gc2
    gemmf32(stream, EPI_RELU, out_adj, P4HG, P4h2, HRD, HRD, HRD, nullptr, nullptr);        // h2
    final_z_k<<<(unsigned)(((size_t)HRD*HRD + 255)/256), 256, 0, stream>>>(P4h2, out_z, HRD); // z
}

// Round 4
// 18827.692 us; speedup vs baseline: 1.2755x; 1.0252x over previous
//
#include <hip/hip_runtime.h>
#include <cstddef>
#include <cstdint>
#include <math.h>

// ============================ constants ============================
static constexpr int NN   = 1024;   // lr_dim
static constexpr int HRD  = 2048;   // hr_dim
static constexpr int DIMF = 320;
static constexpr int TB   = 85;     // sytrd LDS tail block
static constexpr int CB3  = 128;    // persistent sytrd blocks (8 rows each)
static constexpr int BT3  = 1024;   // threads per sytrd block (16 waves)
static constexpr int NWY  = 16;     // WY reflector groups (64 each)

#define EPI_NONE      0
#define EPI_BIAS      1
#define EPI_BIAS_ADD  2
#define EPI_ABS_DIAG1 3
#define EPI_RELU      4

// agent-scope coherent access helpers (sc1).
__device__ __forceinline__ double gload(const double* p){
    return __hip_atomic_load(p, __ATOMIC_RELAXED, __HIP_MEMORY_SCOPE_AGENT);
}
__device__ __forceinline__ void gstore(double* p, double v){
    __hip_atomic_store(p, v, __ATOMIC_RELAXED, __HIP_MEMORY_SCOPE_AGENT);
}

// ============================ fp32 GEMM 64-tile (fallback, odd K) ============================
template<int EPI>
__global__ __launch_bounds__(256) void gemm32(
    const float* __restrict__ A, const float* __restrict__ B, float* __restrict__ C,
    int M, int N, int K, const float* __restrict__ bias, const float* __restrict__ D)
{
    __shared__ float As[16][65];
    __shared__ float Bs[16][65];
    const int bm = blockIdx.y << 6, bn = blockIdx.x << 6;
    const int tid = threadIdx.x;
    const int tm = (tid >> 4) << 2, tn = (tid & 15) << 2;
    float acc[4][4] = {};
    const int kt = (K + 15) >> 4;
    for (int k0 = 0; k0 < kt; ++k0){
        const int kb = k0 << 4;
        for (int t = tid; t < 1024; t += 256){
            int m = t >> 4, k = t & 15;
            int gm = bm + m, gk = kb + k;
            As[k][m] = (gm < M && gk < K) ? A[(size_t)gm*K + gk] : 0.f;
        }
        for (int t = tid; t < 1024; t += 256){
            int k = t >> 6, nn2 = t & 63;
            int gk = kb + k, gn = bn + nn2;
            Bs[k][nn2] = (gk < K && gn < N) ? B[(size_t)gk*N + gn] : 0.f;
        }
        __syncthreads();
        #pragma unroll
        for (int k = 0; k < 16; ++k){
            float a0 = As[k][tm], a1 = As[k][tm+1], a2 = As[k][tm+2], a3 = As[k][tm+3];
            float b0 = Bs[k][tn], b1 = Bs[k][tn+1], b2 = Bs[k][tn+2], b3 = Bs[k][tn+3];
            acc[0][0] += a0*b0; acc[0][1] += a0*b1; acc[0][2] += a0*b2; acc[0][3] += a0*b3;
            acc[1][0] += a1*b0; acc[1][1] += a1*b1; acc[1][2] += a1*b2; acc[1][3] += a1*b3;
            acc[2][0] += a2*b0; acc[2][1] += a2*b1; acc[2][2] += a2*b2; acc[2][3] += a2*b3;
            acc[3][0] += a3*b0; acc[3][1] += a3*b1; acc[3][2] += a3*b2; acc[3][3] += a3*b3;
        }
        __syncthreads();
    }
    #pragma unroll
    for (int r = 0; r < 4; ++r){
        int gm = bm + tm + r; if (gm >= M) continue;
        #pragma unroll
        for (int c = 0; c < 4; ++c){
            int gn = bn + tn + c; if (gn >= N) continue;
            float v = acc[r][c];
            if (EPI == EPI_BIAS)            v += bias[gn];
            else if (EPI == EPI_BIAS_ADD)   v += bias[gn] + D[(size_t)gm*N + gn];
            else if (EPI == EPI_ABS_DIAG1)  v = (gm == gn) ? 1.0f : fabsf(v);
            else if (EPI == EPI_RELU)       v = fmaxf(v, 0.0f);
            C[(size_t)gm*N + gn] = v;
        }
    }
}

// ============================ fp32 GEMM 64x128 double-buffered (K%16==0, N%8==0) ============================
template<int EPI>
__global__ __launch_bounds__(128) void gemm_db(
    const float* __restrict__ A, const float* __restrict__ B, float* __restrict__ C,
    int M, int N, int K, const float* __restrict__ bias, const float* __restrict__ D)
{
    __shared__ float As[2][16][68];
    __shared__ float Bs[2][16][132];
    const int bm = blockIdx.y << 6;
    const int bn = blockIdx.x << 7;
    const int tid = threadIdx.x;
    const int tm = (tid >> 4) << 3;
    const int tn = (tid & 15) << 3;
    const int ar = tid >> 2;
    const int af = tid & 3;
    const int br = tid >> 5;
    const int bf = tid & 31;

    float4 a_reg[2], b_reg[4];

    auto loadA = [&](int kb, int q) -> float4 {
        int gm = bm + ar + (q << 5);
        int gk = kb + (af << 2);
        if (gm < M) return *(const float4*)(A + (size_t)gm*K + gk);
        return make_float4(0.f,0.f,0.f,0.f);
    };
    auto loadB = [&](int kb, int q) -> float4 {
        int gk = kb + br + (q << 2);
        int gn = bn + (bf << 2);
        if (gn < N) return *(const float4*)(B + (size_t)gk*N + gn);
        return make_float4(0.f,0.f,0.f,0.f);
    };
    auto stash = [&](int p){
        #pragma unroll
        for (int q = 0; q < 2; ++q){
            int r = ar + (q << 5);
            As[p][(af<<2)+0][r] = a_reg[q].x; As[p][(af<<2)+1][r] = a_reg[q].y;
            As[p][(af<<2)+2][r] = a_reg[q].z; As[p][(af<<2)+3][r] = a_reg[q].w;
        }
        #pragma unroll
        for (int q = 0; q < 4; ++q)
            *(float4*)&Bs[p][br + (q<<2)][bf << 2] = b_reg[q];
    };

    #pragma unroll
    for (int q = 0; q < 2; ++q) a_reg[q] = loadA(0, q);
    #pragma unroll
    for (int q = 0; q < 4; ++q) b_reg[q] = loadB(0, q);
    stash(0);
    __syncthreads();

    float acc[8][8] = {};
    int p = 0;
    for (int kb = 16; ; kb += 16){
        const bool more = (kb < K);
        if (more){
            #pragma unroll
            for (int q = 0; q < 2; ++q) a_reg[q] = loadA(kb, q);
            #pragma unroll
            for (int q = 0; q < 4; ++q) b_reg[q] = loadB(kb, q);
        }
        #pragma unroll
        for (int k = 0; k < 16; ++k){
            float4 a0 = *(const float4*)&As[p][k][tm];
            float4 a1 = *(const float4*)&As[p][k][tm+4];
            float4 b0 = *(const float4*)&Bs[p][k][tn];
            float4 b1 = *(const float4*)&Bs[p][k][tn+4];
            float av[8] = {a0.x,a0.y,a0.z,a0.w,a1.x,a1.y,a1.z,a1.w};
            float bv[8] = {b0.x,b0.y,b0.z,b0.w,b1.x,b1.y,b1.z,b1.w};
            #pragma unroll
            for (int i = 0; i < 8; ++i)
                #pragma unroll
                for (int jj = 0; jj < 8; ++jj) acc[i][jj] += av[i]*bv[jj];
        }
        if (!more) break;
        stash(p ^ 1);
        __syncthreads();
        p ^= 1;
    }
    #pragma unroll
    for (int i = 0; i < 8; ++i){
        int gm = bm + tm + i; if (gm >= M) continue;
        #pragma unroll
        for (int jj = 0; jj < 8; ++jj){
            int gn = bn + tn + jj; if (gn >= N) continue;
            float v = acc[i][jj];
            if (EPI == EPI_BIAS)            v += bias[gn];
            else if (EPI == EPI_BIAS_ADD)   v += bias[gn] + D[(size_t)gm*N + gn];
            else if (EPI == EPI_ABS_DIAG1)  v = (gm == gn) ? 1.0f : fabsf(v);
            else if (EPI == EPI_RELU)       v = fmaxf(v, 0.0f);
            C[(size_t)gm*N + gn] = v;
        }
    }
}

// ============================ fp32 GEMM 128x128 double-buffered (K%16==0, N%8==0, big M) ============================
// 256 threads, 8x8 acc/thread, ping-pong LDS, one sync per K-tile. Same k-order as gemm_db.
template<int EPI>
__global__ __launch_bounds__(256) void gemm128db(
    const float* __restrict__ A, const float* __restrict__ B, float* __restrict__ C,
    int M, int N, int K, const float* __restrict__ bias, const float* __restrict__ D)
{
    __shared__ float As[2][16][132];
    __shared__ float Bs[2][16][132];
    const int bm = blockIdx.y << 7, bn = blockIdx.x << 7;
    const int tid = threadIdx.x;
    const int tm = (tid >> 4) << 3;
    const int tn = (tid & 15) << 3;
    const int ar = tid >> 1;         // 0..127
    const int ak = (tid & 1) << 3;   // 0/8
    const int br = tid >> 4;         // 0..15
    const int bc = (tid & 15) << 3;  // 0..120

    float4 a0r, a1r, b0r, b1r;

    auto loadA = [&](int kb){
        int gm = bm + ar, gk = kb + ak;
        if (gm < M){
            const float* p = A + (size_t)gm*K + gk;
            a0r = *(const float4*)p; a1r = *(const float4*)(p + 4);
        } else { a0r = make_float4(0.f,0.f,0.f,0.f); a1r = a0r; }
    };
    auto loadB = [&](int kb){
        int gk = kb + br, gn = bn + bc;
        if (gn + 7 < N){
            const float* p = B + (size_t)gk*N + gn;
            b0r = *(const float4*)p; b1r = *(const float4*)(p + 4);
        } else {
            float t0[8];
            #pragma unroll
            for (int i = 0; i < 8; ++i){ int g2 = gn + i; t0[i] = (g2 < N) ? B[(size_t)gk*N + g2] : 0.f; }
            b0r = make_float4(t0[0],t0[1],t0[2],t0[3]); b1r = make_float4(t0[4],t0[5],t0[6],t0[7]);
        }
    };
    auto stash = [&](int p){
        As[p][ak+0][ar]=a0r.x; As[p][ak+1][ar]=a0r.y; As[p][ak+2][ar]=a0r.z; As[p][ak+3][ar]=a0r.w;
        As[p][ak+4][ar]=a1r.x; As[p][ak+5][ar]=a1r.y; As[p][ak+6][ar]=a1r.z; As[p][ak+7][ar]=a1r.w;
        *(float4*)&Bs[p][br][bc] = b0r; *(float4*)&Bs[p][br][bc+4] = b1r;
    };

    loadA(0); loadB(0); stash(0);
    __syncthreads();

    float acc[8][8] = {};
    int p = 0;
    for (int kb = 16; ; kb += 16){
        const bool more = (kb < K);
        if (more){ loadA(kb); loadB(kb); }
        #pragma unroll
        for (int k = 0; k < 16; ++k){
            float4 a0 = *(const float4*)&As[p][k][tm];
            float4 a1 = *(const float4*)&As[p][k][tm+4];
            float4 b0 = *(const float4*)&Bs[p][k][tn];
            float4 b1 = *(const float4*)&Bs[p][k][tn+4];
            float av[8] = {a0.x,a0.y,a0.z,a0.w,a1.x,a1.y,a1.z,a1.w};
            float bv[8] = {b0.x,b0.y,b0.z,b0.w,b1.x,b1.y,b1.z,b1.w};
            #pragma unroll
            for (int i = 0; i < 8; ++i)
                #pragma unroll
                for (int jj = 0; jj < 8; ++jj) acc[i][jj] += av[i]*bv[jj];
        }
        if (!more) break;
        stash(p ^ 1);
        __syncthreads();
        p ^= 1;
    }
    #pragma unroll
    for (int i = 0; i < 8; ++i){
        int gm = bm + tm + i; if (gm >= M) continue;
        #pragma unroll
        for (int jj = 0; jj < 8; ++jj){
            int gn = bn + tn + jj; if (gn >= N) continue;
            float v = acc[i][jj];
            if (EPI == EPI_BIAS)            v += bias[gn];
            else if (EPI == EPI_BIAS_ADD)   v += bias[gn] + D[(size_t)gm*N + gn];
            else if (EPI == EPI_ABS_DIAG1)  v = (gm == gn) ? 1.0f : fabsf(v);
            else if (EPI == EPI_RELU)       v = fmaxf(v, 0.0f);
            C[(size_t)gm*N + gn] = v;
        }
    }
}

// ============================ symmetric C = A @ A^T (B = A^T given), n%128==0 ============================
// Z[i][j] and Z[j][i] are bitwise identical (same products, same k order) -> compute only
// upper tile pairs (ti<=tj) and mirror-store. Saves ~47% of the FMA work.
__global__ __launch_bounds__(256) void gemm_symAAT(
    const float* __restrict__ A, const float* __restrict__ Bt, float* __restrict__ C, int n)
{
    __shared__ float As[2][16][132];
    __shared__ float Bs[2][16][132];
    const int T = n >> 7;
    int ti = 0, rem = blockIdx.x;
    while (rem >= T - ti){ rem -= T - ti; ++ti; }
    const int tj = ti + rem;
    const int bm = ti << 7, bn = tj << 7;
    const int tid = threadIdx.x;
    const int tm = (tid >> 4) << 3;
    const int tn = (tid & 15) << 3;
    const int ar = tid >> 1;
    const int ak = (tid & 1) << 3;
    const int br = tid >> 4;
    const int bc = (tid & 15) << 3;

    float4 a0r, a1r, b0r, b1r;
    auto loadA = [&](int kb){
        const float* p = A + (size_t)(bm + ar)*n + kb + ak;
        a0r = *(const float4*)p; a1r = *(const float4*)(p + 4);
    };
    auto loadB = [&](int kb){
        const float* p = Bt + (size_t)(kb + br)*n + bn + bc;
        b0r = *(const float4*)p; b1r = *(const float4*)(p + 4);
    };
    auto stash = [&](int p){
        As[p][ak+0][ar]=a0r.x; As[p][ak+1][ar]=a0r.y; As[p][ak+2][ar]=a0r.z; As[p][ak+3][ar]=a0r.w;
        As[p][ak+4][ar]=a1r.x; As[p][ak+5][ar]=a1r.y; As[p][ak+6][ar]=a1r.z; As[p][ak+7][ar]=a1r.w;
        *(float4*)&Bs[p][br][bc] = b0r; *(float4*)&Bs[p][br][bc+4] = b1r;
    };

    loadA(0); loadB(0); stash(0);
    __syncthreads();

    float acc[8][8] = {};
    int p = 0;
    for (int kb = 16; ; kb += 16){
        const bool more = (kb < n);
        if (more){ loadA(kb); loadB(kb); }
        #pragma unroll
        for (int k = 0; k < 16; ++k){
            float4 a0 = *(const float4*)&As[p][k][tm];
            float4 a1 = *(const float4*)&As[p][k][tm+4];
            float4 b0 = *(const float4*)&Bs[p][k][tn];
            float4 b1 = *(const float4*)&Bs[p][k][tn+4];
            float av[8] = {a0.x,a0.y,a0.z,a0.w,a1.x,a1.y,a1.z,a1.w};
            float bv[8] = {b0.x,b0.y,b0.z,b0.w,b1.x,b1.y,b1.z,b1.w};
            #pragma unroll
            for (int i = 0; i < 8; ++i)
                #pragma unroll
                for (int jj = 0; jj < 8; ++jj) acc[i][jj] += av[i]*bv[jj];
        }
        if (!more) break;
        stash(p ^ 1);
        __syncthreads();
        p ^= 1;
    }
    #pragma unroll
    for (int i = 0; i < 8; ++i){
        #pragma unroll
        for (int jj = 0; jj < 8; ++jj)
            C[(size_t)(bm + tm + i)*n + (bn + tn + jj)] = acc[i][jj];
    }
    if (ti != tj){
        #pragma unroll
        for (int i = 0; i < 8; ++i)
            #pragma unroll
            for (int jj = 0; jj < 8; ++jj)
                C[(size_t)(bn + tn + jj)*n + (bm + tm + i)] = acc[i][jj];
    }
}

// ============================ small kernels ============================
__global__ __launch_bounds__(256) void rowsum_rsqrt_k(const float* __restrict__ lr, double* __restrict__ r64, int n)
{
    __shared__ double sm[256];
    int row = blockIdx.x;
    double s = 0.0;
    for (int j = threadIdx.x; j < n; j += 256) s += (double)lr[(size_t)row*n + j];
    sm[threadIdx.x] = s; __syncthreads();
    for (int o = 128; o; o >>= 1){ if (threadIdx.x < o) sm[threadIdx.x] += sm[threadIdx.x + o]; __syncthreads(); }
    if (threadIdx.x == 0){
        double t = sm[0];
        r64[row] = (t > 0.0) ? 1.0/sqrt(t) : 0.0;
    }
}

__global__ __launch_bounds__(256) void build_A_k(const float* __restrict__ lr, const double* __restrict__ r64,
                                                 float* __restrict__ A32, double* __restrict__ A64, int n)
{
    size_t idx = (size_t)blockIdx.x*256 + threadIdx.x;
    if (idx >= (size_t)n*n) return;
    int i = (int)(idx / n), j = (int)(idx % n);
    if (j < i) return;
    double v = (double)lr[(size_t)j*n + i] * r64[i] * r64[j];
    A64[(size_t)i*n + j] = v; A64[(size_t)j*n + i] = v;
    float vf = (float)v;
    A32[(size_t)i*n + j] = vf; A32[(size_t)j*n + i] = vf;
}

__global__ __launch_bounds__(256) void score_k(const float* __restrict__ X, const float* __restrict__ pw,
                                               const float* __restrict__ pb, float* __restrict__ out,
                                               int n, int dim)
{
    int row = blockIdx.x*4 + (threadIdx.x >> 6);
    int lane = threadIdx.x & 63;
    if (row >= n) return;
    float acc = 0.f;
    for (int c = lane; c < dim; c += 64) acc += X[(size_t)row*dim + c]*pw[c];
    #pragma unroll
    for (int o = 32; o; o >>= 1) acc += __shfl_down(acc, o);
    if (lane == 0){
        float t = (acc + pb[0]) * 0.01f;
        out[row] = 1.0f/(1.0f + expf(-t));
    }
}

// jax.lax.top_k semantics: descending value, ties -> lower index first
__global__ __launch_bounds__(256) void topk_k(const float* __restrict__ scores, int n, int k,
                                              int* __restrict__ idxo, float* __restrict__ valo)
{
    __shared__ float s[1024];
    int tid = threadIdx.x;
    for (int i = tid; i < n; i += 256) s[i] = scores[i];
    __syncthreads();
    for (int i = tid; i < n; i += 256){
        float si = s[i]; int r = 0;
        for (int j = 0; j < n; ++j){
            float sj = s[j];
            r += (sj > si) || (sj == si && j < i);
        }
        if (r < k){ idxo[r] = i; valo[r] = si; }
    }
}

__global__ __launch_bounds__(256) void gatherX_k(const float* __restrict__ X, const int* __restrict__ idx,
                                                 const float* __restrict__ vals, float* __restrict__ Xo,
                                                 int k, int dim)
{
    size_t t = (size_t)blockIdx.x*256 + threadIdx.x;
    if (t >= (size_t)k*dim) return;
    int m = (int)(t / dim), c = (int)(t % dim);
    Xo[t] = X[(size_t)idx[m]*dim + c] * vals[m];
}

__global__ __launch_bounds__(256) void scatterX_k(const float* __restrict__ Xs, const int* __restrict__ idx,
                                                  float* __restrict__ Xu, int k, int dim)
{
    size_t t = (size_t)blockIdx.x*256 + threadIdx.x;
    if (t >= (size_t)k*dim) return;
    int m = (int)(t / dim), c = (int)(t % dim);
    Xu[(size_t)idx[m]*dim + c] = Xs[t];
}

__global__ __launch_bounds__(256) void gatherA_k(const float* __restrict__ A, const int* __restrict__ idx,
                                                 float* __restrict__ Ao, int k, int n)
{
    size_t t = (size_t)blockIdx.x*256 + threadIdx.x;
    if (t >= (size_t)k*k) return;
    int m1 = (int)(t / k), m2 = (int)(t % k);
    Ao[t] = A[(size_t)idx[m1]*n + idx[m2]];
}

__global__ __launch_bounds__(256) void fill0_k(float* __restrict__ p, size_t cnt)
{
    size_t t = (size_t)blockIdx.x*256 + threadIdx.x;
    if (t < cnt) p[t] = 0.f;
}

__global__ __launch_bounds__(256) void filld0_k(double* __restrict__ p, size_t cnt)
{
    size_t t = (size_t)blockIdx.x*256 + threadIdx.x;
    if (t < cnt) p[t] = 0.0;
}

__global__ __launch_bounds__(256) void init_sytrd_k(double* __restrict__ pv, unsigned* __restrict__ bar, int n)
{
    int t = blockIdx.x*256 + threadIdx.x;
    if (t < n) pv[t] = 0.0;
    if (t < 1024) bar[t] = 0u;
}

__global__ __launch_bounds__(256) void concat_k(const float* __restrict__ X, const float* __restrict__ orgX,
                                                float* __restrict__ Xc, int n, int dim)
{
    size_t t = (size_t)blockIdx.x*256 + threadIdx.x;
    size_t tot = (size_t)n*2*dim;
    if (t >= tot) return;
    int i = (int)(t / (2*dim)), c = (int)(t % (2*dim));
    Xc[t] = (c < dim) ? X[(size_t)i*dim + c] : orgX[(size_t)i*dim + (c - dim)];
}

__global__ __launch_bounds__(256) void build_a_k(const float* __restrict__ gsr, float* __restrict__ a)
{
    size_t idx = (size_t)blockIdx.x*256 + threadIdx.x;
    if (idx >= (size_t)HRD*NN) return;
    int i = (int)(idx >> 10), k = (int)(idx & 1023);
    a[idx] = gsr[(size_t)i*HRD + k] + gsr[(size_t)i*HRD + NN + k];
}

__global__ __launch_bounds__(256) void symabs1_k(float* __restrict__ Z, int n)
{
    size_t idx = (size_t)blockIdx.x*256 + threadIdx.x;
    if (idx >= (size_t)n*n) return;
    int i = (int)(idx / n), j = (int)(idx % n);
    if (i > j) return;
    float a = Z[(size_t)i*n + j], b = Z[(size_t)j*n + i];
    float v = 0.5f*(a + b);
    float o = (i == j) ? 1.0f : fabsf(v);
    Z[(size_t)i*n + j] = o; Z[(size_t)j*n + i] = o;
}

__global__ __launch_bounds__(256) void final_z_k(const float* __restrict__ h2, float* __restrict__ z, int n)
{
    size_t idx = (size_t)blockIdx.x*256 + threadIdx.x;
    if (idx >= (size_t)n*n) return;
    int i = (int)(idx / n), j = (int)(idx % n);
    if (i > j) return;
    float v = 0.5f*(h2[(size_t)i*n + j] + h2[(size_t)j*n + i]);
    float o = (i == j) ? 1.0f : fabsf(v);
    z[(size_t)i*n + j] = o; z[(size_t)j*n + i] = o;
}

// dst[c][r] = (float)src[r][c]   (n x n, n % 32 == 0)
__global__ __launch_bounds__(256) void transpose_cast_k(const double* __restrict__ src, float* __restrict__ dst, int n)
{
    __shared__ float tile[32][33];
    int r0 = blockIdx.y*32, c0 = blockIdx.x*32;
    int tx = threadIdx.x & 31, ty = threadIdx.x >> 5;
    for (int i = ty; i < 32; i += 8)
        tile[i][tx] = (float)src[(size_t)(r0 + i)*n + (c0 + tx)];
    __syncthreads();
    for (int i = ty; i < 32; i += 8)
        dst[(size_t)(c0 + i)*n + (r0 + tx)] = tile[tx][i];
}

// dst[c][r] = src[r][c]  (n x n, n % 32 == 0)
__global__ __launch_bounds__(256) void transpose32_k(const float* __restrict__ src, float* __restrict__ dst, int n)
{
    __shared__ float tile[32][33];
    int r0 = blockIdx.y*32, c0 = blockIdx.x*32;
    int tx = threadIdx.x & 31, ty = threadIdx.x >> 5;
    for (int i = ty; i < 32; i += 8)
        tile[i][tx] = src[(size_t)(r0 + i)*n + (c0 + tx)];
    __syncthreads();
    for (int i = ty; i < 32; i += 8)
        dst[(size_t)(c0 + i)*n + (r0 + tx)] = tile[tx][i];
}

// ============================ persistent Householder tridiagonalization ============================
// sytrd_coop7: like coop6 but pvA is ELIMINATED. pv = sum_r P[j-1][r]*v_r is computed
// redundantly per block inside the fused phase-A pass (piggyback LDS reduction) instead of a
// global atomic + vmcnt drain on the arrival critical path. The x-recurrence uses the
// IDENTICAL formula/rounding as before, just evaluated after the pv reduction.
__global__ __launch_bounds__(BT3) void sytrd_coop7(
    double* __restrict__ A, double* __restrict__ e, double* __restrict__ tauA,
    double* __restrict__ sclA, double* __restrict__ P,
    double* __restrict__ Rst, unsigned* __restrict__ bar, int n, int jend)
{
    __shared__ double VP[1024], WP[1024], VJ2[2][1024];
    __shared__ double redA[16], redB[16];
    const int tid   = threadIdx.x;
    const int bid   = blockIdx.x;
    const int lane  = tid & 63;
    const int wid   = tid >> 6;
    const int rwav  = wid >> 1;
    const int half  = wid & 1;
    const int u     = (bid << 3) + rwav;
    const int g     = bid >> 4;
    const int mylast = (bid << 3) + 7;

    double tau_p = 0.0, sc_p = 0.0;
    unsigned cumG = 0, cumC = 0;

    for (int j = 0; j < jend; ++j){
        const int m = n - 1 - j;
        double* __restrict__ VJnew = VJ2[j & 1];
        const double* __restrict__ VJold = VJ2[(j & 1) ^ 1];

        {
            const int retired = j >> 3;
            int d = retired - (g << 4);
            d = (d < 0) ? 0 : (d > 16 ? 16 : d);
            cumG += (unsigned)(16 - d);
            cumC += (unsigned)(8 - (j >> 7));
        }

        // ---- fused phase A + pivot row; pv via block-local reduction ----
        double s = 0.0, wp0 = 0.0;
        if (j > 0){
            const double* __restrict__ Prow = P + (size_t)(j-1)*NN;
            const double* __restrict__ rs   = Rst + ((size_t)(j & 1) << 10);
            const double p0 = gload(&Prow[0]);
            double pi = 0.0, rsi = 0.0, vp = 0.0, pvp = 0.0;
            const bool act = (tid <= m);
            if (act){
                pi = gload(&Prow[tid]);
                if (tid >= 1){ rsi = gload(&rs[tid]); vp = VJold[tid]*sc_p; }
                else vp = 1.0;
                pvp = pi*vp;
            }
            double t = pvp;
            #pragma unroll
            for (int o = 32; o; o >>= 1) t += __shfl_down(t, o);
            if (lane == 0) redA[wid] = t;
            __syncthreads();
            double pv = 0.0;
            #pragma unroll
            for (int i = 0; i < 16; ++i) pv += redA[i];
            const double c2 = 0.5*tau_p*tau_p*pv;
            wp0 = tau_p*p0 - c2;
            if (act){
                double wp = tau_p*pi - c2*vp;
                VP[tid] = vp; WP[tid] = wp;
                if (tid >= 1){
                    double x = rsi - wp - wp0*vp;
                    VJnew[tid-1] = x;
                    if (tid >= 2) s += x*x;
                }
            }
        } else {
            if (tid < m){
                double x = A[1 + tid];   // row 0, fresh from build_A_k
                VJnew[tid] = x;
                if (tid >= 1) s += x*x;
            }
        }
        #pragma unroll
        for (int o = 32; o; o >>= 1) s += __shfl_down(s, o);
        if (lane == 0) redB[wid] = s;
        __syncthreads();     // VP/WP/VJnew visible + redB ready

        double sigma2 = 0.0;
        #pragma unroll
        for (int i = 0; i < 16; ++i) sigma2 += redB[i];
        double alpha = VJnew[0];
        double beta, tl, sc;
        if (sigma2 == 0.0){ beta = alpha; tl = 0.0; sc = 0.0; }
        else {
            beta = -copysign(sqrt(alpha*alpha + sigma2), alpha);
            tl = (beta - alpha)/beta;
            sc = 1.0/(alpha - beta);
        }

        // ---- owner-block writeback of row j ----
        if (bid == (j >> 3)){
            double* __restrict__ row = A + (size_t)j*n + (j+1);
            if (tid < m) row[tid] = VJnew[tid];
            if (tid == 0){
                e[j] = beta; tauA[j] = tl; sclA[j] = sc;
                if (j > 0) A[(size_t)j*n + j] -= 2.0*wp0;
            }
        }

        // ---- phase B: owner-private trailing update + matvec; publish next pivot row ----
        if (u > j){
            const int r = u - (j+1);
            double* __restrict__ Ar   = A + (size_t)u*n + (j+1);
            double* __restrict__ rs_w = Rst + ((size_t)((j+1) & 1) << 10);
            const bool pub = (r == 0);
            double acc = 0.0;
            if (j > 0){
                double vpr = VP[1+r], wpr = WP[1+r];
                for (int c = half*64 + lane; c < m; c += 128){
                    double a = Ar[c] - (vpr*WP[1+c] + wpr*VP[1+c]);
                    Ar[c] = a;
                    if (pub) gstore(&rs_w[c], a);
                    double vj = (c == 0) ? 1.0 : VJnew[c]*sc;
                    acc += a*vj;
                }
            } else {
                for (int c = half*64 + lane; c < m; c += 128){
                    double a = Ar[c];
                    if (pub) gstore(&rs_w[c], a);
                    double vj = (c == 0) ? 1.0 : VJnew[c]*sc;
                    acc += a*vj;
                }
            }
            #pragma unroll
            for (int o = 32; o; o >>= 1) acc += __shfl_down(acc, o);
            if (lane == 0)
                atomicAdd(&P[(size_t)j*NN + r], acc);
        }
        __syncthreads();     // each wave's vmcnt(0) drains its P atomics/Rst stores before tid0 arrives

        if (tid == 0){
            unsigned t = __hip_atomic_fetch_add(&bar[g*32], 1u, __ATOMIC_RELAXED, __HIP_MEMORY_SCOPE_AGENT);
            if (t == cumG - 1u)
                __hip_atomic_fetch_add(&bar[256], 1u, __ATOMIC_RELAXED, __HIP_MEMORY_SCOPE_AGENT);
            if (j != mylast){
                while (__hip_atomic_load(&bar[256], __ATOMIC_RELAXED, __HIP_MEMORY_SCOPE_AGENT) < cumC)
                    __builtin_amdgcn_s_sleep(1);
            }
        }
        if (j == mylast) break;    // retired (block-uniform)
        __syncthreads();           // release after spin
        tau_p = tl; sc_p = sc;
    }

    // ---- final pending update (column jend-1) on the TB x TB tail, owner-only ----
    // Blocks bid >= jend>>3 never break (mylast >= jend-1) -> VJ2/tau_p/sc_p are live.
    if (bid >= (jend >> 3)){
        const int tb = n - jend;
        const double* __restrict__ VJf = VJ2[(jend-1) & 1];
        const double* __restrict__ pp  = P + (size_t)(jend-1)*NN;
        // local pv reduction over r = 0..tb-1
        double pvp = 0.0;
        if (tid < tb){
            double pi = gload(&pp[tid]);
            double v = (tid == 0) ? 1.0 : VJf[tid]*sc_p;
            pvp = pi*v;
        }
        #pragma unroll
        for (int o = 32; o; o >>= 1) pvp += __shfl_down(pvp, o);
        if (lane == 0) redA[wid] = pvp;
        __syncthreads();
        double pv = 0.0;
        #pragma unroll
        for (int i = 0; i < 16; ++i) pv += redA[i];
        double c2f = 0.5*tau_p*tau_p*pv;
        if (u >= jend){
            const int ri = u - jend;
            double vpr = (ri == 0) ? 1.0 : VJf[ri]*sc_p;
            double wpr = tau_p*gload(&pp[ri]) - c2f*vpr;
            double* __restrict__ Ar = A + (size_t)u*n + jend;
            for (int ci = half*64 + lane; ci < tb; ci += 128){
                double vpc = (ci == 0) ? 1.0 : VJf[ci]*sc_p;
                double wpc = tau_p*gload(&pp[ci]) - c2f*vpc;
                Ar[ci] -= vpr*wpc + wpr*vpc;
            }
        }
    }
}

// Tail: remaining (TB-2) Householder steps entirely in LDS (single block).
__global__ __launch_bounds__(256) void hh_tail(double* __restrict__ A64, double* __restrict__ e,
                                               double* __restrict__ tau, double* __restrict__ scaleg, int n)
{
    __shared__ double T[TB][TB+2];
    __shared__ double v[TB], p[TB], red[256];
    const int base = n - TB;
    const int tid = threadIdx.x;
    for (int t = tid; t < TB*TB; t += 256){
        int r = t / TB, c = t % TB;
        T[r][c] = A64[(size_t)(base + r)*n + base + c];
    }
    __syncthreads();
    for (int l = 0; l <= TB - 3; ++l){
        const int m = TB - 1 - l;
        double s = 0.0;
        for (int i = 1 + tid; i < m; i += 256){ double x = T[l+1+i][l]; s += x*x; }
        red[tid] = s; __syncthreads();
        for (int o = 128; o; o >>= 1){ if (tid < o) red[tid] += red[tid + o]; __syncthreads(); }
        double sigma2 = red[0];
        double alpha = T[l+1][l];
        double beta, tl, sc;
        if (sigma2 == 0.0){ beta = alpha; tl = 0.0; sc = 0.0; }
        else {
            beta = -copysign(sqrt(alpha*alpha + sigma2), alpha);
            tl = (beta - alpha)/beta;
            sc = 1.0/(alpha - beta);
        }
        for (int i = tid; i < m; i += 256) v[i] = (i == 0) ? 1.0 : T[l+1+i][l]*sc;
        __syncthreads();
        for (int i = tid; i < m; i += 256){
            double acc = 0.0;
            for (int c = 0; c < m; ++c) acc += T[l+1+i][l+1+c]*v[c];
            p[i] = acc;
        }
        __syncthreads();
        double s2 = 0.0;
        for (int i = tid; i < m; i += 256) s2 += p[i]*v[i];
        red[tid] = s2; __syncthreads();
        for (int o = 128; o; o >>= 1){ if (tid < o) red[tid] += red[tid + o]; __syncthreads(); }
        double pvv = red[0];
        double c2 = 0.5*tl*tl*pvv;
        for (int t2 = tid; t2 < m*m; t2 += 256){
            int r = t2 / m, c = t2 % m;
            double wr = tl*p[r] - c2*v[r];
            double wc = tl*p[c] - c2*v[c];
            T[l+1+r][l+1+c] -= v[r]*wc + wr*v[c];
        }
        if (tid == 0){ int j = base + l; e[j] = beta; tau[j] = tl; scaleg[j] = 1.0; }
        for (int i = tid; i < m; i += 256) A64[(size_t)(base + l)*n + (base + l + 1) + i] = v[i];
        __syncthreads();
    }
    for (int r = tid; r < TB; r += 256) A64[(size_t)(base + r)*n + base + r] = T[r][r];
    if (tid == 0) A64[(size_t)(n-1)*n + (n-2)] = T[TB-1][TB-2];
}

__global__ __launch_bounds__(256) void extract_de_k(const double* __restrict__ A64, double* __restrict__ d,
                                                    double* __restrict__ e, int n)
{
    int i = blockIdx.x*256 + threadIdx.x;
    if (i < n) d[i] = A64[(size_t)i*n + i];
    if (i == 0) e[n-2] = A64[(size_t)(n-1)*n + (n-2)];
}

// ============================ tridiagonal eigensolver ============================
__global__ __launch_bounds__(256) void bisect_k(const double* __restrict__ d, const double* __restrict__ e,
                                                double* __restrict__ w, int n)
{
    __shared__ double ds[1024], e2s[1024];
    const int tid = threadIdx.x;
    for (int i = tid; i < n; i += 256) ds[i] = d[i];
    for (int i = tid; i < n-1; i += 256){ double ei = e[i]; e2s[i] = ei*ei; }
    __syncthreads();
    int k = blockIdx.x*256 + tid;
    if (k >= n) return;
    double gl = 1e300, gu = -1e300;
    for (int i = 0; i < n; ++i){
        double em = (i > 0) ? sqrt(e2s[i-1]) : 0.0, ep2 = (i < n-1) ? sqrt(e2s[i]) : 0.0;
        double lo2 = ds[i] - em - ep2, hi2 = ds[i] + em + ep2;
        gl = fmin(gl, lo2); gu = fmax(gu, hi2);
    }
    double lo = gl - 1e-10, hi = gu + 1e-10;
    for (int it = 0; it < 42; ++it){
        double mid = 0.5*(lo + hi);
        int cnt = 0;
        double p0 = 1.0;
        double p1 = ds[0] - mid;
        if (p1 <= 0.0){ ++cnt; if (p1 == 0.0) p1 = -1e-300; }
        for (int i = 1; i < n; ++i){
            double pn = (ds[i] - mid)*p1 - e2s[i-1]*p0;
            bool neg = ((pn < 0.0) != (p1 < 0.0)) || (pn == 0.0);
            cnt += neg;
            if (pn == 0.0) pn = (p1 > 0.0) ? -1e-300 : 1e-300;
            p0 = p1; p1 = pn;
            double ap = fabs(p1);
            if (ap > 1e120){ p1 *= 1e-200; p0 *= 1e-200; }
            else if (ap < 1e-120){ p1 *= 1e200; p0 *= 1e200; }
        }
        if (cnt <= k) lo = mid; else hi = mid;
    }
    w[k] = 0.5*(lo + hi);
}

// Inverse iteration; 16-deep load prefetch in the dependent solve passes (1024 threads total,
// latency-bound -> MLP is the lever). Recurrence arithmetic order preserved exactly.
__global__ __launch_bounds__(256) void invit_k(const double* __restrict__ d, const double* __restrict__ e,
                                               const double* __restrict__ w,
                                               double* __restrict__ FD, double* __restrict__ FL,
                                               double* __restrict__ FU, double* __restrict__ FU2,
                                               signed char* __restrict__ PIV, double* __restrict__ Z, int n)
{
    __shared__ double dsm[1024], esm[1024];
    const int tid = threadIdx.x;
    for (int i = tid; i < n; i += 256) dsm[i] = d[i];
    for (int i = tid; i < n-1; i += 256) esm[i] = e[i];
    __syncthreads();
    int k = blockIdx.x*256 + tid;
    if (k >= n) return;
    const double lam = w[k];
    const double tiny = 1e-280;
    double dcur = dsm[0] - lam;
    double ucur = esm[0];
    for (int i = 0; i < n-1; ++i){
        double dli = esm[i];
        double dnext_init = dsm[i+1] - lam;
        double unext_init = (i < n-2) ? esm[i+1] : 0.0;
        size_t o = (size_t)i*n + k;
        if (fabs(dcur) >= fabs(dli)){
            if (dcur == 0.0) dcur = tiny;
            double f = dli/dcur;
            FD[o] = dcur; FL[o] = f; FU[o] = ucur; FU2[o] = 0.0; PIV[o] = 0;
            dcur = dnext_init - f*ucur;
            ucur = unext_init;
        } else {
            double f = dcur/dli;
            FD[o] = dli; FL[o] = f; FU[o] = dnext_init; FU2[o] = unext_init; PIV[o] = 1;
            dcur = ucur - f*dnext_init;
            ucur = -f*unext_init;
        }
    }
    if (dcur == 0.0) dcur = tiny;
    FD[(size_t)(n-1)*n + k] = dcur;
    for (int i = 0; i < n; ++i){
        unsigned h = (unsigned)(i + 1)*0x9E3779B9u + (unsigned)(k + 1)*0x85EBCA6Bu;
        h ^= h >> 16; h *= 0x7FEB352Du; h ^= h >> 15; h *= 0x846CA68Bu; h ^= h >> 16;
        Z[(size_t)i*n + k] = (double)(h >> 8)*(1.0/16777216.0) - 0.5;
    }
    const double fdlast = FD[(size_t)(n-1)*n + k];
    for (int iter = 0; iter < 2; ++iter){
        // ---- forward substitution (prefetch-16) ----
        double zc = Z[k];
        int i = 0;
        const int nm1 = n - 1;
        for (; i + 16 <= nm1; i += 16){
            double fl[16], zn[16]; int pv[16];
            #pragma unroll
            for (int u2 = 0; u2 < 16; ++u2){
                size_t o = (size_t)(i+u2)*n + k;
                fl[u2] = FL[o]; zn[u2] = Z[o + n]; pv[u2] = PIV[o];
            }
            #pragma unroll
            for (int u2 = 0; u2 < 16; ++u2){
                size_t o = (size_t)(i+u2)*n + k;
                if (!pv[u2]){ Z[o] = zc; zc = zn[u2] - fl[u2]*zc; }
                else        { Z[o] = zn[u2]; zc = zc - fl[u2]*zn[u2]; }
            }
        }
        for (; i < nm1; ++i){
            size_t o = (size_t)i*n + k;
            double fl = FL[o], zn = Z[o + n];
            if (!PIV[o]){ Z[o] = zc; zc = zn - fl*zc; }
            else        { Z[o] = zn; zc = zc - fl*zn; }
        }
        // ---- backward substitution (prefetch-16) ----
        double za = zc / fdlast;
        Z[(size_t)(n-1)*n + k] = za;
        size_t o2 = (size_t)(n-2)*n + k;
        double zaa = (Z[o2] - FU[o2]*za) / FD[o2];
        Z[o2] = zaa;
        double zb = za;
        int i2 = n - 3;
        for (; i2 >= 15; i2 -= 16){
            double zv[16], fu[16], fu2v[16], fd[16];
            #pragma unroll
            for (int u2 = 0; u2 < 16; ++u2){
                size_t o = (size_t)(i2-u2)*n + k;
                zv[u2] = Z[o]; fu[u2] = FU[o]; fu2v[u2] = FU2[o]; fd[u2] = FD[o];
            }
            #pragma unroll
            for (int u2 = 0; u2 < 16; ++u2){
                size_t o = (size_t)(i2-u2)*n + k;
                double znew = (zv[u2] - fu[u2]*zaa - fu2v[u2]*zb) / fd[u2];
                Z[o] = znew;
                zb = zaa; zaa = znew;
            }
        }
        for (; i2 >= 0; --i2){
            size_t o = (size_t)i2*n + k;
            double znew = (Z[o] - FU[o]*zaa - FU2[o]*zb) / FD[o];
            Z[o] = znew;
            zb = zaa; zaa = znew;
        }
        // ---- max-normalize (prefetch-8) ----
        double m0=0,m1=0,m2=0,m3=0,m4=0,m5=0,m6=0,m7=0;
        int i3 = 0;
        for (; i3 + 8 <= n; i3 += 8){
            m0 = fmax(m0, fabs(Z[(size_t)(i3+0)*n + k]));
            m1 = fmax(m1, fabs(Z[(size_t)(i3+1)*n + k]));
            m2 = fmax(m2, fabs(Z[(size_t)(i3+2)*n + k]));
            m3 = fmax(m3, fabs(Z[(size_t)(i3+3)*n + k]));
            m4 = fmax(m4, fabs(Z[(size_t)(i3+4)*n + k]));
            m5 = fmax(m5, fabs(Z[(size_t)(i3+5)*n + k]));
            m6 = fmax(m6, fabs(Z[(size_t)(i3+6)*n + k]));
            m7 = fmax(m7, fabs(Z[(size_t)(i3+7)*n + k]));
        }
        double mx = fmax(fmax(fmax(m0,m1),fmax(m2,m3)), fmax(fmax(m4,m5),fmax(m6,m7)));
        for (; i3 < n; ++i3) mx = fmax(mx, fabs(Z[(size_t)i3*n + k]));
        double s = (mx > 0.0) ? 1.0/mx : 1.0;
        for (int i4 = 0; i4 + 8 <= n; i4 += 8){
            double zv[8];
            #pragma unroll
            for (int u2 = 0; u2 < 8; ++u2) zv[u2] = Z[(size_t)(i4+u2)*n + k];
            #pragma unroll
            for (int u2 = 0; u2 < 8; ++u2) Z[(size_t)(i4+u2)*n + k] = zv[u2]*s;
        }
    }
    // ---- 2-norm normalize (prefetch-8) ----
    double n0=0,n1=0,n2=0,n3=0,n4=0,n5=0,n6=0,n7=0;
    int i5 = 0;
    for (; i5 + 8 <= n; i5 += 8){
        double zv[8];
        #pragma unroll
        for (int u2 = 0; u2 < 8; ++u2) zv[u2] = Z[(size_t)(i5+u2)*n + k];
        n0 += zv[0]*zv[0]; n1 += zv[1]*zv[1]; n2 += zv[2]*zv[2]; n3 += zv[3]*zv[3];
        n4 += zv[4]*zv[4]; n5 += zv[5]*zv[5]; n6 += zv[6]*zv[6]; n7 += zv[7]*zv[7];
    }
    double nrm = ((n0+n1)+(n2+n3)) + ((n4+n5)+(n6+n7));
    for (; i5 < n; ++i5){ double v = Z[(size_t)i5*n + k]; nrm += v*v; }
    double s = 1.0/sqrt(nrm);
    for (int i6 = 0; i6 + 8 <= n; i6 += 8){
        double zv[8];
        #pragma unroll
        for (int u2 = 0; u2 < 8; ++u2) zv[u2] = Z[(size_t)(i6+u2)*n + k];
        #pragma unroll
        for (int u2 = 0; u2 < 8; ++u2) Z[(size_t)(i6+u2)*n + k] = zv[u2]*s;
    }
}

// ============================ batched blocked-WY back-transform ============================
__global__ __launch_bounds__(256) void wy_buildV_k(const double* __restrict__ A64, const double* __restrict__ scaleg,
                                                   double* __restrict__ Vbig, int n)
{
    size_t idx = (size_t)blockIdx.x*256 + threadIdx.x;
    if (idx >= (size_t)NWY*1024*64) return;
    int g = (int)(idx >> 16);
    int r = (int)((idx >> 6) & 1023);
    int t = (int)(idx & 63);
    int b0 = g*64;
    int nbsz = (n - 2) - b0; if (nbsz > 64) nbsz = 64;
    double v = 0.0;
    if (t < nbsz){
        int j = b0 + t;
        if (r == j + 1) v = 1.0;
        else if (r > j + 1) v = A64[(size_t)j*n + r]*scaleg[j];
    }
    Vbig[idx] = v;
}

__global__ __launch_bounds__(256) void wy_buildT_k(const double* __restrict__ Vbig, const double* __restrict__ tau,
                                                   double* __restrict__ Tbig, int n)
{
    __shared__ double G[64][65];
    __shared__ double Ts[64][65];
    __shared__ double Vs[32][65];
    const int g = blockIdx.x;
    const int tid = threadIdx.x;
    const double* __restrict__ V = Vbig + ((size_t)g << 16);
    const int b0 = g*64;
    int nbsz = (n - 2) - b0; if (nbsz > 64) nbsz = 64;
    for (int p = tid; p < 64*64; p += 256) G[p >> 6][p & 63] = 0.0;
    __syncthreads();
    for (int rb = b0; rb < n; rb += 32){
        for (int s = tid; s < 2048; s += 256){
            int rr = s >> 6, tt = s & 63;
            Vs[rr][tt] = V[((size_t)(rb + rr) << 6) + tt];
        }
        __syncthreads();
        for (int p = tid; p < 4096; p += 256){
            int t = p >> 6, s2 = p & 63;
            if (t < s2 && s2 < nbsz){
                double acc = 0.0;
                #pragma unroll 8
                for (int rr = 0; rr < 32; ++rr) acc += Vs[rr][t]*Vs[rr][s2];
                G[t][s2] += acc;
            }
        }
        __syncthreads();
    }
    for (int t = nbsz - 1; t >= 0; --t){
        for (int u = tid; u < 64; u += 256){
            double val = 0.0;
            if (u == t) val = tau[b0 + t];
            else if (u > t && u < nbsz){
                double s = 0.0;
                for (int s2 = t + 1; s2 <= u; ++s2) s += G[t][s2]*Ts[s2][u];
                val = -tau[b0 + t]*s;
            }
            Ts[t][u] = val;
        }
        __syncthreads();
    }
    for (int p = tid; p < 64*64; p += 256){
        int t = p >> 6, u = p & 63;
        Tbig[((size_t)g << 12) + p] = (t < nbsz) ? Ts[t][u] : 0.0;
    }
}

__global__ __launch_bounds__(256) void wy_apply_k(const double* __restrict__ Vbig, const double* __restrict__ Tbig,
                                                  double* __restrict__ Z, int n)
{
    __shared__ double Vs[32][65];
    __shared__ double Zs[32][17];
    __shared__ double Y[64][17];
    __shared__ double W[64][17];
    const int tid = threadIdx.x;
    const int c   = tid & 15;
    const int tq  = tid >> 4;
    const int c0  = blockIdx.x * 16;

    for (int g = NWY - 1; g >= 0; --g){
        const double* __restrict__ V = Vbig + ((size_t)g << 16);
        const double* __restrict__ T = Tbig + ((size_t)g << 12);
        const int b0 = g*64;
        double acc0 = 0.0, acc1 = 0.0, acc2 = 0.0, acc3 = 0.0;
        for (int rb = b0; rb < n; rb += 32){
            for (int s = tid; s < 2048; s += 256){
                int rr = s >> 6, tt = s & 63;
                Vs[rr][tt] = V[((size_t)(rb + rr) << 6) + tt];
            }
            for (int s = tid; s < 512; s += 256){
                int rr = s >> 4, cc = s & 15;
                Zs[rr][cc] = Z[(size_t)(rb + rr)*n + c0 + cc];
            }
            __syncthreads();
            #pragma unroll 8
            for (int rr = 0; rr < 32; ++rr){
                double z = Zs[rr][c];
                acc0 += Vs[rr][tq*4+0]*z;
                acc1 += Vs[rr][tq*4+1]*z;
                acc2 += Vs[rr][tq*4+2]*z;
                acc3 += Vs[rr][tq*4+3]*z;
            }
            __syncthreads();
        }
        Y[tq*4+0][c] = acc0; Y[tq*4+1][c] = acc1; Y[tq*4+2][c] = acc2; Y[tq*4+3][c] = acc3;
        __syncthreads();
        #pragma unroll
        for (int i = 0; i < 4; ++i){
            int t = tq*4 + i;
            double a = 0.0;
            for (int s = t; s < 64; ++s) a += T[(t << 6) + s]*Y[s][c];
            W[t][c] = a;
        }
        __syncthreads();
        for (int rb = b0; rb < n; rb += 32){
            for (int s = tid; s < 2048; s += 256){
                int rr = s >> 6, tt = s & 63;
                Vs[rr][tt] = V[((size_t)(rb + rr) << 6) + tt];
            }
            __syncthreads();
            #pragma unroll
            for (int half = 0; half < 2; ++half){
                int item = tid + half*256;
                int rr = item >> 4, cc = item & 15;
                double s = 0.0;
                #pragma unroll 16
                for (int t = 0; t < 64; ++t) s += Vs[rr][t]*W[t][cc];
                Z[(size_t)(rb + rr)*n + c0 + cc] -= s;
            }
            __syncthreads();
        }
        __syncthreads();
    }
}

// ============================ host dispatch helpers ============================
static void gemmf32(hipStream_t st, int epi,
                    const float* A, const float* B, float* C, int M, int N, int K,
                    const float* bias, const float* D)
{
    if ((K & 15) == 0 && (N & 7) == 0){
        if (M >= 768){
            dim3 g((N + 127)/128, (M + 127)/128), b(256);
            switch (epi){
            case EPI_NONE:      gemm128db<EPI_NONE><<<g, b, 0, st>>>(A, B, C, M, N, K, bias, D); break;
            case EPI_BIAS:      gemm128db<EPI_BIAS><<<g, b, 0, st>>>(A, B, C, M, N, K, bias, D); break;
            case EPI_BIAS_ADD:  gemm128db<EPI_BIAS_ADD><<<g, b, 0, st>>>(A, B, C, M, N, K, bias, D); break;
            case EPI_ABS_DIAG1: gemm128db<EPI_ABS_DIAG1><<<g, b, 0, st>>>(A, B, C, M, N, K, bias, D); break;
            case EPI_RELU:      gemm128db<EPI_RELU><<<g, b, 0, st>>>(A, B, C, M, N, K, bias, D); break;
            }
        } else {
            dim3 g((N + 127)/128, (M + 63)/64), b(128);
            switch (epi){
            case EPI_NONE:      gemm_db<EPI_NONE><<<g, b, 0, st>>>(A, B, C, M, N, K, bias, D); break;
            case EPI_BIAS:      gemm_db<EPI_BIAS><<<g, b, 0, st>>>(A, B, C, M, N, K, bias, D); break;
            case EPI_BIAS_ADD:  gemm_db<EPI_BIAS_ADD><<<g, b, 0, st>>>(A, B, C, M, N, K, bias, D); break;
            case EPI_ABS_DIAG1: gemm_db<EPI_ABS_DIAG1><<<g, b, 0, st>>>(A, B, C, M, N, K, bias, D); break;
            case EPI_RELU:      gemm_db<EPI_RELU><<<g, b, 0, st>>>(A, B, C, M, N, K, bias, D); break;
            }
        }
    } else {
        dim3 g((N + 63)/64, (M + 63)/64), b(256);
        switch (epi){
        case EPI_NONE:      gemm32<EPI_NONE><<<g, b, 0, st>>>(A, B, C, M, N, K, bias, D); break;
        case EPI_BIAS:      gemm32<EPI_BIAS><<<g, b, 0, st>>>(A, B, C, M, N, K, bias, D); break;
        case EPI_BIAS_ADD:  gemm32<EPI_BIAS_ADD><<<g, b, 0, st>>>(A, B, C, M, N, K, bias, D); break;
        case EPI_ABS_DIAG1: gemm32<EPI_ABS_DIAG1><<<g, b, 0, st>>>(A, B, C, M, N, K, bias, D); break;
        case EPI_RELU:      gemm32<EPI_RELU><<<g, b, 0, st>>>(A, B, C, M, N, K, bias, D); break;
        }
    }
}

// ============================ kernel_launch ============================
extern "C" void kernel_launch(void* const* d_in, const int* in_sizes, int n_in,
                              void* d_out, int out_size, void* d_ws, size_t ws_size,
                              hipStream_t stream)
{
    (void)in_sizes; (void)n_in; (void)out_size; (void)ws_size;
    const float* lr       = (const float*)d_in[0];
    const float* gsr_w    = (const float*)d_in[1];
    const float* start_w  = (const float*)d_in[2];
    const float* start_b  = (const float*)d_in[3];
    const float* down_w   = (const float*)d_in[4];
    const float* down_b   = (const float*)d_in[5];
    const float* pool_w   = (const float*)d_in[6];
    const float* pool_b   = (const float*)d_in[7];
    const float* bottom_w = (const float*)d_in[8];
    const float* bottom_b = (const float*)d_in[9];
    const float* end_w    = (const float*)d_in[10];
    const float* end_b    = (const float*)d_in[11];
    const float* up_w     = (const float*)d_in[12];
    const float* up_b     = (const float*)d_in[13];
    const float* gc1      = (const float*)d_in[14];
    const float* gc2      = (const float*)d_in[15];

    float* out_z     = (float*)d_out;                       // [2048,2048]
    float* out_net   = out_z + (size_t)HRD*HRD;             // [1024,2048]
    float* out_start = out_net + (size_t)NN*HRD;            // [1024,320]
    float* out_adj   = out_start + (size_t)NN*DIMF;         // [2048,2048]

    static const int LVL_N[4] = {1024, 921, 644, 386};
    static const int LVL_K[4] = {921, 644, 386, 193};

    // -------- workspace arena --------
    char* Wb = (char*)d_ws;
    size_t off = 0;
    auto alloc = [&](size_t bb)->char*{ char* p = Wb + off; off = (off + bb + 255) & ~(size_t)255; return p; };

    float*  A32  = (float*) alloc((size_t)NN*NN*4);
    double* A64  = (double*)alloc((size_t)NN*NN*8);
    float*  UfT  = (float*) alloc((size_t)NN*NN*4);   // U^T as [k][j] fp32
    double* r64  = (double*)alloc(NN*8);
    double* dD   = (double*)alloc(NN*8);
    double* dE   = (double*)alloc(NN*8);
    double* dTau = (double*)alloc(NN*8);
    double* dScl = (double*)alloc(NN*8);
    double* dWev = (double*)alloc(NN*8);
    double* pvA  = (double*)alloc(NN*8);              // kept (init target), unused by coop7
    double* Rst  = (double*)alloc((size_t)2*NN*8);    // double-buffered pivot-row stage (sc1)
    unsigned* barcnt = (unsigned*)alloc(8192);
    char* SBASE = Wb + off;

    // P2 overlay (U-Net)
    size_t so = 0;
    auto salloc = [&](size_t bb)->char*{ char* p = SBASE + so; so = (so + bb + 255) & ~(size_t)255; return p; };
    float* XT  = (float*)salloc((size_t)NN*DIMF*4);
    float* XP1 = (float*)salloc((size_t)NN*DIMF*4);
    float* XP2 = (float*)salloc((size_t)NN*DIMF*4);
    float* XU  = (float*)salloc((size_t)NN*DIMF*4);
    float* DN[4]; for (int l = 0; l < 4; ++l) DN[l] = (float*)salloc((size_t)NN*DIMF*4);
    float* Asub[4];
    for (int l = 0; l < 4; ++l) Asub[l] = (float*)salloc((size_t)LVL_K[l]*LVL_K[l]*4);
    float* SC = (float*)salloc(NN*4);
    int*   IDX[4]; for (int l = 0; l < 4; ++l) IDX[l] = (int*)salloc(NN*4);
    float* VAL[4]; for (int l = 0; l < 4; ++l) VAL[l] = (float*)salloc(NN*4);
    float* XC  = (float*)salloc((size_t)NN*2*DIMF*4);
    float* AXC = (float*)salloc((size_t)NN*2*DIMF*4);

    // P3 overlay (eigensolver scratch)
    const size_t PL = (size_t)NN*NN*8;
    double* Z64 = (double*)(SBASE);
    double* FD  = (double*)(SBASE + PL);       // doubles as Pmat during sytrd, Vbig during WY
    double* FL  = (double*)(SBASE + 2*PL);     // doubles as Tbig during WY
    double* FU  = (double*)(SBASE + 3*PL);
    double* FU2 = (double*)(SBASE + 4*PL);
    signed char* FPIV = (signed char*)(SBASE + 5*PL);
    double* Pmat = FD;
    double* Vbig = FD;
    double* Tbig = FL;

    // P4 overlay (GSR / refinement)
    const size_t MB8  = (size_t)HRD*NN*4;    // 8 MiB
    const size_t MB16 = (size_t)HRD*HRD*4;   // 16 MiB
    float* P4a   = (float*)(SBASE);
    float* P4t1  = (float*)(SBASE + MB8);
    float* P4adT = (float*)(SBASE);
    float* P4Zb  = (float*)(SBASE + MB16);
    float* P4ZG  = (float*)(SBASE);
    float* P4h1  = (float*)(SBASE + MB8);
    float* P4HG  = (float*)(SBASE + MB16);
    float* P4h2  = (float*)(SBASE);

    // =============== P1: normalized adjacency ===============
    rowsum_rsqrt_k<<<NN, 256, 0, stream>>>(lr, r64, NN);
    build_A_k<<<(NN*NN + 255)/256, 256, 0, stream>>>(lr, r64, A32, A64, NN);

    // =============== P2: graph U-Net (fp32) ===============
    gemmf32(stream, EPI_BIAS, A32, start_w, out_start, NN, DIMF, NN, start_b, nullptr);

    const float* Xcur = out_start;
    const float* Acur = A32;
    float* ping = XP1; float* pong = XP2;
    for (int l = 0; l < 4; ++l){
        int nl = LVL_N[l], kl = LVL_K[l];
        gemmf32(stream, EPI_NONE, Acur, Xcur, XT, nl, DIMF, nl, nullptr, nullptr);
        gemmf32(stream, EPI_BIAS, XT, down_w + (size_t)l*DIMF*DIMF, DN[l], nl, DIMF, DIMF,
                down_b + (size_t)l*DIMF, nullptr);
        score_k<<<(nl + 3)/4, 256, 0, stream>>>(DN[l], pool_w + (size_t)l*DIMF, pool_b + l, SC, nl, DIMF);
        topk_k<<<1, 256, 0, stream>>>(SC, nl, kl, IDX[l], VAL[l]);
        gatherX_k<<<(unsigned)(((size_t)kl*DIMF + 255)/256), 256, 0, stream>>>(DN[l], IDX[l], VAL[l], ping, kl, DIMF);
        gatherA_k<<<(unsigned)(((size_t)kl*kl + 255)/256), 256, 0, stream>>>(Acur, IDX[l], Asub[l], kl, nl);
        Xcur = ping; Acur = Asub[l];
        float* t = ping; ping = pong; pong = t;
    }
    gemmf32(stream, EPI_NONE, Acur, Xcur, XT, 193, DIMF, 193, nullptr, nullptr);
    float* Xb = ping;
    gemmf32(stream, EPI_BIAS, XT, bottom_w, Xb, 193, DIMF, DIMF, bottom_b, nullptr);
    const float* Xup = Xb;
    float* upbuf[2] = { (Xb == XP1) ? XP2 : XP1, (Xb == XP1) ? XP1 : XP2 };
    for (int i2 = 0; i2 < 4; ++i2){
        int jl = 3 - i2;
        int nj = LVL_N[jl];
        int kj = LVL_K[jl];
        fill0_k<<<(unsigned)(((size_t)nj*DIMF + 255)/256), 256, 0, stream>>>(XU, (size_t)nj*DIMF);
        scatterX_k<<<(unsigned)(((size_t)kj*DIMF + 255)/256), 256, 0, stream>>>(Xup, IDX[jl], XU, kj, DIMF);
        const float* Aj = (jl == 0) ? A32 : Asub[jl - 1];
        gemmf32(stream, EPI_NONE, Aj, XU, XT, nj, DIMF, nj, nullptr, nullptr);
        float* Xn = upbuf[i2 & 1];
        gemmf32(stream, EPI_BIAS_ADD, XT, up_w + (size_t)i2*DIMF*DIMF, Xn, nj, DIMF, DIMF,
                up_b + (size_t)i2*DIMF, DN[jl]);
        Xup = Xn;
    }
    concat_k<<<(unsigned)(((size_t)NN*2*DIMF + 255)/256), 256, 0, stream>>>(Xup, out_start, XC, NN, DIMF);
    gemmf32(stream, EPI_NONE, A32, XC, AXC, NN, 2*DIMF, NN, nullptr, nullptr);
    gemmf32(stream, EPI_BIAS, AXC, end_w, out_net, NN, HRD, 2*DIMF, end_b, nullptr);

    // =============== P3: eigendecomposition of A (fp64) ===============
    const int JEND = NN - TB;
    init_sytrd_k<<<4, 256, 0, stream>>>(pvA, barcnt, NN);
    filld0_k<<<(unsigned)(((size_t)JEND*NN + 255)/256), 256, 0, stream>>>(Pmat, (size_t)JEND*NN);
    sytrd_coop7<<<CB3, BT3, 0, stream>>>(A64, dE, dTau, dScl, Pmat, Rst, barcnt, NN, JEND);
    hh_tail<<<1, 256, 0, stream>>>(A64, dE, dTau, dScl, NN);
    extract_de_k<<<4, 256, 0, stream>>>(A64, dD, dE, NN);
    bisect_k<<<4, 256, 0, stream>>>(dD, dE, dWev, NN);
    invit_k<<<4, 256, 0, stream>>>(dD, dE, dWev, FD, FL, FU, FU2, FPIV, Z64, NN);
    wy_buildV_k<<<(unsigned)(((size_t)NWY*1024*64 + 255)/256), 256, 0, stream>>>(A64, dScl, Vbig, NN);
    wy_buildT_k<<<NWY, 256, 0, stream>>>(Vbig, dTau, Tbig, NN);
    wy_apply_k<<<NN/16, 256, 0, stream>>>(Vbig, Tbig, Z64, NN);
    {
        dim3 g(NN/32, NN/32), b(256);
        transpose_cast_k<<<g, b, 0, stream>>>(Z64, UfT, NN);
    }

    // =============== P4: GSR layer + refinement (fp32) ===============
    build_a_k<<<(unsigned)(((size_t)HRD*NN + 255)/256), 256, 0, stream>>>(gsr_w, P4a);
    gemmf32(stream, EPI_NONE, P4a, UfT, P4t1, HRD, NN, NN, nullptr, nullptr);               // a @ U^T
    gemmf32(stream, EPI_ABS_DIAG1, P4t1, out_net, out_adj, HRD, HRD, NN, nullptr, nullptr); // adj
    {
        dim3 g(HRD/32, HRD/32), b(256);
        transpose32_k<<<g, b, 0, stream>>>(out_adj, P4adT, HRD);                            // adj^T
    }
    {
        const int T = HRD >> 7;                       // 16 tiles -> 136 upper pairs
        gemm_symAAT<<<T*(T+1)/2, 256, 0, stream>>>(out_adj, P4adT, P4Zb, HRD);              // adj @ adj^T (sym)
    }
    symabs1_k<<<(unsigned)(((size_t)HRD*HRD + 255)/256), 256, 0, stream>>>(P4Zb, HRD);      // Z
    gemmf32(stream, EPI_NONE, P4Zb, gc1, P4ZG, HRD, NN, HRD, nullptr, nullptr);             // Z @ gc1
    gemmf32(stream, EPI_RELU, out_adj, P4ZG, P4h1, HRD, NN, HRD, nullptr, nullptr);         // h1
    gemmf32(stream, EPI_NONE, P4h1, gc2, P4HG, HRD, HRD, NN, nullptr, nullptr);             // h1 @ gc2
    gemmf32(stream, EPI_RELU, out_adj, P4HG, P4h2, HRD, HRD, HRD, nullptr, nullptr);        // h2
    final_z_k<<<(unsigned)(((size_t)HRD*HRD + 255)/256), 256, 0, stream>>>(P4h2, out_z, HRD); // z
}

// Round 5
// 18118.620 us; speedup vs baseline: 1.3255x; 1.0391x over previous
//
#include <hip/hip_runtime.h>
#include <cstddef>
#include <cstdint>
#include <math.h>

// ============================ constants ============================
static constexpr int NN   = 1024;   // lr_dim
static constexpr int HRD  = 2048;   // hr_dim
static constexpr int DIMF = 320;
static constexpr int TB   = 85;     // sytrd LDS tail block
static constexpr int CB3  = 128;    // persistent sytrd blocks (8 rows each)
static constexpr int BT3  = 1024;   // threads per sytrd block (16 waves)
static constexpr int NWY  = 16;     // WY reflector groups (64 each)

#define EPI_NONE      0
#define EPI_BIAS      1
#define EPI_BIAS_ADD  2
#define EPI_ABS_DIAG1 3
#define EPI_RELU      4

// agent-scope coherent access helpers (sc1).
__device__ __forceinline__ double gload(const double* p){
    return __hip_atomic_load(p, __ATOMIC_RELAXED, __HIP_MEMORY_SCOPE_AGENT);
}
__device__ __forceinline__ void gstore(double* p, double v){
    __hip_atomic_store(p, v, __ATOMIC_RELAXED, __HIP_MEMORY_SCOPE_AGENT);
}

// ============================ fp32 GEMM 64-tile (fallback, odd K) ============================
template<int EPI>
__global__ __launch_bounds__(256) void gemm32(
    const float* __restrict__ A, const float* __restrict__ B, float* __restrict__ C,
    int M, int N, int K, const float* __restrict__ bias, const float* __restrict__ D)
{
    __shared__ float As[16][65];
    __shared__ float Bs[16][65];
    const int bm = blockIdx.y << 6, bn = blockIdx.x << 6;
    const int tid = threadIdx.x;
    const int tm = (tid >> 4) << 2, tn = (tid & 15) << 2;
    float acc[4][4] = {};
    const int kt = (K + 15) >> 4;
    for (int k0 = 0; k0 < kt; ++k0){
        const int kb = k0 << 4;
        for (int t = tid; t < 1024; t += 256){
            int m = t >> 4, k = t & 15;
            int gm = bm + m, gk = kb + k;
            As[k][m] = (gm < M && gk < K) ? A[(size_t)gm*K + gk] : 0.f;
        }
        for (int t = tid; t < 1024; t += 256){
            int k = t >> 6, nn2 = t & 63;
            int gk = kb + k, gn = bn + nn2;
            Bs[k][nn2] = (gk < K && gn < N) ? B[(size_t)gk*N + gn] : 0.f;
        }
        __syncthreads();
        #pragma unroll
        for (int k = 0; k < 16; ++k){
            float a0 = As[k][tm], a1 = As[k][tm+1], a2 = As[k][tm+2], a3 = As[k][tm+3];
            float b0 = Bs[k][tn], b1 = Bs[k][tn+1], b2 = Bs[k][tn+2], b3 = Bs[k][tn+3];
            acc[0][0] += a0*b0; acc[0][1] += a0*b1; acc[0][2] += a0*b2; acc[0][3] += a0*b3;
            acc[1][0] += a1*b0; acc[1][1] += a1*b1; acc[1][2] += a1*b2; acc[1][3] += a1*b3;
            acc[2][0] += a2*b0; acc[2][1] += a2*b1; acc[2][2] += a2*b2; acc[2][3] += a2*b3;
            acc[3][0] += a3*b0; acc[3][1] += a3*b1; acc[3][2] += a3*b2; acc[3][3] += a3*b3;
        }
        __syncthreads();
    }
    #pragma unroll
    for (int r = 0; r < 4; ++r){
        int gm = bm + tm + r; if (gm >= M) continue;
        #pragma unroll
        for (int c = 0; c < 4; ++c){
            int gn = bn + tn + c; if (gn >= N) continue;
            float v = acc[r][c];
            if (EPI == EPI_BIAS)            v += bias[gn];
            else if (EPI == EPI_BIAS_ADD)   v += bias[gn] + D[(size_t)gm*N + gn];
            else if (EPI == EPI_ABS_DIAG1)  v = (gm == gn) ? 1.0f : fabsf(v);
            else if (EPI == EPI_RELU)       v = fmaxf(v, 0.0f);
            C[(size_t)gm*N + gn] = v;
        }
    }
}

// ============================ fp32 GEMM 64x128 double-buffered (K%16==0, N%8==0) ============================
template<int EPI>
__global__ __launch_bounds__(128) void gemm_db(
    const float* __restrict__ A, const float* __restrict__ B, float* __restrict__ C,
    int M, int N, int K, const float* __restrict__ bias, const float* __restrict__ D)
{
    __shared__ float As[2][16][68];
    __shared__ float Bs[2][16][132];
    const int bm = blockIdx.y << 6;
    const int bn = blockIdx.x << 7;
    const int tid = threadIdx.x;
    const int tm = (tid >> 4) << 3;
    const int tn = (tid & 15) << 3;
    const int ar = tid >> 2;
    const int af = tid & 3;
    const int br = tid >> 5;
    const int bf = tid & 31;

    float4 a_reg[2], b_reg[4];

    auto loadA = [&](int kb, int q) -> float4 {
        int gm = bm + ar + (q << 5);
        int gk = kb + (af << 2);
        if (gm < M) return *(const float4*)(A + (size_t)gm*K + gk);
        return make_float4(0.f,0.f,0.f,0.f);
    };
    auto loadB = [&](int kb, int q) -> float4 {
        int gk = kb + br + (q << 2);
        int gn = bn + (bf << 2);
        if (gn < N) return *(const float4*)(B + (size_t)gk*N + gn);
        return make_float4(0.f,0.f,0.f,0.f);
    };
    auto stash = [&](int p){
        #pragma unroll
        for (int q = 0; q < 2; ++q){
            int r = ar + (q << 5);
            As[p][(af<<2)+0][r] = a_reg[q].x; As[p][(af<<2)+1][r] = a_reg[q].y;
            As[p][(af<<2)+2][r] = a_reg[q].z; As[p][(af<<2)+3][r] = a_reg[q].w;
        }
        #pragma unroll
        for (int q = 0; q < 4; ++q)
            *(float4*)&Bs[p][br + (q<<2)][bf << 2] = b_reg[q];
    };

    #pragma unroll
    for (int q = 0; q < 2; ++q) a_reg[q] = loadA(0, q);
    #pragma unroll
    for (int q = 0; q < 4; ++q) b_reg[q] = loadB(0, q);
    stash(0);
    __syncthreads();

    float acc[8][8] = {};
    int p = 0;
    for (int kb = 16; ; kb += 16){
        const bool more = (kb < K);
        if (more){
            #pragma unroll
            for (int q = 0; q < 2; ++q) a_reg[q] = loadA(kb, q);
            #pragma unroll
            for (int q = 0; q < 4; ++q) b_reg[q] = loadB(kb, q);
        }
        #pragma unroll
        for (int k = 0; k < 16; ++k){
            float4 a0 = *(const float4*)&As[p][k][tm];
            float4 a1 = *(const float4*)&As[p][k][tm+4];
            float4 b0 = *(const float4*)&Bs[p][k][tn];
            float4 b1 = *(const float4*)&Bs[p][k][tn+4];
            float av[8] = {a0.x,a0.y,a0.z,a0.w,a1.x,a1.y,a1.z,a1.w};
            float bv[8] = {b0.x,b0.y,b0.z,b0.w,b1.x,b1.y,b1.z,b1.w};
            #pragma unroll
            for (int i = 0; i < 8; ++i)
                #pragma unroll
                for (int jj = 0; jj < 8; ++jj) acc[i][jj] += av[i]*bv[jj];
        }
        if (!more) break;
        stash(p ^ 1);
        __syncthreads();
        p ^= 1;
    }
    #pragma unroll
    for (int i = 0; i < 8; ++i){
        int gm = bm + tm + i; if (gm >= M) continue;
        #pragma unroll
        for (int jj = 0; jj < 8; ++jj){
            int gn = bn + tn + jj; if (gn >= N) continue;
            float v = acc[i][jj];
            if (EPI == EPI_BIAS)            v += bias[gn];
            else if (EPI == EPI_BIAS_ADD)   v += bias[gn] + D[(size_t)gm*N + gn];
            else if (EPI == EPI_ABS_DIAG1)  v = (gm == gn) ? 1.0f : fabsf(v);
            else if (EPI == EPI_RELU)       v = fmaxf(v, 0.0f);
            C[(size_t)gm*N + gn] = v;
        }
    }
}

// ============================ fp32 GEMM 128x128 double-buffered (K%16==0, N%8==0, big M) ============================
template<int EPI>
__global__ __launch_bounds__(256) void gemm128db(
    const float* __restrict__ A, const float* __restrict__ B, float* __restrict__ C,
    int M, int N, int K, const float* __restrict__ bias, const float* __restrict__ D)
{
    __shared__ float As[2][16][132];
    __shared__ float Bs[2][16][132];
    const int bm = blockIdx.y << 7, bn = blockIdx.x << 7;
    const int tid = threadIdx.x;
    const int tm = (tid >> 4) << 3;
    const int tn = (tid & 15) << 3;
    const int ar = tid >> 1;         // 0..127
    const int ak = (tid & 1) << 3;   // 0/8
    const int br = tid >> 4;         // 0..15
    const int bc = (tid & 15) << 3;  // 0..120

    float4 a0r, a1r, b0r, b1r;

    auto loadA = [&](int kb){
        int gm = bm + ar, gk = kb + ak;
        if (gm < M){
            const float* p = A + (size_t)gm*K + gk;
            a0r = *(const float4*)p; a1r = *(const float4*)(p + 4);
        } else { a0r = make_float4(0.f,0.f,0.f,0.f); a1r = a0r; }
    };
    auto loadB = [&](int kb){
        int gk = kb + br, gn = bn + bc;
        if (gn + 7 < N){
            const float* p = B + (size_t)gk*N + gn;
            b0r = *(const float4*)p; b1r = *(const float4*)(p + 4);
        } else {
            float t0[8];
            #pragma unroll
            for (int i = 0; i < 8; ++i){ int g2 = gn + i; t0[i] = (g2 < N) ? B[(size_t)gk*N + g2] : 0.f; }
            b0r = make_float4(t0[0],t0[1],t0[2],t0[3]); b1r = make_float4(t0[4],t0[5],t0[6],t0[7]);
        }
    };
    auto stash = [&](int p){
        As[p][ak+0][ar]=a0r.x; As[p][ak+1][ar]=a0r.y; As[p][ak+2][ar]=a0r.z; As[p][ak+3][ar]=a0r.w;
        As[p][ak+4][ar]=a1r.x; As[p][ak+5][ar]=a1r.y; As[p][ak+6][ar]=a1r.z; As[p][ak+7][ar]=a1r.w;
        *(float4*)&Bs[p][br][bc] = b0r; *(float4*)&Bs[p][br][bc+4] = b1r;
    };

    loadA(0); loadB(0); stash(0);
    __syncthreads();

    float acc[8][8] = {};
    int p = 0;
    for (int kb = 16; ; kb += 16){
        const bool more = (kb < K);
        if (more){ loadA(kb); loadB(kb); }
        #pragma unroll
        for (int k = 0; k < 16; ++k){
            float4 a0 = *(const float4*)&As[p][k][tm];
            float4 a1 = *(const float4*)&As[p][k][tm+4];
            float4 b0 = *(const float4*)&Bs[p][k][tn];
            float4 b1 = *(const float4*)&Bs[p][k][tn+4];
            float av[8] = {a0.x,a0.y,a0.z,a0.w,a1.x,a1.y,a1.z,a1.w};
            float bv[8] = {b0.x,b0.y,b0.z,b0.w,b1.x,b1.y,b1.z,b1.w};
            #pragma unroll
            for (int i = 0; i < 8; ++i)
                #pragma unroll
                for (int jj = 0; jj < 8; ++jj) acc[i][jj] += av[i]*bv[jj];
        }
        if (!more) break;
        stash(p ^ 1);
        __syncthreads();
        p ^= 1;
    }
    #pragma unroll
    for (int i = 0; i < 8; ++i){
        int gm = bm + tm + i; if (gm >= M) continue;
        #pragma unroll
        for (int jj = 0; jj < 8; ++jj){
            int gn = bn + tn + jj; if (gn >= N) continue;
            float v = acc[i][jj];
            if (EPI == EPI_BIAS)            v += bias[gn];
            else if (EPI == EPI_BIAS_ADD)   v += bias[gn] + D[(size_t)gm*N + gn];
            else if (EPI == EPI_ABS_DIAG1)  v = (gm == gn) ? 1.0f : fabsf(v);
            else if (EPI == EPI_RELU)       v = fmaxf(v, 0.0f);
            C[(size_t)gm*N + gn] = v;
        }
    }
}

// ============================ symmetric C = A @ A^T (B = A^T given), n%128==0 ============================
__global__ __launch_bounds__(256) void gemm_symAAT(
    const float* __restrict__ A, const float* __restrict__ Bt, float* __restrict__ C, int n)
{
    __shared__ float As[2][16][132];
    __shared__ float Bs[2][16][132];
    const int T = n >> 7;
    int ti = 0, rem = blockIdx.x;
    while (rem >= T - ti){ rem -= T - ti; ++ti; }
    const int tj = ti + rem;
    const int bm = ti << 7, bn = tj << 7;
    const int tid = threadIdx.x;
    const int tm = (tid >> 4) << 3;
    const int tn = (tid & 15) << 3;
    const int ar = tid >> 1;
    const int ak = (tid & 1) << 3;
    const int br = tid >> 4;
    const int bc = (tid & 15) << 3;

    float4 a0r, a1r, b0r, b1r;
    auto loadA = [&](int kb){
        const float* p = A + (size_t)(bm + ar)*n + kb + ak;
        a0r = *(const float4*)p; a1r = *(const float4*)(p + 4);
    };
    auto loadB = [&](int kb){
        const float* p = Bt + (size_t)(kb + br)*n + bn + bc;
        b0r = *(const float4*)p; b1r = *(const float4*)(p + 4);
    };
    auto stash = [&](int p){
        As[p][ak+0][ar]=a0r.x; As[p][ak+1][ar]=a0r.y; As[p][ak+2][ar]=a0r.z; As[p][ak+3][ar]=a0r.w;
        As[p][ak+4][ar]=a1r.x; As[p][ak+5][ar]=a1r.y; As[p][ak+6][ar]=a1r.z; As[p][ak+7][ar]=a1r.w;
        *(float4*)&Bs[p][br][bc] = b0r; *(float4*)&Bs[p][br][bc+4] = b1r;
    };

    loadA(0); loadB(0); stash(0);
    __syncthreads();

    float acc[8][8] = {};
    int p = 0;
    for (int kb = 16; ; kb += 16){
        const bool more = (kb < n);
        if (more){ loadA(kb); loadB(kb); }
        #pragma unroll
        for (int k = 0; k < 16; ++k){
            float4 a0 = *(const float4*)&As[p][k][tm];
            float4 a1 = *(const float4*)&As[p][k][tm+4];
            float4 b0 = *(const float4*)&Bs[p][k][tn];
            float4 b1 = *(const float4*)&Bs[p][k][tn+4];
            float av[8] = {a0.x,a0.y,a0.z,a0.w,a1.x,a1.y,a1.z,a1.w};
            float bv[8] = {b0.x,b0.y,b0.z,b0.w,b1.x,b1.y,b1.z,b1.w};
            #pragma unroll
            for (int i = 0; i < 8; ++i)
                #pragma unroll
                for (int jj = 0; jj < 8; ++jj) acc[i][jj] += av[i]*bv[jj];
        }
        if (!more) break;
        stash(p ^ 1);
        __syncthreads();
        p ^= 1;
    }
    #pragma unroll
    for (int i = 0; i < 8; ++i){
        #pragma unroll
        for (int jj = 0; jj < 8; ++jj)
            C[(size_t)(bm + tm + i)*n + (bn + tn + jj)] = acc[i][jj];
    }
    if (ti != tj){
        #pragma unroll
        for (int i = 0; i < 8; ++i)
            #pragma unroll
            for (int jj = 0; jj < 8; ++jj)
                C[(size_t)(bn + tn + jj)*n + (bm + tm + i)] = acc[i][jj];
    }
}

// ============================ small kernels ============================
__global__ __launch_bounds__(256) void rowsum_rsqrt_k(const float* __restrict__ lr, double* __restrict__ r64, int n)
{
    __shared__ double sm[256];
    int row = blockIdx.x;
    double s = 0.0;
    for (int j = threadIdx.x; j < n; j += 256) s += (double)lr[(size_t)row*n + j];
    sm[threadIdx.x] = s; __syncthreads();
    for (int o = 128; o; o >>= 1){ if (threadIdx.x < o) sm[threadIdx.x] += sm[threadIdx.x + o]; __syncthreads(); }
    if (threadIdx.x == 0){
        double t = sm[0];
        r64[row] = (t > 0.0) ? 1.0/sqrt(t) : 0.0;
    }
}

__global__ __launch_bounds__(256) void build_A_k(const float* __restrict__ lr, const double* __restrict__ r64,
                                                 float* __restrict__ A32, double* __restrict__ A64, int n)
{
    size_t idx = (size_t)blockIdx.x*256 + threadIdx.x;
    if (idx >= (size_t)n*n) return;
    int i = (int)(idx / n), j = (int)(idx % n);
    if (j < i) return;
    double v = (double)lr[(size_t)j*n + i] * r64[i] * r64[j];
    A64[(size_t)i*n + j] = v; A64[(size_t)j*n + i] = v;
    float vf = (float)v;
    A32[(size_t)i*n + j] = vf; A32[(size_t)j*n + i] = vf;
}

__global__ __launch_bounds__(256) void score_k(const float* __restrict__ X, const float* __restrict__ pw,
                                               const float* __restrict__ pb, float* __restrict__ out,
                                               int n, int dim)
{
    int row = blockIdx.x*4 + (threadIdx.x >> 6);
    int lane = threadIdx.x & 63;
    if (row >= n) return;
    float acc = 0.f;
    for (int c = lane; c < dim; c += 64) acc += X[(size_t)row*dim + c]*pw[c];
    #pragma unroll
    for (int o = 32; o; o >>= 1) acc += __shfl_down(acc, o);
    if (lane == 0){
        float t = (acc + pb[0]) * 0.01f;
        out[row] = 1.0f/(1.0f + expf(-t));
    }
}

// jax.lax.top_k semantics: descending value, ties -> lower index first
__global__ __launch_bounds__(256) void topk_k(const float* __restrict__ scores, int n, int k,
                                              int* __restrict__ idxo, float* __restrict__ valo)
{
    __shared__ float s[1024];
    int tid = threadIdx.x;
    for (int i = tid; i < n; i += 256) s[i] = scores[i];
    __syncthreads();
    for (int i = tid; i < n; i += 256){
        float si = s[i]; int r = 0;
        for (int j = 0; j < n; ++j){
            float sj = s[j];
            r += (sj > si) || (sj == si && j < i);
        }
        if (r < k){ idxo[r] = i; valo[r] = si; }
    }
}

__global__ __launch_bounds__(256) void gatherX_k(const float* __restrict__ X, const int* __restrict__ idx,
                                                 const float* __restrict__ vals, float* __restrict__ Xo,
                                                 int k, int dim)
{
    size_t t = (size_t)blockIdx.x*256 + threadIdx.x;
    if (t >= (size_t)k*dim) return;
    int m = (int)(t / dim), c = (int)(t % dim);
    Xo[t] = X[(size_t)idx[m]*dim + c] * vals[m];
}

__global__ __launch_bounds__(256) void scatterX_k(const float* __restrict__ Xs, const int* __restrict__ idx,
                                                  float* __restrict__ Xu, int k, int dim)
{
    size_t t = (size_t)blockIdx.x*256 + threadIdx.x;
    if (t >= (size_t)k*dim) return;
    int m = (int)(t / dim), c = (int)(t % dim);
    Xu[(size_t)idx[m]*dim + c] = Xs[t];
}

__global__ __launch_bounds__(256) void gatherA_k(const float* __restrict__ A, const int* __restrict__ idx,
                                                 float* __restrict__ Ao, int k, int n)
{
    size_t t = (size_t)blockIdx.x*256 + threadIdx.x;
    if (t >= (size_t)k*k) return;
    int m1 = (int)(t / k), m2 = (int)(t % k);
    Ao[t] = A[(size_t)idx[m1]*n + idx[m2]];
}

__global__ __launch_bounds__(256) void fill0_k(float* __restrict__ p, size_t cnt)
{
    size_t t = (size_t)blockIdx.x*256 + threadIdx.x;
    if (t < cnt) p[t] = 0.f;
}

__global__ __launch_bounds__(256) void filld0_k(double* __restrict__ p, size_t cnt)
{
    size_t t = (size_t)blockIdx.x*256 + threadIdx.x;
    if (t < cnt) p[t] = 0.0;
}

__global__ __launch_bounds__(256) void init_sytrd_k(double* __restrict__ pv, unsigned* __restrict__ bar, int n)
{
    int t = blockIdx.x*256 + threadIdx.x;
    if (t < n) pv[t] = 0.0;
    if (t < 1024) bar[t] = 0u;
}

__global__ __launch_bounds__(256) void concat_k(const float* __restrict__ X, const float* __restrict__ orgX,
                                                float* __restrict__ Xc, int n, int dim)
{
    size_t t = (size_t)blockIdx.x*256 + threadIdx.x;
    size_t tot = (size_t)n*2*dim;
    if (t >= tot) return;
    int i = (int)(t / (2*dim)), c = (int)(t % (2*dim));
    Xc[t] = (c < dim) ? X[(size_t)i*dim + c] : orgX[(size_t)i*dim + (c - dim)];
}

__global__ __launch_bounds__(256) void build_a_k(const float* __restrict__ gsr, float* __restrict__ a)
{
    size_t idx = (size_t)blockIdx.x*256 + threadIdx.x;
    if (idx >= (size_t)HRD*NN) return;
    int i = (int)(idx >> 10), k = (int)(idx & 1023);
    a[idx] = gsr[(size_t)i*HRD + k] + gsr[(size_t)i*HRD + NN + k];
}

__global__ __launch_bounds__(256) void symabs1_k(float* __restrict__ Z, int n)
{
    size_t idx = (size_t)blockIdx.x*256 + threadIdx.x;
    if (idx >= (size_t)n*n) return;
    int i = (int)(idx / n), j = (int)(idx % n);
    if (i > j) return;
    float a = Z[(size_t)i*n + j], b = Z[(size_t)j*n + i];
    float v = 0.5f*(a + b);
    float o = (i == j) ? 1.0f : fabsf(v);
    Z[(size_t)i*n + j] = o; Z[(size_t)j*n + i] = o;
}

__global__ __launch_bounds__(256) void final_z_k(const float* __restrict__ h2, float* __restrict__ z, int n)
{
    size_t idx = (size_t)blockIdx.x*256 + threadIdx.x;
    if (idx >= (size_t)n*n) return;
    int i = (int)(idx / n), j = (int)(idx % n);
    if (i > j) return;
    float v = 0.5f*(h2[(size_t)i*n + j] + h2[(size_t)j*n + i]);
    float o = (i == j) ? 1.0f : fabsf(v);
    z[(size_t)i*n + j] = o; z[(size_t)j*n + i] = o;
}

// dst[c][r] = (float)src[r][c]   (n x n, n % 32 == 0)
__global__ __launch_bounds__(256) void transpose_cast_k(const double* __restrict__ src, float* __restrict__ dst, int n)
{
    __shared__ float tile[32][33];
    int r0 = blockIdx.y*32, c0 = blockIdx.x*32;
    int tx = threadIdx.x & 31, ty = threadIdx.x >> 5;
    for (int i = ty; i < 32; i += 8)
        tile[i][tx] = (float)src[(size_t)(r0 + i)*n + (c0 + tx)];
    __syncthreads();
    for (int i = ty; i < 32; i += 8)
        dst[(size_t)(c0 + i)*n + (r0 + tx)] = tile[tx][i];
}

// dst[c][r] = src[r][c]  (n x n, n % 32 == 0)
__global__ __launch_bounds__(256) void transpose32_k(const float* __restrict__ src, float* __restrict__ dst, int n)
{
    __shared__ float tile[32][33];
    int r0 = blockIdx.y*32, c0 = blockIdx.x*32;
    int tx = threadIdx.x & 31, ty = threadIdx.x >> 5;
    for (int i = ty; i < 32; i += 8)
        tile[i][tx] = src[(size_t)(r0 + i)*n + (c0 + tx)];
    __syncthreads();
    for (int i = ty; i < 32; i += 8)
        dst[(size_t)(c0 + i)*n + (r0 + tx)] = tile[tx][i];
}

// ============================ persistent Householder tridiagonalization ============================
// sytrd_coop8: coop7 + register-prefetch of the owned trailing-row slots at loop top.
// The 8 independent L2 loads issue BEFORE phase A's sc1 round; the compiler's vmcnt(0)
// at the phase-A barrier drains them inside the (longer) sc1 latency shadow, so phase B
// computes from registers with no post-sync load chain.
__global__ __launch_bounds__(BT3) void sytrd_coop8(
    double* __restrict__ A, double* __restrict__ e, double* __restrict__ tauA,
    double* __restrict__ sclA, double* __restrict__ P,
    double* __restrict__ Rst, unsigned* __restrict__ bar, int n, int jend)
{
    __shared__ double VP[1024], WP[1024], VJ2[2][1024];
    __shared__ double redA[16], redB[16];
    const int tid   = threadIdx.x;
    const int bid   = blockIdx.x;
    const int lane  = tid & 63;
    const int wid   = tid >> 6;
    const int rwav  = wid >> 1;
    const int half  = wid & 1;
    const int u     = (bid << 3) + rwav;
    const int g     = bid >> 4;
    const int mylast = (bid << 3) + 7;
    const int cbase = half*64 + lane;

    double tau_p = 0.0, sc_p = 0.0;
    unsigned cumG = 0, cumC = 0;

    for (int j = 0; j < jend; ++j){
        const int m = n - 1 - j;
        double* __restrict__ VJnew = VJ2[j & 1];
        const double* __restrict__ VJold = VJ2[(j & 1) ^ 1];

        {
            const int retired = j >> 3;
            int d = retired - (g << 4);
            d = (d < 0) ? 0 : (d > 16 ? 16 : d);
            cumG += (unsigned)(16 - d);
            cumC += (unsigned)(8 - (j >> 7));
        }

        // ---- register-prefetch the owned trailing-row slots (overlaps phase-A sc1 round) ----
        double AR[8];
        double* __restrict__ Arow = A + (size_t)u*n + (j+1);
        if (u > j){
            #pragma unroll
            for (int q = 0; q < 8; ++q){
                int c = cbase + (q << 7);
                AR[q] = (c < m) ? Arow[c] : 0.0;
            }
        }

        // ---- fused phase A + pivot row; pv via block-local reduction ----
        double s = 0.0, wp0 = 0.0;
        if (j > 0){
            const double* __restrict__ Prow = P + (size_t)(j-1)*NN;
            const double* __restrict__ rs   = Rst + ((size_t)(j & 1) << 10);
            const double p0 = gload(&Prow[0]);
            double pi = 0.0, rsi = 0.0, vp = 0.0, pvp = 0.0;
            const bool act = (tid <= m);
            if (act){
                pi = gload(&Prow[tid]);
                if (tid >= 1){ rsi = gload(&rs[tid]); vp = VJold[tid]*sc_p; }
                else vp = 1.0;
                pvp = pi*vp;
            }
            double t = pvp;
            #pragma unroll
            for (int o = 32; o; o >>= 1) t += __shfl_down(t, o);
            if (lane == 0) redA[wid] = t;
            __syncthreads();
            double pv = 0.0;
            #pragma unroll
            for (int i = 0; i < 16; ++i) pv += redA[i];
            const double c2 = 0.5*tau_p*tau_p*pv;
            wp0 = tau_p*p0 - c2;
            if (act){
                double wp = tau_p*pi - c2*vp;
                VP[tid] = vp; WP[tid] = wp;
                if (tid >= 1){
                    double x = rsi - wp - wp0*vp;
                    VJnew[tid-1] = x;
                    if (tid >= 2) s += x*x;
                }
            }
        } else {
            if (tid < m){
                double x = A[1 + tid];   // row 0, fresh from build_A_k
                VJnew[tid] = x;
                if (tid >= 1) s += x*x;
            }
        }
        #pragma unroll
        for (int o = 32; o; o >>= 1) s += __shfl_down(s, o);
        if (lane == 0) redB[wid] = s;
        __syncthreads();     // VP/WP/VJnew visible + redB ready

        double sigma2 = 0.0;
        #pragma unroll
        for (int i = 0; i < 16; ++i) sigma2 += redB[i];
        double alpha = VJnew[0];
        double beta, tl, sc;
        if (sigma2 == 0.0){ beta = alpha; tl = 0.0; sc = 0.0; }
        else {
            beta = -copysign(sqrt(alpha*alpha + sigma2), alpha);
            tl = (beta - alpha)/beta;
            sc = 1.0/(alpha - beta);
        }

        // ---- owner-block writeback of row j ----
        if (bid == (j >> 3)){
            double* __restrict__ row = A + (size_t)j*n + (j+1);
            if (tid < m) row[tid] = VJnew[tid];
            if (tid == 0){
                e[j] = beta; tauA[j] = tl; sclA[j] = sc;
                if (j > 0) A[(size_t)j*n + j] -= 2.0*wp0;
            }
        }

        // ---- phase B: owner-private trailing update (from registers) + matvec; publish pivot ----
        if (u > j){
            const int r = u - (j+1);
            double* __restrict__ rs_w = Rst + ((size_t)((j+1) & 1) << 10);
            const bool pub = (r == 0);
            double acc = 0.0;
            if (j > 0){
                double vpr = VP[1+r], wpr = WP[1+r];
                #pragma unroll
                for (int q = 0; q < 8; ++q){
                    int c = cbase + (q << 7);
                    if (c < m){
                        double a = AR[q] - (vpr*WP[1+c] + wpr*VP[1+c]);
                        Arow[c] = a;
                        if (pub) gstore(&rs_w[c], a);
                        double vj = (c == 0) ? 1.0 : VJnew[c]*sc;
                        acc += a*vj;
                    }
                }
            } else {
                #pragma unroll
                for (int q = 0; q < 8; ++q){
                    int c = cbase + (q << 7);
                    if (c < m){
                        double a = AR[q];
                        if (pub) gstore(&rs_w[c], a);
                        double vj = (c == 0) ? 1.0 : VJnew[c]*sc;
                        acc += a*vj;
                    }
                }
            }
            #pragma unroll
            for (int o = 32; o; o >>= 1) acc += __shfl_down(acc, o);
            if (lane == 0)
                atomicAdd(&P[(size_t)j*NN + r], acc);
        }
        __syncthreads();     // each wave's vmcnt(0) drains its P atomics/Rst stores before tid0 arrives

        if (tid == 0){
            unsigned t = __hip_atomic_fetch_add(&bar[g*32], 1u, __ATOMIC_RELAXED, __HIP_MEMORY_SCOPE_AGENT);
            if (t == cumG - 1u)
                __hip_atomic_fetch_add(&bar[256], 1u, __ATOMIC_RELAXED, __HIP_MEMORY_SCOPE_AGENT);
            if (j != mylast){
                while (__hip_atomic_load(&bar[256], __ATOMIC_RELAXED, __HIP_MEMORY_SCOPE_AGENT) < cumC)
                    __builtin_amdgcn_s_sleep(1);
            }
        }
        if (j == mylast) break;    // retired (block-uniform)
        __syncthreads();           // release after spin
        tau_p = tl; sc_p = sc;
    }

    // ---- final pending update (column jend-1) on the TB x TB tail, owner-only ----
    if (bid >= (jend >> 3)){
        const int tb = n - jend;
        const double* __restrict__ VJf = VJ2[(jend-1) & 1];
        const double* __restrict__ pp  = P + (size_t)(jend-1)*NN;
        double pvp = 0.0;
        if (tid < tb){
            double pi = gload(&pp[tid]);
            double v = (tid == 0) ? 1.0 : VJf[tid]*sc_p;
            pvp = pi*v;
        }
        #pragma unroll
        for (int o = 32; o; o >>= 1) pvp += __shfl_down(pvp, o);
        if (lane == 0) redA[wid] = pvp;
        __syncthreads();
        double pv = 0.0;
        #pragma unroll
        for (int i = 0; i < 16; ++i) pv += redA[i];
        double c2f = 0.5*tau_p*tau_p*pv;
        if (u >= jend){
            const int ri = u - jend;
            double vpr = (ri == 0) ? 1.0 : VJf[ri]*sc_p;
            double wpr = tau_p*gload(&pp[ri]) - c2f*vpr;
            double* __restrict__ Ar = A + (size_t)u*n + jend;
            for (int ci = half*64 + lane; ci < tb; ci += 128){
                double vpc = (ci == 0) ? 1.0 : VJf[ci]*sc_p;
                double wpc = tau_p*gload(&pp[ci]) - c2f*vpc;
                Ar[ci] -= vpr*wpc + wpr*vpc;
            }
        }
    }
}

// Tail: remaining (TB-2) Householder steps entirely in LDS (single block).
__global__ __launch_bounds__(256) void hh_tail(double* __restrict__ A64, double* __restrict__ e,
                                               double* __restrict__ tau, double* __restrict__ scaleg, int n)
{
    __shared__ double T[TB][TB+2];
    __shared__ double v[TB], p[TB], red[256];
    const int base = n - TB;
    const int tid = threadIdx.x;
    for (int t = tid; t < TB*TB; t += 256){
        int r = t / TB, c = t % TB;
        T[r][c] = A64[(size_t)(base + r)*n + base + c];
    }
    __syncthreads();
    for (int l = 0; l <= TB - 3; ++l){
        const int m = TB - 1 - l;
        double s = 0.0;
        for (int i = 1 + tid; i < m; i += 256){ double x = T[l+1+i][l]; s += x*x; }
        red[tid] = s; __syncthreads();
        for (int o = 128; o; o >>= 1){ if (tid < o) red[tid] += red[tid + o]; __syncthreads(); }
        double sigma2 = red[0];
        double alpha = T[l+1][l];
        double beta, tl, sc;
        if (sigma2 == 0.0){ beta = alpha; tl = 0.0; sc = 0.0; }
        else {
            beta = -copysign(sqrt(alpha*alpha + sigma2), alpha);
            tl = (beta - alpha)/beta;
            sc = 1.0/(alpha - beta);
        }
        for (int i = tid; i < m; i += 256) v[i] = (i == 0) ? 1.0 : T[l+1+i][l]*sc;
        __syncthreads();
        for (int i = tid; i < m; i += 256){
            double acc = 0.0;
            for (int c = 0; c < m; ++c) acc += T[l+1+i][l+1+c]*v[c];
            p[i] = acc;
        }
        __syncthreads();
        double s2 = 0.0;
        for (int i = tid; i < m; i += 256) s2 += p[i]*v[i];
        red[tid] = s2; __syncthreads();
        for (int o = 128; o; o >>= 1){ if (tid < o) red[tid] += red[tid + o]; __syncthreads(); }
        double pvv = red[0];
        double c2 = 0.5*tl*tl*pvv;
        for (int t2 = tid; t2 < m*m; t2 += 256){
            int r = t2 / m, c = t2 % m;
            double wr = tl*p[r] - c2*v[r];
            double wc = tl*p[c] - c2*v[c];
            T[l+1+r][l+1+c] -= v[r]*wc + wr*v[c];
        }
        if (tid == 0){ int j = base + l; e[j] = beta; tau[j] = tl; scaleg[j] = 1.0; }
        for (int i = tid; i < m; i += 256) A64[(size_t)(base + l)*n + (base + l + 1) + i] = v[i];
        __syncthreads();
    }
    for (int r = tid; r < TB; r += 256) A64[(size_t)(base + r)*n + base + r] = T[r][r];
    if (tid == 0) A64[(size_t)(n-1)*n + (n-2)] = T[TB-1][TB-2];
}

__global__ __launch_bounds__(256) void extract_de_k(const double* __restrict__ A64, double* __restrict__ d,
                                                    double* __restrict__ e, int n)
{
    int i = blockIdx.x*256 + threadIdx.x;
    if (i < n) d[i] = A64[(size_t)i*n + i];
    if (i == 0) e[n-2] = A64[(size_t)(n-1)*n + (n-2)];
}

// ============================ tridiagonal eigensolver ============================
__global__ __launch_bounds__(256) void bisect_k(const double* __restrict__ d, const double* __restrict__ e,
                                                double* __restrict__ w, int n)
{
    __shared__ double ds[1024], e2s[1024];
    const int tid = threadIdx.x;
    for (int i = tid; i < n; i += 256) ds[i] = d[i];
    for (int i = tid; i < n-1; i += 256){ double ei = e[i]; e2s[i] = ei*ei; }
    __syncthreads();
    int k = blockIdx.x*256 + tid;
    if (k >= n) return;
    double gl = 1e300, gu = -1e300;
    for (int i = 0; i < n; ++i){
        double em = (i > 0) ? sqrt(e2s[i-1]) : 0.0, ep2 = (i < n-1) ? sqrt(e2s[i]) : 0.0;
        double lo2 = ds[i] - em - ep2, hi2 = ds[i] + em + ep2;
        gl = fmin(gl, lo2); gu = fmax(gu, hi2);
    }
    double lo = gl - 1e-10, hi = gu + 1e-10;
    for (int it = 0; it < 42; ++it){
        double mid = 0.5*(lo + hi);
        int cnt = 0;
        double p0 = 1.0;
        double p1 = ds[0] - mid;
        if (p1 <= 0.0){ ++cnt; if (p1 == 0.0) p1 = -1e-300; }
        for (int i = 1; i < n; ++i){
            double pn = (ds[i] - mid)*p1 - e2s[i-1]*p0;
            bool neg = ((pn < 0.0) != (p1 < 0.0)) || (pn == 0.0);
            cnt += neg;
            if (pn == 0.0) pn = (p1 > 0.0) ? -1e-300 : 1e-300;
            p0 = p1; p1 = pn;
            double ap = fabs(p1);
            if (ap > 1e120){ p1 *= 1e-200; p0 *= 1e-200; }
            else if (ap < 1e-120){ p1 *= 1e200; p0 *= 1e200; }
        }
        if (cnt <= k) lo = mid; else hi = mid;
    }
    w[k] = 0.5*(lo + hi);
}

// Inverse iteration; 16-deep load prefetch in the dependent solve passes.
__global__ __launch_bounds__(256) void invit_k(const double* __restrict__ d, const double* __restrict__ e,
                                               const double* __restrict__ w,
                                               double* __restrict__ FD, double* __restrict__ FL,
                                               double* __restrict__ FU, double* __restrict__ FU2,
                                               signed char* __restrict__ PIV, double* __restrict__ Z, int n)
{
    __shared__ double dsm[1024], esm[1024];
    const int tid = threadIdx.x;
    for (int i = tid; i < n; i += 256) dsm[i] = d[i];
    for (int i = tid; i < n-1; i += 256) esm[i] = e[i];
    __syncthreads();
    int k = blockIdx.x*256 + tid;
    if (k >= n) return;
    const double lam = w[k];
    const double tiny = 1e-280;
    double dcur = dsm[0] - lam;
    double ucur = esm[0];
    for (int i = 0; i < n-1; ++i){
        double dli = esm[i];
        double dnext_init = dsm[i+1] - lam;
        double unext_init = (i < n-2) ? esm[i+1] : 0.0;
        size_t o = (size_t)i*n + k;
        if (fabs(dcur) >= fabs(dli)){
            if (dcur == 0.0) dcur = tiny;
            double f = dli/dcur;
            FD[o] = dcur; FL[o] = f; FU[o] = ucur; FU2[o] = 0.0; PIV[o] = 0;
            dcur = dnext_init - f*ucur;
            ucur = unext_init;
        } else {
            double f = dcur/dli;
            FD[o] = dli; FL[o] = f; FU[o] = dnext_init; FU2[o] = unext_init; PIV[o] = 1;
            dcur = ucur - f*dnext_init;
            ucur = -f*unext_init;
        }
    }
    if (dcur == 0.0) dcur = tiny;
    FD[(size_t)(n-1)*n + k] = dcur;
    for (int i = 0; i < n; ++i){
        unsigned h = (unsigned)(i + 1)*0x9E3779B9u + (unsigned)(k + 1)*0x85EBCA6Bu;
        h ^= h >> 16; h *= 0x7FEB352Du; h ^= h >> 15; h *= 0x846CA68Bu; h ^= h >> 16;
        Z[(size_t)i*n + k] = (double)(h >> 8)*(1.0/16777216.0) - 0.5;
    }
    const double fdlast = FD[(size_t)(n-1)*n + k];
    for (int iter = 0; iter < 2; ++iter){
        // ---- forward substitution (prefetch-16) ----
        double zc = Z[k];
        int i = 0;
        const int nm1 = n - 1;
        for (; i + 16 <= nm1; i += 16){
            double fl[16], zn[16]; int pv[16];
            #pragma unroll
            for (int u2 = 0; u2 < 16; ++u2){
                size_t o = (size_t)(i+u2)*n + k;
                fl[u2] = FL[o]; zn[u2] = Z[o + n]; pv[u2] = PIV[o];
            }
            #pragma unroll
            for (int u2 = 0; u2 < 16; ++u2){
                size_t o = (size_t)(i+u2)*n + k;
                if (!pv[u2]){ Z[o] = zc; zc = zn[u2] - fl[u2]*zc; }
                else        { Z[o] = zn[u2]; zc = zc - fl[u2]*zn[u2]; }
            }
        }
        for (; i < nm1; ++i){
            size_t o = (size_t)i*n + k;
            double fl = FL[o], zn = Z[o + n];
            if (!PIV[o]){ Z[o] = zc; zc = zn - fl*zc; }
            else        { Z[o] = zn; zc = zc - fl*zn; }
        }
        // ---- backward substitution (prefetch-16) ----
        double za = zc / fdlast;
        Z[(size_t)(n-1)*n + k] = za;
        size_t o2 = (size_t)(n-2)*n + k;
        double zaa = (Z[o2] - FU[o2]*za) / FD[o2];
        Z[o2] = zaa;
        double zb = za;
        int i2 = n - 3;
        for (; i2 >= 15; i2 -= 16){
            double zv[16], fu[16], fu2v[16], fd[16];
            #pragma unroll
            for (int u2 = 0; u2 < 16; ++u2){
                size_t o = (size_t)(i2-u2)*n + k;
                zv[u2] = Z[o]; fu[u2] = FU[o]; fu2v[u2] = FU2[o]; fd[u2] = FD[o];
            }
            #pragma unroll
            for (int u2 = 0; u2 < 16; ++u2){
                size_t o = (size_t)(i2-u2)*n + k;
                double znew = (zv[u2] - fu[u2]*zaa - fu2v[u2]*zb) / fd[u2];
                Z[o] = znew;
                zb = zaa; zaa = znew;
            }
        }
        for (; i2 >= 0; --i2){
            size_t o = (size_t)i2*n + k;
            double znew = (Z[o] - FU[o]*zaa - FU2[o]*zb) / FD[o];
            Z[o] = znew;
            zb = zaa; zaa = znew;
        }
        // ---- max-normalize (prefetch-8) ----
        double m0=0,m1=0,m2=0,m3=0,m4=0,m5=0,m6=0,m7=0;
        int i3 = 0;
        for (; i3 + 8 <= n; i3 += 8){
            m0 = fmax(m0, fabs(Z[(size_t)(i3+0)*n + k]));
            m1 = fmax(m1, fabs(Z[(size_t)(i3+1)*n + k]));
            m2 = fmax(m2, fabs(Z[(size_t)(i3+2)*n + k]));
            m3 = fmax(m3, fabs(Z[(size_t)(i3+3)*n + k]));
            m4 = fmax(m4, fabs(Z[(size_t)(i3+4)*n + k]));
            m5 = fmax(m5, fabs(Z[(size_t)(i3+5)*n + k]));
            m6 = fmax(m6, fabs(Z[(size_t)(i3+6)*n + k]));
            m7 = fmax(m7, fabs(Z[(size_t)(i3+7)*n + k]));
        }
        double mx = fmax(fmax(fmax(m0,m1),fmax(m2,m3)), fmax(fmax(m4,m5),fmax(m6,m7)));
        for (; i3 < n; ++i3) mx = fmax(mx, fabs(Z[(size_t)i3*n + k]));
        double s = (mx > 0.0) ? 1.0/mx : 1.0;
        for (int i4 = 0; i4 + 8 <= n; i4 += 8){
            double zv[8];
            #pragma unroll
            for (int u2 = 0; u2 < 8; ++u2) zv[u2] = Z[(size_t)(i4+u2)*n + k];
            #pragma unroll
            for (int u2 = 0; u2 < 8; ++u2) Z[(size_t)(i4+u2)*n + k] = zv[u2]*s;
        }
    }
    // ---- 2-norm normalize (prefetch-8) ----
    double n0=0,n1=0,n2=0,n3=0,n4=0,n5=0,n6=0,n7=0;
    int i5 = 0;
    for (; i5 + 8 <= n; i5 += 8){
        double zv[8];
        #pragma unroll
        for (int u2 = 0; u2 < 8; ++u2) zv[u2] = Z[(size_t)(i5+u2)*n + k];
        n0 += zv[0]*zv[0]; n1 += zv[1]*zv[1]; n2 += zv[2]*zv[2]; n3 += zv[3]*zv[3];
        n4 += zv[4]*zv[4]; n5 += zv[5]*zv[5]; n6 += zv[6]*zv[6]; n7 += zv[7]*zv[7];
    }
    double nrm = ((n0+n1)+(n2+n3)) + ((n4+n5)+(n6+n7));
    for (; i5 < n; ++i5){ double v = Z[(size_t)i5*n + k]; nrm += v*v; }
    double s = 1.0/sqrt(nrm);
    for (int i6 = 0; i6 + 8 <= n; i6 += 8){
        double zv[8];
        #pragma unroll
        for (int u2 = 0; u2 < 8; ++u2) zv[u2] = Z[(size_t)(i6+u2)*n + k];
        #pragma unroll
        for (int u2 = 0; u2 < 8; ++u2) Z[(size_t)(i6+u2)*n + k] = zv[u2]*s;
    }
}

// ============================ batched blocked-WY back-transform ============================
__global__ __launch_bounds__(256) void wy_buildV_k(const double* __restrict__ A64, const double* __restrict__ scaleg,
                                                   double* __restrict__ Vbig, int n)
{
    size_t idx = (size_t)blockIdx.x*256 + threadIdx.x;
    if (idx >= (size_t)NWY*1024*64) return;
    int g = (int)(idx >> 16);
    int r = (int)((idx >> 6) & 1023);
    int t = (int)(idx & 63);
    int b0 = g*64;
    int nbsz = (n - 2) - b0; if (nbsz > 64) nbsz = 64;
    double v = 0.0;
    if (t < nbsz){
        int j = b0 + t;
        if (r == j + 1) v = 1.0;
        else if (r > j + 1) v = A64[(size_t)j*n + r]*scaleg[j];
    }
    Vbig[idx] = v;
}

__global__ __launch_bounds__(256) void wy_buildT_k(const double* __restrict__ Vbig, const double* __restrict__ tau,
                                                   double* __restrict__ Tbig, int n)
{
    __shared__ double G[64][65];
    __shared__ double Ts[64][65];
    __shared__ double Vs[32][65];
    const int g = blockIdx.x;
    const int tid = threadIdx.x;
    const double* __restrict__ V = Vbig + ((size_t)g << 16);
    const int b0 = g*64;
    int nbsz = (n - 2) - b0; if (nbsz > 64) nbsz = 64;
    for (int p = tid; p < 64*64; p += 256) G[p >> 6][p & 63] = 0.0;
    __syncthreads();
    for (int rb = b0; rb < n; rb += 32){
        for (int s = tid; s < 2048; s += 256){
            int rr = s >> 6, tt = s & 63;
            Vs[rr][tt] = V[((size_t)(rb + rr) << 6) + tt];
        }
        __syncthreads();
        for (int p = tid; p < 4096; p += 256){
            int t = p >> 6, s2 = p & 63;
            if (t < s2 && s2 < nbsz){
                double acc = 0.0;
                #pragma unroll 8
                for (int rr = 0; rr < 32; ++rr) acc += Vs[rr][t]*Vs[rr][s2];
                G[t][s2] += acc;
            }
        }
        __syncthreads();
    }
    for (int t = nbsz - 1; t >= 0; --t){
        for (int u = tid; u < 64; u += 256){
            double val = 0.0;
            if (u == t) val = tau[b0 + t];
            else if (u > t && u < nbsz){
                double s = 0.0;
                for (int s2 = t + 1; s2 <= u; ++s2) s += G[t][s2]*Ts[s2][u];
                val = -tau[b0 + t]*s;
            }
            Ts[t][u] = val;
        }
        __syncthreads();
    }
    for (int p = tid; p < 64*64; p += 256){
        int t = p >> 6, u = p & 63;
        Tbig[((size_t)g << 12) + p] = (t < nbsz) ? Ts[t][u] : 0.0;
    }
}

// 1024-thread WY apply: 64-row chunks, one (t,c) pair per thread.
// Identical summation order to the 256-thread version (chunk-ascending, row-ascending,
// t-ascending) -> bitwise-identical Z. 4x the waves of the old config (was 1 wave/CU).
__global__ __launch_bounds__(1024) void wy_apply_k(const double* __restrict__ Vbig, const double* __restrict__ Tbig,
                                                   double* __restrict__ Z, int n)
{
    __shared__ double Vs[64][65];
    __shared__ double Zs[64][17];
    __shared__ double Y[64][17];
    __shared__ double W[64][17];
    const int tid = threadIdx.x;        // 0..1023
    const int c   = tid & 15;
    const int tq  = tid >> 4;           // 0..63
    const int c0  = blockIdx.x * 16;

    for (int g = NWY - 1; g >= 0; --g){
        const double* __restrict__ V = Vbig + ((size_t)g << 16);
        const double* __restrict__ T = Tbig + ((size_t)g << 12);
        const int b0 = g*64;
        double acc = 0.0;
        for (int rb = b0; rb < n; rb += 64){
            for (int s = tid; s < 4096; s += 1024){
                int rr = s >> 6, tt = s & 63;
                Vs[rr][tt] = V[((size_t)(rb + rr) << 6) + tt];
            }
            {
                int rr = tid >> 4, cc = tid & 15;
                Zs[rr][cc] = Z[(size_t)(rb + rr)*n + c0 + cc];
            }
            __syncthreads();
            #pragma unroll 8
            for (int rr = 0; rr < 64; ++rr)
                acc += Vs[rr][tq]*Zs[rr][c];
            __syncthreads();
        }
        Y[tq][c] = acc;
        __syncthreads();
        {
            double a = 0.0;
            for (int s = tq; s < 64; ++s) a += T[(tq << 6) + s]*Y[s][c];
            W[tq][c] = a;
        }
        __syncthreads();
        for (int rb = b0; rb < n; rb += 64){
            for (int s = tid; s < 4096; s += 1024){
                int rr = s >> 6, tt = s & 63;
                Vs[rr][tt] = V[((size_t)(rb + rr) << 6) + tt];
            }
            __syncthreads();
            {
                int rr = tid >> 4, cc = tid & 15;
                double s2 = 0.0;
                #pragma unroll 16
                for (int t = 0; t < 64; ++t) s2 += Vs[rr][t]*W[t][cc];
                Z[(size_t)(rb + rr)*n + c0 + cc] -= s2;
            }
            __syncthreads();
        }
        __syncthreads();
    }
}

// ============================ host dispatch helpers ============================
static void gemmf32(hipStream_t st, int epi,
                    const float* A, const float* B, float* C, int M, int N, int K,
                    const float* bias, const float* D)
{
    if ((K & 15) == 0 && (N & 7) == 0){
        if (M >= 768){
            dim3 g((N + 127)/128, (M + 127)/128), b(256);
            switch (epi){
            case EPI_NONE:      gemm128db<EPI_NONE><<<g, b, 0, st>>>(A, B, C, M, N, K, bias, D); break;
            case EPI_BIAS:      gemm128db<EPI_BIAS><<<g, b, 0, st>>>(A, B, C, M, N, K, bias, D); break;
            case EPI_BIAS_ADD:  gemm128db<EPI_BIAS_ADD><<<g, b, 0, st>>>(A, B, C, M, N, K, bias, D); break;
            case EPI_ABS_DIAG1: gemm128db<EPI_ABS_DIAG1><<<g, b, 0, st>>>(A, B, C, M, N, K, bias, D); break;
            case EPI_RELU:      gemm128db<EPI_RELU><<<g, b, 0, st>>>(A, B, C, M, N, K, bias, D); break;
            }
        } else {
            dim3 g((N + 127)/128, (M + 63)/64), b(128);
            switch (epi){
            case EPI_NONE:      gemm_db<EPI_NONE><<<g, b, 0, st>>>(A, B, C, M, N, K, bias, D); break;
            case EPI_BIAS:      gemm_db<EPI_BIAS><<<g, b, 0, st>>>(A, B, C, M, N, K, bias, D); break;
            case EPI_BIAS_ADD:  gemm_db<EPI_BIAS_ADD><<<g, b, 0, st>>>(A, B, C, M, N, K, bias, D); break;
            case EPI_ABS_DIAG1: gemm_db<EPI_ABS_DIAG1><<<g, b, 0, st>>>(A, B, C, M, N, K, bias, D); break;
            case EPI_RELU:      gemm_db<EPI_RELU><<<g, b, 0, st>>>(A, B, C, M, N, K, bias, D); break;
            }
        }
    } else {
        dim3 g((N + 63)/64, (M + 63)/64), b(256);
        switch (epi){
        case EPI_NONE:      gemm32<EPI_NONE><<<g, b, 0, st>>>(A, B, C, M, N, K, bias, D); break;
        case EPI_BIAS:      gemm32<EPI_BIAS><<<g, b, 0, st>>>(A, B, C, M, N, K, bias, D); break;
        case EPI_BIAS_ADD:  gemm32<EPI_BIAS_ADD><<<g, b, 0, st>>>(A, B, C, M, N, K, bias, D); break;
        case EPI_ABS_DIAG1: gemm32<EPI_ABS_DIAG1><<<g, b, 0, st>>>(A, B, C, M, N, K, bias, D); break;
        case EPI_RELU:      gemm32<EPI_RELU><<<g, b, 0, st>>>(A, B, C, M, N, K, bias, D); break;
        }
    }
}

// ============================ kernel_launch ============================
extern "C" void kernel_launch(void* const* d_in, const int* in_sizes, int n_in,
                              void* d_out, int out_size, void* d_ws, size_t ws_size,
                              hipStream_t stream)
{
    (void)in_sizes; (void)n_in; (void)out_size; (void)ws_size;
    const float* lr       = (const float*)d_in[0];
    const float* gsr_w    = (const float*)d_in[1];
    const float* start_w  = (const float*)d_in[2];
    const float* start_b  = (const float*)d_in[3];
    const float* down_w   = (const float*)d_in[4];
    const float* down_b   = (const float*)d_in[5];
    const float* pool_w   = (const float*)d_in[6];
    const float* pool_b   = (const float*)d_in[7];
    const float* bottom_w = (const float*)d_in[8];
    const float* bottom_b = (const float*)d_in[9];
    const float* end_w    = (const float*)d_in[10];
    const float* end_b    = (const float*)d_in[11];
    const float* up_w     = (const float*)d_in[12];
    const float* up_b     = (const float*)d_in[13];
    const float* gc1      = (const float*)d_in[14];
    const float* gc2      = (const float*)d_in[15];

    float* out_z     = (float*)d_out;                       // [2048,2048]
    float* out_net   = out_z + (size_t)HRD*HRD;             // [1024,2048]
    float* out_start = out_net + (size_t)NN*HRD;            // [1024,320]
    float* out_adj   = out_start + (size_t)NN*DIMF;         // [2048,2048]

    static const int LVL_N[4] = {1024, 921, 644, 386};
    static const int LVL_K[4] = {921, 644, 386, 193};

    // -------- workspace arena --------
    char* Wb = (char*)d_ws;
    size_t off = 0;
    auto alloc = [&](size_t bb)->char*{ char* p = Wb + off; off = (off + bb + 255) & ~(size_t)255; return p; };

    float*  A32  = (float*) alloc((size_t)NN*NN*4);
    double* A64  = (double*)alloc((size_t)NN*NN*8);
    float*  UfT  = (float*) alloc((size_t)NN*NN*4);   // U^T as [k][j] fp32
    double* r64  = (double*)alloc(NN*8);
    double* dD   = (double*)alloc(NN*8);
    double* dE   = (double*)alloc(NN*8);
    double* dTau = (double*)alloc(NN*8);
    double* dScl = (double*)alloc(NN*8);
    double* dWev = (double*)alloc(NN*8);
    double* pvA  = (double*)alloc(NN*8);              // kept (init target), unused by coop8
    double* Rst  = (double*)alloc((size_t)2*NN*8);    // double-buffered pivot-row stage (sc1)
    unsigned* barcnt = (unsigned*)alloc(8192);
    char* SBASE = Wb + off;

    // P2 overlay (U-Net)
    size_t so = 0;
    auto salloc = [&](size_t bb)->char*{ char* p = SBASE + so; so = (so + bb + 255) & ~(size_t)255; return p; };
    float* XT  = (float*)salloc((size_t)NN*DIMF*4);
    float* XP1 = (float*)salloc((size_t)NN*DIMF*4);
    float* XP2 = (float*)salloc((size_t)NN*DIMF*4);
    float* XU  = (float*)salloc((size_t)NN*DIMF*4);
    float* DN[4]; for (int l = 0; l < 4; ++l) DN[l] = (float*)salloc((size_t)NN*DIMF*4);
    float* Asub[4];
    for (int l = 0; l < 4; ++l) Asub[l] = (float*)salloc((size_t)LVL_K[l]*LVL_K[l]*4);
    float* SC = (float*)salloc(NN*4);
    int*   IDX[4]; for (int l = 0; l < 4; ++l) IDX[l] = (int*)salloc(NN*4);
    float* VAL[4]; for (int l = 0; l < 4; ++l) VAL[l] = (float*)salloc(NN*4);
    float* XC  = (float*)salloc((size_t)NN*2*DIMF*4);
    float* AXC = (float*)salloc((size_t)NN*2*DIMF*4);

    // P3 overlay (eigensolver scratch)
    const size_t PL = (size_t)NN*NN*8;
    double* Z64 = (double*)(SBASE);
    double* FD  = (double*)(SBASE + PL);       // doubles as Pmat during sytrd, Vbig during WY
    double* FL  = (double*)(SBASE + 2*PL);     // doubles as Tbig during WY
    double* FU  = (double*)(SBASE + 3*PL);
    double* FU2 = (double*)(SBASE + 4*PL);
    signed char* FPIV = (signed char*)(SBASE + 5*PL);
    double* Pmat = FD;
    double* Vbig = FD;
    double* Tbig = FL;

    // P4 overlay (GSR / refinement)
    const size_t MB8  = (size_t)HRD*NN*4;    // 8 MiB
    const size_t MB16 = (size_t)HRD*HRD*4;   // 16 MiB
    float* P4a   = (float*)(SBASE);
    float* P4t1  = (float*)(SBASE + MB8);
    float* P4adT = (float*)(SBASE);
    float* P4Zb  = (float*)(SBASE + MB16);
    float* P4ZG  = (float*)(SBASE);
    float* P4h1  = (float*)(SBASE + MB8);
    float* P4HG  = (float*)(SBASE + MB16);
    float* P4h2  = (float*)(SBASE);

    // =============== P1: normalized adjacency ===============
    rowsum_rsqrt_k<<<NN, 256, 0, stream>>>(lr, r64, NN);
    build_A_k<<<(NN*NN + 255)/256, 256, 0, stream>>>(lr, r64, A32, A64, NN);

    // =============== P2: graph U-Net (fp32) ===============
    gemmf32(stream, EPI_BIAS, A32, start_w, out_start, NN, DIMF, NN, start_b, nullptr);

    const float* Xcur = out_start;
    const float* Acur = A32;
    float* ping = XP1; float* pong = XP2;
    for (int l = 0; l < 4; ++l){
        int nl = LVL_N[l], kl = LVL_K[l];
        gemmf32(stream, EPI_NONE, Acur, Xcur, XT, nl, DIMF, nl, nullptr, nullptr);
        gemmf32(stream, EPI_BIAS, XT, down_w + (size_t)l*DIMF*DIMF, DN[l], nl, DIMF, DIMF,
                down_b + (size_t)l*DIMF, nullptr);
        score_k<<<(nl + 3)/4, 256, 0, stream>>>(DN[l], pool_w + (size_t)l*DIMF, pool_b + l, SC, nl, DIMF);
        topk_k<<<1, 256, 0, stream>>>(SC, nl, kl, IDX[l], VAL[l]);
        gatherX_k<<<(unsigned)(((size_t)kl*DIMF + 255)/256), 256, 0, stream>>>(DN[l], IDX[l], VAL[l], ping, kl, DIMF);
        gatherA_k<<<(unsigned)(((size_t)kl*kl + 255)/256), 256, 0, stream>>>(Acur, IDX[l], Asub[l], kl, nl);
        Xcur = ping; Acur = Asub[l];
        float* t = ping; ping = pong; pong = t;
    }
    gemmf32(stream, EPI_NONE, Acur, Xcur, XT, 193, DIMF, 193, nullptr, nullptr);
    float* Xb = ping;
    gemmf32(stream, EPI_BIAS, XT, bottom_w, Xb, 193, DIMF, DIMF, bottom_b, nullptr);
    const float* Xup = Xb;
    float* upbuf[2] = { (Xb == XP1) ? XP2 : XP1, (Xb == XP1) ? XP1 : XP2 };
    for (int i2 = 0; i2 < 4; ++i2){
        int jl = 3 - i2;
        int nj = LVL_N[jl];
        int kj = LVL_K[jl];
        fill0_k<<<(unsigned)(((size_t)nj*DIMF + 255)/256), 256, 0, stream>>>(XU, (size_t)nj*DIMF);
        scatterX_k<<<(unsigned)(((size_t)kj*DIMF + 255)/256), 256, 0, stream>>>(Xup, IDX[jl], XU, kj, DIMF);
        const float* Aj = (jl == 0) ? A32 : Asub[jl - 1];
        gemmf32(stream, EPI_NONE, Aj, XU, XT, nj, DIMF, nj, nullptr, nullptr);
        float* Xn = upbuf[i2 & 1];
        gemmf32(stream, EPI_BIAS_ADD, XT, up_w + (size_t)i2*DIMF*DIMF, Xn, nj, DIMF, DIMF,
                up_b + (size_t)i2*DIMF, DN[jl]);
        Xup = Xn;
    }
    concat_k<<<(unsigned)(((size_t)NN*2*DIMF + 255)/256), 256, 0, stream>>>(Xup, out_start, XC, NN, DIMF);
    gemmf32(stream, EPI_NONE, A32, XC, AXC, NN, 2*DIMF, NN, nullptr, nullptr);
    gemmf32(stream, EPI_BIAS, AXC, end_w, out_net, NN, HRD, 2*DIMF, end_b, nullptr);

    // =============== P3: eigendecomposition of A (fp64) ===============
    const int JEND = NN - TB;
    init_sytrd_k<<<4, 256, 0, stream>>>(pvA, barcnt, NN);
    filld0_k<<<(unsigned)(((size_t)JEND*NN + 255)/256), 256, 0, stream>>>(Pmat, (size_t)JEND*NN);
    sytrd_coop8<<<CB3, BT3, 0, stream>>>(A64, dE, dTau, dScl, Pmat, Rst, barcnt, NN, JEND);
    hh_tail<<<1, 256, 0, stream>>>(A64, dE, dTau, dScl, NN);
    extract_de_k<<<4, 256, 0, stream>>>(A64, dD, dE, NN);
    bisect_k<<<4, 256, 0, stream>>>(dD, dE, dWev, NN);
    invit_k<<<4, 256, 0, stream>>>(dD, dE, dWev, FD, FL, FU, FU2, FPIV, Z64, NN);
    wy_buildV_k<<<(unsigned)(((size_t)NWY*1024*64 + 255)/256), 256, 0, stream>>>(A64, dScl, Vbig, NN);
    wy_buildT_k<<<NWY, 256, 0, stream>>>(Vbig, dTau, Tbig, NN);
    wy_apply_k<<<NN/16, 1024, 0, stream>>>(Vbig, Tbig, Z64, NN);
    {
        dim3 g(NN/32, NN/32), b(256);
        transpose_cast_k<<<g, b, 0, stream>>>(Z64, UfT, NN);
    }

    // =============== P4: GSR layer + refinement (fp32) ===============
    build_a_k<<<(unsigned)(((size_t)HRD*NN + 255)/256), 256, 0, stream>>>(gsr_w, P4a);
    gemmf32(stream, EPI_NONE, P4a, UfT, P4t1, HRD, NN, NN, nullptr, nullptr);               // a @ U^T
    gemmf32(stream, EPI_ABS_DIAG1, P4t1, out_net, out_adj, HRD, HRD, NN, nullptr, nullptr); // adj
    {
        dim3 g(HRD/32, HRD/32), b(256);
        transpose32_k<<<g, b, 0, stream>>>(out_adj, P4adT, HRD);                            // adj^T
    }
    {
        const int T = HRD >> 7;                       // 16 tiles -> 136 upper pairs
        gemm_symAAT<<<T*(T+1)/2, 256, 0, stream>>>(out_adj, P4adT, P4Zb, HRD);              // adj @ adj^T (sym)
    }
    symabs1_k<<<(unsigned)(((size_t)HRD*HRD + 255)/256), 256, 0, stream>>>(P4Zb, HRD);      // Z
    gemmf32(stream, EPI_NONE, P4Zb, gc1, P4ZG, HRD, NN, HRD, nullptr, nullptr);             // Z @ gc1
    gemmf32(stream, EPI_RELU, out_adj, P4ZG, P4h1, HRD, NN, HRD, nullptr, nullptr);         // h1
    gemmf32(stream, EPI_NONE, P4h1, gc2, P4HG, HRD, HRD, NN, nullptr, nullptr);             // h1 @ gc2
    gemmf32(stream, EPI_RELU, out_adj, P4HG, P4h2, HRD, HRD, HRD, nullptr, nullptr);        // h2
    final_z_k<<<(unsigned)(((size_t)HRD*HRD + 255)/256), 256, 0, stream>>>(P4h2, out_z, HRD); // z
}